// Round 3
// baseline (6396.154 us; speedup 1.0000x reference)
//
#include <hip/hip_runtime.h>
#include <math.h>

typedef __attribute__((ext_vector_type(8))) short bf16x8;
typedef __attribute__((ext_vector_type(4))) float f32x4;
typedef unsigned short u16;
typedef __attribute__((ext_vector_type(4))) unsigned short u16x4;

namespace {
constexpr int Bc = 64, Tc = 12, Nn = 1024, Hc = 64, Ec = 10;
constexpr int NB = Nn * Bc;  // 65536
constexpr int Cc = 66;       // unified channel count (enc uses 65, col 65 zeroed)
constexpr int SA = 208;      // XA row stride ([X(66)|Y1(66)|Y2(66)|pad10])
constexpr int KP = 224;      // padded K for gate/update GEMMs (7 x 32)
constexpr int KD = Bc * Ec;  // 640, dec gram K
constexpr int TN = Tc * Nn;  // 12288
constexpr int NC = Bc * Cc;  // 4224, ygemm N extent
// Row index convention: rid = b*Nn + n  (b outer, n inner).
}

#define SWZ(r) (((r) >> 1) & 3)

__device__ __forceinline__ void gld16(const void* g, void* l) {
  __builtin_amdgcn_global_load_lds(
      (const __attribute__((address_space(1))) void*)g,
      (__attribute__((address_space(3))) void*)l, 16, 0, 0);
}

__device__ __forceinline__ void split_bf(float v, u16& h, u16& l) {
  unsigned u = __float_as_uint(v);
  unsigned hu = (u + 0x7FFFu + ((u >> 16) & 1u)) & 0xFFFF0000u;
  h = (u16)(hu >> 16);
  float r = v - __uint_as_float(hu);
  unsigned u2 = __float_as_uint(r);
  l = (u16)((u2 + 0x7FFFu + ((u2 >> 16) & 1u)) >> 16);
}
__device__ __forceinline__ u16 bf_rne(float v) {
  unsigned u = __float_as_uint(v);
  return (u16)((u + 0x7FFFu + ((u >> 16) & 1u)) >> 16);
}
__device__ __forceinline__ float bf_to_f(u16 v) {
  return __uint_as_float(((unsigned)v) << 16);
}
__device__ __forceinline__ bf16x8 ldfrag(const u16* p) { return *(const bf16x8*)p; }

// ---------- enc gram: G = emb @ emb^T (Kd small, fp32) ----------
__global__ __launch_bounds__(256) void k_gram(const float* __restrict__ in, int Kd,
                                              float* __restrict__ G) {
  __shared__ float At[16][64];
  __shared__ float Bt[16][64];
  int i0 = blockIdx.y * 64, j0 = blockIdx.x * 64;
  int tx = threadIdx.x & 15, ty = threadIdx.x >> 4;
  float acc[4][4] = {};
  for (int k0 = 0; k0 < Kd; k0 += 16) {
    for (int u = threadIdx.x; u < 1024; u += 256) {
      int i = u >> 4, k = u & 15;
      At[k][i] = (k0 + k < Kd) ? in[(size_t)(i0 + i) * Kd + k0 + k] : 0.f;
    }
    for (int u = threadIdx.x; u < 1024; u += 256) {
      int j = u >> 4, k = u & 15;
      Bt[k][j] = (k0 + k < Kd) ? in[(size_t)(j0 + j) * Kd + k0 + k] : 0.f;
    }
    __syncthreads();
#pragma unroll
    for (int kk = 0; kk < 16; kk++) {
      float a[4], b[4];
#pragma unroll
      for (int p = 0; p < 4; p++) a[p] = At[kk][ty * 4 + p];
#pragma unroll
      for (int q = 0; q < 4; q++) b[q] = Bt[kk][tx * 4 + q];
#pragma unroll
      for (int p = 0; p < 4; p++)
#pragma unroll
        for (int q = 0; q < 4; q++) acc[p][q] = fmaf(a[p], b[q], acc[p][q]);
    }
    __syncthreads();
  }
  for (int p = 0; p < 4; p++)
    for (int q = 0; q < 4; q++)
      G[(size_t)(i0 + ty * 4 + p) * Nn + j0 + tx * 4 + q] = acc[p][q];
}

// ---------- dec gram via split-MFMA: G = DE @ DE^T ----------
__global__ __launch_bounds__(256) void k_gram_mfma(const u16* __restrict__ Dh,
                                                   const u16* __restrict__ Dl,
                                                   float* __restrict__ G) {
  __shared__ u16 lds[12288];
  const int tid = threadIdx.x;
  const int wave = tid >> 6, lane = tid & 63;
  const int i0 = blockIdx.y * 64;
  const int j0 = blockIdx.x * 128;
  const int wy = wave >> 1, wx = wave & 1;
  const int m = lane & 15, quad = lane >> 4;

  f32x4 acc[2][4];
  f32x4 z4 = {0.f, 0.f, 0.f, 0.f};
#pragma unroll
  for (int a = 0; a < 2; a++)
#pragma unroll
    for (int q = 0; q < 4; q++) acc[a][q] = z4;

  const int ar = tid >> 2;
  const int akc = (tid & 3) ^ SWZ(ar);

  for (int k0 = 0; k0 < KD; k0 += 32) {
    gld16(Dh + (size_t)(i0 + ar) * KD + k0 + akc * 8, &lds[wave * 512]);
    gld16(Dl + (size_t)(i0 + ar) * KD + k0 + akc * 8, &lds[2048 + wave * 512]);
#pragma unroll
    for (int p = 0; p < 2; p++) {
      int r = p * 64 + (tid >> 2);
      int kc = (tid & 3) ^ SWZ(r);
      gld16(Dh + (size_t)(j0 + r) * KD + k0 + kc * 8, &lds[4096 + p * 2048 + wave * 512]);
      gld16(Dl + (size_t)(j0 + r) * KD + k0 + kc * 8, &lds[8192 + p * 2048 + wave * 512]);
    }
    __syncthreads();

    bf16x8 ah[2], al[2], bh[4], bl[4];
#pragma unroll
    for (int mb = 0; mb < 2; mb++) {
      int r = wy * 32 + mb * 16 + m;
      int ci = r * 4 + (quad ^ SWZ(r));
      ah[mb] = *(const bf16x8*)&lds[ci * 8];
      al[mb] = *(const bf16x8*)&lds[2048 + ci * 8];
    }
#pragma unroll
    for (int nb = 0; nb < 4; nb++) {
      int rj = wx * 64 + nb * 16 + m;
      int cj = rj * 4 + (quad ^ SWZ(rj));
      bh[nb] = *(const bf16x8*)&lds[4096 + cj * 8];
      bl[nb] = *(const bf16x8*)&lds[8192 + cj * 8];
    }
#pragma unroll
    for (int mb = 0; mb < 2; mb++)
#pragma unroll
      for (int nb = 0; nb < 4; nb++) {
        acc[mb][nb] = __builtin_amdgcn_mfma_f32_16x16x32_bf16(ah[mb], bh[nb], acc[mb][nb], 0, 0, 0);
        acc[mb][nb] = __builtin_amdgcn_mfma_f32_16x16x32_bf16(ah[mb], bl[nb], acc[mb][nb], 0, 0, 0);
        acc[mb][nb] = __builtin_amdgcn_mfma_f32_16x16x32_bf16(al[mb], bh[nb], acc[mb][nb], 0, 0, 0);
      }
    __syncthreads();
  }

#pragma unroll
  for (int mb = 0; mb < 2; mb++)
#pragma unroll
    for (int nb = 0; nb < 4; nb++) {
      int col = j0 + wx * 64 + nb * 16 + m;
#pragma unroll
      for (int p = 0; p < 4; p++) {
        int row = i0 + wy * 32 + mb * 16 + quad * 4 + p;
        G[(size_t)row * Nn + col] = acc[mb][nb][p];
      }
    }
}

// ---------- S = row_softmax(relu(G)) -> split to S1h/S1l ----------
__global__ __launch_bounds__(256) void k_softmax(const float* __restrict__ G,
                                                 u16* __restrict__ S1h,
                                                 u16* __restrict__ S1l) {
  __shared__ float sred[8];
  int n = blockIdx.x;
  float v[4];
#pragma unroll
  for (int i = 0; i < 4; i++)
    v[i] = fmaxf(G[(size_t)n * Nn + threadIdx.x + i * 256], 0.f);
  float mx = fmaxf(fmaxf(v[0], v[1]), fmaxf(v[2], v[3]));
  for (int off = 32; off > 0; off >>= 1) mx = fmaxf(mx, __shfl_down(mx, off));
  if ((threadIdx.x & 63) == 0) sred[threadIdx.x >> 6] = mx;
  __syncthreads();
  float rmax = fmaxf(fmaxf(sred[0], sred[1]), fmaxf(sred[2], sred[3]));
  float s = 0.f;
#pragma unroll
  for (int i = 0; i < 4; i++) { v[i] = expf(v[i] - rmax); s += v[i]; }
  for (int off = 32; off > 0; off >>= 1) s += __shfl_down(s, off);
  if ((threadIdx.x & 63) == 0) sred[4 + (threadIdx.x >> 6)] = s;
  __syncthreads();
  float inv = 1.f / (sred[4] + sred[5] + sred[6] + sred[7]);
#pragma unroll
  for (int i = 0; i < 4; i++) {
    u16 h, l;
    split_bf(v[i] * inv, h, l);
    size_t a = (size_t)n * Nn + threadIdx.x + i * 256;
    S1h[a] = h; S1l[a] = l;
  }
}

// ---------- transpose S1h/S1l -> Sth/Stl ----------
__global__ __launch_bounds__(256) void k_tr2(const u16* __restrict__ Ah,
                                             const u16* __restrict__ Al,
                                             u16* __restrict__ Th, u16* __restrict__ Tl) {
  __shared__ u16 sm[64][72];
  int i0 = blockIdx.y * 64, j0 = blockIdx.x * 64;
  int tid = threadIdx.x;
  for (int pass = 0; pass < 2; pass++) {
    const u16* src = pass ? Al : Ah;
    u16* dst = pass ? Tl : Th;
    for (int u = tid; u < 4096; u += 256) {
      int i = u >> 6, c = u & 63;
      sm[i][c] = src[(size_t)(i0 + i) * Nn + j0 + c];
    }
    __syncthreads();
    for (int u = tid; u < 4096; u += 256) {
      int c = u >> 6, i = u & 63;
      dst[(size_t)(j0 + c) * Nn + i0 + i] = sm[i][c];
    }
    __syncthreads();
  }
}

// ---------- S2 = 2*S@S - I via direct-fragment split MFMA (3-term, bf16 out) ----------
// 128 blocks 1D, XCD-clustered: xcd = blk&7 -> i0 pair {2*xcd, 2*xcd+1}.
__global__ __launch_bounds__(256) void k_s2_mfma(const u16* __restrict__ S1h,
                                                 const u16* __restrict__ S1l,
                                                 const u16* __restrict__ Sth,
                                                 const u16* __restrict__ Stl,
                                                 u16* __restrict__ S2h) {
  const int tid = threadIdx.x;
  const int wave = tid >> 6, lane = tid & 63;
  const int blk = blockIdx.x;
  const int s = blk >> 3;
  const int i0 = ((blk & 7) * 2 + (s & 1)) * 64;
  const int j0 = (s >> 1) * 128;
  const int wy = wave >> 1, wx = wave & 1;
  const int m = lane & 15, quad = lane >> 4;

  const size_t aoff = (size_t)(i0 + wy * 32 + m) * Nn + quad * 8;
  const size_t boff = (size_t)(j0 + wx * 64 + m) * Nn + quad * 8;

  f32x4 acc[2][4];
  f32x4 z4 = {0.f, 0.f, 0.f, 0.f};
#pragma unroll
  for (int a = 0; a < 2; a++)
#pragma unroll
    for (int q = 0; q < 4; q++) acc[a][q] = z4;

  bf16x8 fAh[2][2], fAl[2][2], fBh[2][4], fBl[2][4];
  auto ld = [&](int k0, int sb) {
#pragma unroll
    for (int mb = 0; mb < 2; mb++) {
      fAh[sb][mb] = ldfrag(S1h + aoff + (size_t)mb * 16 * Nn + k0);
      fAl[sb][mb] = ldfrag(S1l + aoff + (size_t)mb * 16 * Nn + k0);
    }
#pragma unroll
    for (int nb = 0; nb < 4; nb++) {
      fBh[sb][nb] = ldfrag(Sth + boff + (size_t)nb * 16 * Nn + k0);
      fBl[sb][nb] = ldfrag(Stl + boff + (size_t)nb * 16 * Nn + k0);
    }
  };
  ld(0, 0);
#pragma unroll 2
  for (int kt = 0; kt < 32; kt++) {
    int cur = kt & 1;
    if (kt < 31) ld((kt + 1) * 32, cur ^ 1);
#pragma unroll
    for (int mb = 0; mb < 2; mb++)
#pragma unroll
      for (int nb = 0; nb < 4; nb++) {
        acc[mb][nb] = __builtin_amdgcn_mfma_f32_16x16x32_bf16(fAh[cur][mb], fBh[cur][nb], acc[mb][nb], 0, 0, 0);
        acc[mb][nb] = __builtin_amdgcn_mfma_f32_16x16x32_bf16(fAh[cur][mb], fBl[cur][nb], acc[mb][nb], 0, 0, 0);
        acc[mb][nb] = __builtin_amdgcn_mfma_f32_16x16x32_bf16(fAl[cur][mb], fBh[cur][nb], acc[mb][nb], 0, 0, 0);
      }
  }

#pragma unroll
  for (int mb = 0; mb < 2; mb++)
#pragma unroll
    for (int nb = 0; nb < 4; nb++) {
      int col = j0 + wx * 64 + nb * 16 + m;
#pragma unroll
      for (int p = 0; p < 4; p++) {
        int row = i0 + wy * 32 + mb * 16 + quad * 4 + p;
        float v = 2.f * acc[mb][nb][p] - (row == col ? 1.f : 0.f);
        S2h[(size_t)row * Nn + col] = bf_rne(v);
      }
    }
}

// ---------- Wt prep (split hi/lo) ----------
__global__ __launch_bounds__(256) void k_prep_wt(const float* __restrict__ W, int Csrc,
                                                 int ncol, u16* __restrict__ Wh,
                                                 u16* __restrict__ Wl) {
  int idx = blockIdx.x * 256 + threadIdx.x;
  if (idx >= ncol * KP) return;
  int n = idx / KP, kp = idx % KP;
  int chunk = kp / Cc, c = kp % Cc;
  float v = 0.f;
  if (kp < 3 * Cc && c < Csrc) v = W[((size_t)chunk * Csrc + c) * ncol + n];
  u16 h, l;
  split_bf(v, h, l);
  Wh[idx] = h; Wl[idx] = l;
}

// ---------- fill enc: rid = b*Nn + n ----------
__global__ __launch_bounds__(256) void k_fill_enc(const float* __restrict__ x,
                                                  u16* __restrict__ XAh,
                                                  u16* __restrict__ Xth, int t) {
  int idx = blockIdx.x * 256 + threadIdx.x;
  if (idx >= NB) return;
  int n = idx & (Nn - 1), b = idx >> 10;
  u16 h = bf_rne(x[(size_t)b * TN + t * Nn + n]);
  XAh[(size_t)idx * SA] = h;
  Xth[(size_t)b * Cc * Nn + n] = h;
}

// ---------- dec init ----------
__global__ __launch_bounds__(256) void k_dec_init(const float* __restrict__ x,
                                                  const float* __restrict__ ycov,
                                                  u16* __restrict__ XAh,
                                                  u16* __restrict__ Xth) {
  int idx = blockIdx.x * 256 + threadIdx.x;
  if (idx >= NB) return;
  int n = idx & (Nn - 1), b = idx >> 10;
  u16 h0 = bf_rne(x[(size_t)b * TN + (size_t)(Tc - 1) * Nn + n]);
  u16 h1 = bf_rne(ycov[(size_t)b * TN + n]);
  XAh[(size_t)idx * SA] = h0;
  XAh[(size_t)idx * SA + 1] = h1;
  Xth[((size_t)b * Cc) * Nn + n] = h0;
  Xth[((size_t)b * Cc + 1) * Nn + n] = h1;
}

// ---------- ygemm: Y1 = S1@X, Y2 = S2@X. ----------
// Direct-fragment (s2_mfma structure): NO LDS, NO barriers. Each lane loads its
// MFMA fragments straight from global (K-contiguous 16B); S re-reads are L2-local
// to the XCD (blk&7 -> i0 cluster), X re-reads L3-served. Grid 264 = machine-filling.
__global__ __launch_bounds__(256) void k_ygemm(const u16* __restrict__ S1h,
                                               const u16* __restrict__ S2h,
                                               const u16* __restrict__ Xth,
                                               u16* __restrict__ XA) {
  const int tid = threadIdx.x;
  const int wave = tid >> 6, lane = tid & 63;
  const int blk = blockIdx.x;
  const int i0 = (blk & 7) * 128;
  const int j0 = (blk >> 3) * 128;
  const int wy = wave >> 1, wx = wave & 1;
  const int m = lane & 15, quad = lane >> 4;

  const size_t aoff = (size_t)(i0 + wy * 64 + m) * Nn + quad * 8;
  const size_t boff = (size_t)(j0 + wx * 64 + m) * Nn + quad * 8;

  f32x4 acc1[4][4], acc2[4][4];
  f32x4 z4 = {0.f, 0.f, 0.f, 0.f};
#pragma unroll
  for (int a = 0; a < 4; a++)
#pragma unroll
    for (int q = 0; q < 4; q++) { acc1[a][q] = z4; acc2[a][q] = z4; }

  for (int k0 = 0; k0 < Nn; k0 += 32) {
    bf16x8 a1[4], a2[4], bfr[4];
#pragma unroll
    for (int nb = 0; nb < 4; nb++)
      bfr[nb] = ldfrag(Xth + boff + (size_t)nb * 16 * Nn + k0);
#pragma unroll
    for (int mb = 0; mb < 4; mb++) {
      a1[mb] = ldfrag(S1h + aoff + (size_t)mb * 16 * Nn + k0);
      a2[mb] = ldfrag(S2h + aoff + (size_t)mb * 16 * Nn + k0);
    }
#pragma unroll
    for (int mb = 0; mb < 4; mb++)
#pragma unroll
      for (int nb = 0; nb < 4; nb++) {
        acc1[mb][nb] = __builtin_amdgcn_mfma_f32_16x16x32_bf16(a1[mb], bfr[nb], acc1[mb][nb], 0, 0, 0);
        acc2[mb][nb] = __builtin_amdgcn_mfma_f32_16x16x32_bf16(a2[mb], bfr[nb], acc2[mb][nb], 0, 0, 0);
      }
  }

  // epilogue: row = n, col = (bb, cc); XA row rid = bb*Nn + n
#pragma unroll
  for (int mb = 0; mb < 4; mb++)
#pragma unroll
    for (int nb = 0; nb < 4; nb++) {
      int col = j0 + wx * 64 + nb * 16 + m;
      int bb = col / Cc, cc = col % Cc;
#pragma unroll
      for (int p = 0; p < 4; p++) {
        int n = i0 + wy * 64 + mb * 16 + quad * 4 + p;
        size_t base = ((size_t)bb * Nn + n) * SA;
        XA[base + 66 + cc] = bf_rne(acc1[mb][nb][p]);
        XA[base + 132 + cc] = bf_rne(acc2[mb][nb][p]);
      }
    }
}

// ---------- gate: sigmoid(XA@W^T+b); A single bf16, W split 2-term ----------
// Direct-fragment: no LDS/barriers. A rows exclusive per wave (2x L2-absorbed
// re-read across wx); W fragments L2-resident across all 512 blocks.
__global__ __launch_bounds__(256) void k_gate(const u16* __restrict__ XA,
                                              const u16* __restrict__ Wh, const u16* __restrict__ Wl,
                                              const float* __restrict__ bias,
                                              const float* __restrict__ hst,
                                              u16* __restrict__ Rb,
                                              u16* __restrict__ XAo,
                                              u16* __restrict__ Xth, int off) {
  const int tid = threadIdx.x;
  const int wave = tid >> 6, lane = tid & 63;
  const int r0 = blockIdx.x * 128;
  const int wy = wave >> 1, wx = wave & 1;
  const int m = lane & 15, quad = lane >> 4;

  const size_t aoff = (size_t)(r0 + wy * 64 + m) * SA + quad * 8;
  const size_t boff = (size_t)(wx * 64 + m) * KP + quad * 8;

  f32x4 acc[4][4];
  f32x4 z4 = {0.f, 0.f, 0.f, 0.f};
#pragma unroll
  for (int a = 0; a < 4; a++)
#pragma unroll
    for (int q = 0; q < 4; q++) acc[a][q] = z4;

  for (int kt = 0; kt < 7; kt++) {
    int k0 = kt * 32;
    bf16x8 af[4], bh[4], bl[4];
#pragma unroll
    for (int mb = 0; mb < 4; mb++)
      af[mb] = ldfrag(XA + aoff + (size_t)mb * 16 * SA + k0);
#pragma unroll
    for (int nb = 0; nb < 4; nb++) {
      bh[nb] = ldfrag(Wh + boff + (size_t)nb * 16 * KP + k0);
      bl[nb] = ldfrag(Wl + boff + (size_t)nb * 16 * KP + k0);
    }
#pragma unroll
    for (int mb = 0; mb < 4; mb++)
#pragma unroll
      for (int nb = 0; nb < 4; nb++) {
        acc[mb][nb] = __builtin_amdgcn_mfma_f32_16x16x32_bf16(af[mb], bh[nb], acc[mb][nb], 0, 0, 0);
        acc[mb][nb] = __builtin_amdgcn_mfma_f32_16x16x32_bf16(af[mb], bl[nb], acc[mb][nb], 0, 0, 0);
      }
  }

#pragma unroll
  for (int mb = 0; mb < 4; mb++)
#pragma unroll
    for (int nb = 0; nb < 4; nb++) {
      int col = wx * 64 + nb * 16 + m;
      float bv = bias[col];
      int rid0 = r0 + wy * 64 + mb * 16 + quad * 4;
      if (col < 64) {
        u16x4 pk;
#pragma unroll
        for (int p = 0; p < 4; p++) {
          int rid = rid0 + p;
          float sg = 1.f / (1.f + expf(-(acc[mb][nb][p] + bv)));
          float v = sg * hst[(size_t)rid * 64 + col];
          u16 vh = bf_rne(v);
          XAo[(size_t)rid * SA + off + col] = vh;
          pk[p] = vh;
        }
        int n0 = rid0 & (Nn - 1), b = rid0 >> 10;
        *(u16x4*)&Xth[((size_t)b * Cc + off + col) * Nn + n0] = pk;
      } else {
#pragma unroll
        for (int p = 0; p < 4; p++) {
          int rid = rid0 + p;
          float sg = 1.f / (1.f + expf(-(acc[mb][nb][p] + bv)));
          Rb[(size_t)rid * 64 + col - 64] = bf_rne(sg);
        }
      }
    }
}

// ---------- update: hc=tanh(XA@Wu^T+b); h=r*h+(1-r)*hc; optional enc-fill of x[tnext] ----------
// Direct-fragment: no LDS/barriers.
__global__ __launch_bounds__(256) void k_upd(const u16* __restrict__ XA,
                                             const u16* __restrict__ Wh, const u16* __restrict__ Wl,
                                             const float* __restrict__ bias,
                                             const u16* __restrict__ Rb,
                                             float* __restrict__ h,
                                             u16* __restrict__ XAo,
                                             u16* __restrict__ Xth,
                                             const float* __restrict__ xsrc, int tnext,
                                             int off_next) {
  const int tid = threadIdx.x;
  const int wave = tid >> 6, lane = tid & 63;
  const int r0 = blockIdx.x * 128;
  const int wy = wave >> 1, wx = wave & 1;
  const int m = lane & 15, quad = lane >> 4;

  const size_t aoff = (size_t)(r0 + wy * 64 + m) * SA + quad * 8;
  const size_t boff = (size_t)(wx * 32 + m) * KP + quad * 8;

  f32x4 acc[4][2];
  f32x4 z4 = {0.f, 0.f, 0.f, 0.f};
#pragma unroll
  for (int a = 0; a < 4; a++) { acc[a][0] = z4; acc[a][1] = z4; }

  for (int kt = 0; kt < 7; kt++) {
    int k0 = kt * 32;
    bf16x8 af[4], bh[2], bl[2];
#pragma unroll
    for (int mb = 0; mb < 4; mb++)
      af[mb] = ldfrag(XA + aoff + (size_t)mb * 16 * SA + k0);
#pragma unroll
    for (int nb = 0; nb < 2; nb++) {
      bh[nb] = ldfrag(Wh + boff + (size_t)nb * 16 * KP + k0);
      bl[nb] = ldfrag(Wl + boff + (size_t)nb * 16 * KP + k0);
    }
#pragma unroll
    for (int mb = 0; mb < 4; mb++)
#pragma unroll
      for (int nb = 0; nb < 2; nb++) {
        acc[mb][nb] = __builtin_amdgcn_mfma_f32_16x16x32_bf16(af[mb], bh[nb], acc[mb][nb], 0, 0, 0);
        acc[mb][nb] = __builtin_amdgcn_mfma_f32_16x16x32_bf16(af[mb], bl[nb], acc[mb][nb], 0, 0, 0);
      }
  }

#pragma unroll
  for (int mb = 0; mb < 4; mb++)
#pragma unroll
    for (int nb = 0; nb < 2; nb++) {
      int col = wx * 32 + nb * 16 + m;
      float bv = bias[col];
      int rid0 = r0 + wy * 64 + mb * 16 + quad * 4;
      u16x4 pk;
#pragma unroll
      for (int p = 0; p < 4; p++) {
        int rid = rid0 + p;
        float hc = tanhf(acc[mb][nb][p] + bv);
        size_t idx = (size_t)rid * 64 + col;
        float rr = bf_to_f(Rb[idx]);
        float hn = rr * h[idx] + (1.f - rr) * hc;
        h[idx] = hn;
        u16 vh = bf_rne(hn);
        XAo[(size_t)rid * SA + off_next + col] = vh;
        pk[p] = vh;
      }
      int n0 = rid0 & (Nn - 1), b = rid0 >> 10;
      *(u16x4*)&Xth[((size_t)b * Cc + off_next + col) * Nn + n0] = pk;
      if (col == 0 && xsrc != nullptr) {
        u16x4 xk;
#pragma unroll
        for (int p = 0; p < 4; p++) {
          int rid = rid0 + p;
          int n = rid & (Nn - 1);
          u16 xv = bf_rne(xsrc[(size_t)b * TN + (size_t)tnext * Nn + n]);
          XAo[(size_t)rid * SA] = xv;
          xk[p] = xv;
        }
        *(u16x4*)&Xth[((size_t)b * Cc) * Nn + n0] = xk;
      }
    }
}

// ---------- de = h @ FC_E, split output ----------
__global__ __launch_bounds__(256) void k_de(const float* __restrict__ h,
                                            const float* __restrict__ fc,
                                            u16* __restrict__ Dh, u16* __restrict__ Dl) {
  __shared__ float fcs[Hc * Ec];
  for (int j = threadIdx.x; j < Hc * Ec; j += 256) fcs[j] = fc[j];
  __syncthreads();
  int idx = blockIdx.x * 256 + threadIdx.x;
  if (idx >= Nn * KD) return;
  int n = idx / KD;
  int rem = idx % KD;
  int b = rem / Ec, e = rem % Ec;
  const float* hp = h + ((size_t)b * Nn + n) * Hc;
  float acc = 0.f;
#pragma unroll 8
  for (int hh = 0; hh < Hc; hh++) acc = fmaf(hp[hh], fcs[hh * Ec + e], acc);
  u16 vh, vl;
  split_bf(acc, vh, vl);
  Dh[idx] = vh; Dl[idx] = vl;
}

// ---------- proj + fill next dec step ----------
__global__ __launch_bounds__(256) void k_proj_fill(const float* __restrict__ h,
                                                   const float* __restrict__ pw,
                                                   const float* __restrict__ pb,
                                                   const float* __restrict__ ycov,
                                                   u16* __restrict__ XAh,
                                                   u16* __restrict__ Xth,
                                                   float* __restrict__ out, int t) {
  int idx = blockIdx.x * 256 + threadIdx.x;
  if (idx >= NB) return;
  int n = idx & (Nn - 1), b = idx >> 10;
  const float* hp = h + (size_t)idx * Hc;
  float acc = pb[0];
#pragma unroll 8
  for (int i = 0; i < Hc; i++) acc = fmaf(hp[i], pw[i], acc);
  out[(size_t)b * TN + (size_t)t * Nn + n] = acc;
  if (t + 1 < Tc) {
    u16 h0 = bf_rne(acc);
    u16 h1 = bf_rne(ycov[(size_t)b * TN + (size_t)(t + 1) * Nn + n]);
    XAh[(size_t)idx * SA] = h0;
    XAh[(size_t)idx * SA + 1] = h1;
    Xth[((size_t)b * Cc) * Nn + n] = h0;
    Xth[((size_t)b * Cc + 1) * Nn + n] = h1;
  }
}

extern "C" void kernel_launch(void* const* d_in, const int* in_sizes, int n_in,
                              void* d_out, int out_size, void* d_ws, size_t ws_size,
                              hipStream_t stream) {
  (void)in_sizes; (void)n_in; (void)out_size; (void)ws_size;
  const float* x    = (const float*)d_in[0];
  const float* ycov = (const float*)d_in[1];
  const float* emb  = (const float*)d_in[2];
  const float* fce  = (const float*)d_in[3];
  const float* egw  = (const float*)d_in[4];
  const float* egb  = (const float*)d_in[5];
  const float* euw  = (const float*)d_in[6];
  const float* eub  = (const float*)d_in[7];
  const float* dgw  = (const float*)d_in[8];
  const float* dgb  = (const float*)d_in[9];
  const float* duw  = (const float*)d_in[10];
  const float* dub  = (const float*)d_in[11];
  const float* pw   = (const float*)d_in[12];
  const float* pb   = (const float*)d_in[13];
  float* out = (float*)d_out;

  char* wsb = (char*)d_ws;
  size_t off = 0;
  auto alloc = [&](size_t bytes) {
    void* p = wsb + off;
    off = (off + bytes + 255) & ~(size_t)255;
    return p;
  };
  float* Gf = (float*)alloc((size_t)Nn * Nn * 4);
  u16* S1h = (u16*)alloc((size_t)Nn * Nn * 2);
  u16* S1l = (u16*)alloc((size_t)Nn * Nn * 2);
  u16* S2h = (u16*)alloc((size_t)Nn * Nn * 2);
  u16* Sth = (u16*)alloc((size_t)Nn * Nn * 2);
  u16* Stl = (u16*)alloc((size_t)Nn * Nn * 2);
  float* Hst = (float*)alloc((size_t)NB * Hc * 4);
  u16* XAh = (u16*)alloc((size_t)(NB + 4) * SA * 2);
  u16* Xth = (u16*)alloc((size_t)Bc * Cc * Nn * 2);
  u16* Rb = (u16*)alloc((size_t)NB * Hc * 2);
  u16* DEh = (u16*)alloc((size_t)Nn * KD * 2);
  u16* DEl = (u16*)alloc((size_t)Nn * KD * 2);
  u16* WgeH = (u16*)alloc(128 * KP * 2); u16* WgeL = (u16*)alloc(128 * KP * 2);
  u16* WueH = (u16*)alloc(64 * KP * 2);  u16* WueL = (u16*)alloc(64 * KP * 2);
  u16* WgdH = (u16*)alloc(128 * KP * 2); u16* WgdL = (u16*)alloc(128 * KP * 2);
  u16* WudH = (u16*)alloc(64 * KP * 2);  u16* WudL = (u16*)alloc(64 * KP * 2);

  hipMemsetAsync(Hst, 0, (size_t)NB * Hc * 4, stream);
  hipMemsetAsync(XAh, 0, (size_t)(NB + 4) * SA * 2, stream);
  hipMemsetAsync(Xth, 0, (size_t)Bc * Cc * Nn * 2, stream);

  k_prep_wt<<<(128 * KP + 255) / 256, 256, 0, stream>>>(egw, 65, 128, WgeH, WgeL);
  k_prep_wt<<<(64 * KP + 255) / 256, 256, 0, stream>>>(euw, 65, 64, WueH, WueL);
  k_prep_wt<<<(128 * KP + 255) / 256, 256, 0, stream>>>(dgw, 66, 128, WgdH, WgdL);
  k_prep_wt<<<(64 * KP + 255) / 256, 256, 0, stream>>>(duw, 66, 64, WudH, WudL);

  // encoder supports
  k_gram<<<dim3(16, 16), 256, 0, stream>>>(emb, Ec, Gf);
  k_softmax<<<Nn, 256, 0, stream>>>(Gf, S1h, S1l);
  k_tr2<<<dim3(16, 16), 256, 0, stream>>>(S1h, S1l, Sth, Stl);
  k_s2_mfma<<<128, 256, 0, stream>>>(S1h, S1l, Sth, Stl, S2h);

  const int gNB = NB / 256;

  k_fill_enc<<<gNB, 256, 0, stream>>>(x, XAh, Xth, 0);
  for (int t = 0; t < Tc; t++) {
    k_ygemm<<<264, 256, 0, stream>>>(S1h, S2h, Xth, XAh);
    k_gate<<<512, 256, 0, stream>>>(XAh, WgeH, WgeL, egb, Hst, Rb, XAh, Xth, 1);
    k_ygemm<<<264, 256, 0, stream>>>(S1h, S2h, Xth, XAh);
    k_upd<<<512, 256, 0, stream>>>(XAh, WueH, WueL, eub, Rb, Hst, XAh, Xth,
                                   (t + 1 < Tc) ? x : nullptr, t + 1,
                                   (t == Tc - 1) ? 2 : 1);
  }

  // decoder supports
  k_de<<<(Nn * KD + 255) / 256, 256, 0, stream>>>(Hst, fce, DEh, DEl);
  k_gram_mfma<<<dim3(8, 16), 256, 0, stream>>>(DEh, DEl, Gf);
  k_softmax<<<Nn, 256, 0, stream>>>(Gf, S1h, S1l);
  k_tr2<<<dim3(16, 16), 256, 0, stream>>>(S1h, S1l, Sth, Stl);
  k_s2_mfma<<<128, 256, 0, stream>>>(S1h, S1l, Sth, Stl, S2h);
  k_dec_init<<<gNB, 256, 0, stream>>>(x, ycov, XAh, Xth);

  for (int t = 0; t < Tc; t++) {
    k_ygemm<<<264, 256, 0, stream>>>(S1h, S2h, Xth, XAh);
    k_gate<<<512, 256, 0, stream>>>(XAh, WgdH, WgdL, dgb, Hst, Rb, XAh, Xth, 2);
    k_ygemm<<<264, 256, 0, stream>>>(S1h, S2h, Xth, XAh);
    k_upd<<<512, 256, 0, stream>>>(XAh, WudH, WudL, dub, Rb, Hst, XAh, Xth,
                                   nullptr, 0, 2);
    k_proj_fill<<<gNB, 256, 0, stream>>>(Hst, pw, pb, ycov, XAh, Xth, out, t);
  }
}

// Round 4
// 3371.744 us; speedup vs baseline: 1.8970x; 1.8970x over previous
//
#include <hip/hip_runtime.h>
#include <math.h>

typedef __attribute__((ext_vector_type(8))) short bf16x8;
typedef __attribute__((ext_vector_type(4))) float f32x4;
typedef unsigned short u16;

namespace {
constexpr int Bc = 64, Tc = 12, Nn = 1024, Hc = 64, Ec = 10;
constexpr int NB = Nn * Bc;  // 65536
constexpr int Cc = 66;       // unified channel count (enc uses 65, col 65 zeroed)
constexpr int SA = 208;      // XA row stride ([X(66)|Y1(66)|Y2(66)|pad10])
constexpr int KP = 224;      // padded K for gate/update GEMMs (7 x 32)
constexpr int KD = Bc * Ec;  // 640, dec gram K
constexpr int TN = Tc * Nn;  // 12288
constexpr int NXE = 768;     // enc precompute cols: 12t x 64b
constexpr int NXD = 896;     // dec precompute cols: go0(64) + 12t x 64b + pad
// Row index convention: rid = b*Nn + n  (b outer, n inner).
}

#define SWZ(r) (((r) >> 1) & 3)
#define SW8(r) ((r) & 7)

__device__ __forceinline__ void gld16(const void* g, void* l) {
  __builtin_amdgcn_global_load_lds(
      (const __attribute__((address_space(1))) void*)g,
      (__attribute__((address_space(3))) void*)l, 16, 0, 0);
}

__device__ __forceinline__ void split_bf(float v, u16& h, u16& l) {
  unsigned u = __float_as_uint(v);
  unsigned hu = (u + 0x7FFFu + ((u >> 16) & 1u)) & 0xFFFF0000u;
  h = (u16)(hu >> 16);
  float r = v - __uint_as_float(hu);
  unsigned u2 = __float_as_uint(r);
  l = (u16)((u2 + 0x7FFFu + ((u2 >> 16) & 1u)) >> 16);
}
__device__ __forceinline__ u16 bf_rne(float v) {
  unsigned u = __float_as_uint(v);
  return (u16)((u + 0x7FFFu + ((u >> 16) & 1u)) >> 16);
}
__device__ __forceinline__ float bf_to_f(u16 v) {
  return __uint_as_float(((unsigned)v) << 16);
}
__device__ __forceinline__ bf16x8 ldfrag(const u16* p) { return *(const bf16x8*)p; }

// ---------- enc gram: G = emb @ emb^T (Kd small, fp32) ----------
__global__ __launch_bounds__(256) void k_gram(const float* __restrict__ in, int Kd,
                                              float* __restrict__ G) {
  __shared__ float At[16][64];
  __shared__ float Bt[16][64];
  int i0 = blockIdx.y * 64, j0 = blockIdx.x * 64;
  int tx = threadIdx.x & 15, ty = threadIdx.x >> 4;
  float acc[4][4] = {};
  for (int k0 = 0; k0 < Kd; k0 += 16) {
    for (int u = threadIdx.x; u < 1024; u += 256) {
      int i = u >> 4, k = u & 15;
      At[k][i] = (k0 + k < Kd) ? in[(size_t)(i0 + i) * Kd + k0 + k] : 0.f;
    }
    for (int u = threadIdx.x; u < 1024; u += 256) {
      int j = u >> 4, k = u & 15;
      Bt[k][j] = (k0 + k < Kd) ? in[(size_t)(j0 + j) * Kd + k0 + k] : 0.f;
    }
    __syncthreads();
#pragma unroll
    for (int kk = 0; kk < 16; kk++) {
      float a[4], b[4];
#pragma unroll
      for (int p = 0; p < 4; p++) a[p] = At[kk][ty * 4 + p];
#pragma unroll
      for (int q = 0; q < 4; q++) b[q] = Bt[kk][tx * 4 + q];
#pragma unroll
      for (int p = 0; p < 4; p++)
#pragma unroll
        for (int q = 0; q < 4; q++) acc[p][q] = fmaf(a[p], b[q], acc[p][q]);
    }
    __syncthreads();
  }
  for (int p = 0; p < 4; p++)
    for (int q = 0; q < 4; q++)
      G[(size_t)(i0 + ty * 4 + p) * Nn + j0 + tx * 4 + q] = acc[p][q];
}

// ---------- dec gram via split-MFMA: G = DE @ DE^T ----------
__global__ __launch_bounds__(256) void k_gram_mfma(const u16* __restrict__ Dh,
                                                   const u16* __restrict__ Dl,
                                                   float* __restrict__ G) {
  __shared__ u16 lds[12288];
  const int tid = threadIdx.x;
  const int wave = tid >> 6, lane = tid & 63;
  const int i0 = blockIdx.y * 64;
  const int j0 = blockIdx.x * 128;
  const int wy = wave >> 1, wx = wave & 1;
  const int m = lane & 15, quad = lane >> 4;

  f32x4 acc[2][4];
  f32x4 z4 = {0.f, 0.f, 0.f, 0.f};
#pragma unroll
  for (int a = 0; a < 2; a++)
#pragma unroll
    for (int q = 0; q < 4; q++) acc[a][q] = z4;

  const int ar = tid >> 2;
  const int akc = (tid & 3) ^ SWZ(ar);

  for (int k0 = 0; k0 < KD; k0 += 32) {
    gld16(Dh + (size_t)(i0 + ar) * KD + k0 + akc * 8, &lds[wave * 512]);
    gld16(Dl + (size_t)(i0 + ar) * KD + k0 + akc * 8, &lds[2048 + wave * 512]);
#pragma unroll
    for (int p = 0; p < 2; p++) {
      int r = p * 64 + (tid >> 2);
      int kc = (tid & 3) ^ SWZ(r);
      gld16(Dh + (size_t)(j0 + r) * KD + k0 + kc * 8, &lds[4096 + p * 2048 + wave * 512]);
      gld16(Dl + (size_t)(j0 + r) * KD + k0 + kc * 8, &lds[8192 + p * 2048 + wave * 512]);
    }
    __syncthreads();

    bf16x8 ah[2], al[2], bh[4], bl[4];
#pragma unroll
    for (int mb = 0; mb < 2; mb++) {
      int r = wy * 32 + mb * 16 + m;
      int ci = r * 4 + (quad ^ SWZ(r));
      ah[mb] = *(const bf16x8*)&lds[ci * 8];
      al[mb] = *(const bf16x8*)&lds[2048 + ci * 8];
    }
#pragma unroll
    for (int nb = 0; nb < 4; nb++) {
      int rj = wx * 64 + nb * 16 + m;
      int cj = rj * 4 + (quad ^ SWZ(rj));
      bh[nb] = *(const bf16x8*)&lds[4096 + cj * 8];
      bl[nb] = *(const bf16x8*)&lds[8192 + cj * 8];
    }
#pragma unroll
    for (int mb = 0; mb < 2; mb++)
#pragma unroll
      for (int nb = 0; nb < 4; nb++) {
        acc[mb][nb] = __builtin_amdgcn_mfma_f32_16x16x32_bf16(ah[mb], bh[nb], acc[mb][nb], 0, 0, 0);
        acc[mb][nb] = __builtin_amdgcn_mfma_f32_16x16x32_bf16(ah[mb], bl[nb], acc[mb][nb], 0, 0, 0);
        acc[mb][nb] = __builtin_amdgcn_mfma_f32_16x16x32_bf16(al[mb], bh[nb], acc[mb][nb], 0, 0, 0);
      }
    __syncthreads();
  }

#pragma unroll
  for (int mb = 0; mb < 2; mb++)
#pragma unroll
    for (int nb = 0; nb < 4; nb++) {
      int col = j0 + wx * 64 + nb * 16 + m;
#pragma unroll
      for (int p = 0; p < 4; p++) {
        int row = i0 + wy * 32 + mb * 16 + quad * 4 + p;
        G[(size_t)row * Nn + col] = acc[mb][nb][p];
      }
    }
}

// ---------- S = row_softmax(relu(G)) -> split to S1h/S1l ----------
__global__ __launch_bounds__(256) void k_softmax(const float* __restrict__ G,
                                                 u16* __restrict__ S1h,
                                                 u16* __restrict__ S1l) {
  __shared__ float sred[8];
  int n = blockIdx.x;
  float v[4];
#pragma unroll
  for (int i = 0; i < 4; i++)
    v[i] = fmaxf(G[(size_t)n * Nn + threadIdx.x + i * 256], 0.f);
  float mx = fmaxf(fmaxf(v[0], v[1]), fmaxf(v[2], v[3]));
  for (int off = 32; off > 0; off >>= 1) mx = fmaxf(mx, __shfl_down(mx, off));
  if ((threadIdx.x & 63) == 0) sred[threadIdx.x >> 6] = mx;
  __syncthreads();
  float rmax = fmaxf(fmaxf(sred[0], sred[1]), fmaxf(sred[2], sred[3]));
  float s = 0.f;
#pragma unroll
  for (int i = 0; i < 4; i++) { v[i] = expf(v[i] - rmax); s += v[i]; }
  for (int off = 32; off > 0; off >>= 1) s += __shfl_down(s, off);
  if ((threadIdx.x & 63) == 0) sred[4 + (threadIdx.x >> 6)] = s;
  __syncthreads();
  float inv = 1.f / (sred[4] + sred[5] + sred[6] + sred[7]);
#pragma unroll
  for (int i = 0; i < 4; i++) {
    u16 h, l;
    split_bf(v[i] * inv, h, l);
    size_t a = (size_t)n * Nn + threadIdx.x + i * 256;
    S1h[a] = h; S1l[a] = l;
  }
}

// ---------- transpose S1h/S1l -> Sth/Stl ----------
__global__ __launch_bounds__(256) void k_tr2(const u16* __restrict__ Ah,
                                             const u16* __restrict__ Al,
                                             u16* __restrict__ Th, u16* __restrict__ Tl) {
  __shared__ u16 sm[64][72];
  int i0 = blockIdx.y * 64, j0 = blockIdx.x * 64;
  int tid = threadIdx.x;
  for (int pass = 0; pass < 2; pass++) {
    const u16* src = pass ? Al : Ah;
    u16* dst = pass ? Tl : Th;
    for (int u = tid; u < 4096; u += 256) {
      int i = u >> 6, c = u & 63;
      sm[i][c] = src[(size_t)(i0 + i) * Nn + j0 + c];
    }
    __syncthreads();
    for (int u = tid; u < 4096; u += 256) {
      int c = u >> 6, i = u & 63;
      dst[(size_t)(j0 + c) * Nn + i0 + i] = sm[i][c];
    }
    __syncthreads();
  }
}

// ---------- S2 = 2*S@S - I via direct-fragment split MFMA (3-term, bf16 out) ----------
__global__ __launch_bounds__(256) void k_s2_mfma(const u16* __restrict__ S1h,
                                                 const u16* __restrict__ S1l,
                                                 const u16* __restrict__ Sth,
                                                 const u16* __restrict__ Stl,
                                                 u16* __restrict__ S2h) {
  const int tid = threadIdx.x;
  const int wave = tid >> 6, lane = tid & 63;
  const int blk = blockIdx.x;
  const int s = blk >> 3;
  const int i0 = ((blk & 7) * 2 + (s & 1)) * 64;
  const int j0 = (s >> 1) * 128;
  const int wy = wave >> 1, wx = wave & 1;
  const int m = lane & 15, quad = lane >> 4;

  const size_t aoff = (size_t)(i0 + wy * 32 + m) * Nn + quad * 8;
  const size_t boff = (size_t)(j0 + wx * 64 + m) * Nn + quad * 8;

  f32x4 acc[2][4];
  f32x4 z4 = {0.f, 0.f, 0.f, 0.f};
#pragma unroll
  for (int a = 0; a < 2; a++)
#pragma unroll
    for (int q = 0; q < 4; q++) acc[a][q] = z4;

  bf16x8 fAh[2][2], fAl[2][2], fBh[2][4], fBl[2][4];
  auto ld = [&](int k0, int sb) {
#pragma unroll
    for (int mb = 0; mb < 2; mb++) {
      fAh[sb][mb] = ldfrag(S1h + aoff + (size_t)mb * 16 * Nn + k0);
      fAl[sb][mb] = ldfrag(S1l + aoff + (size_t)mb * 16 * Nn + k0);
    }
#pragma unroll
    for (int nb = 0; nb < 4; nb++) {
      fBh[sb][nb] = ldfrag(Sth + boff + (size_t)nb * 16 * Nn + k0);
      fBl[sb][nb] = ldfrag(Stl + boff + (size_t)nb * 16 * Nn + k0);
    }
  };
  ld(0, 0);
#pragma unroll 2
  for (int kt = 0; kt < 32; kt++) {
    int cur = kt & 1;
    if (kt < 31) ld((kt + 1) * 32, cur ^ 1);
#pragma unroll
    for (int mb = 0; mb < 2; mb++)
#pragma unroll
      for (int nb = 0; nb < 4; nb++) {
        acc[mb][nb] = __builtin_amdgcn_mfma_f32_16x16x32_bf16(fAh[cur][mb], fBh[cur][nb], acc[mb][nb], 0, 0, 0);
        acc[mb][nb] = __builtin_amdgcn_mfma_f32_16x16x32_bf16(fAh[cur][mb], fBl[cur][nb], acc[mb][nb], 0, 0, 0);
        acc[mb][nb] = __builtin_amdgcn_mfma_f32_16x16x32_bf16(fAl[cur][mb], fBh[cur][nb], acc[mb][nb], 0, 0, 0);
      }
  }

#pragma unroll
  for (int mb = 0; mb < 2; mb++)
#pragma unroll
    for (int nb = 0; nb < 4; nb++) {
      int col = j0 + wx * 64 + nb * 16 + m;
#pragma unroll
      for (int p = 0; p < 4; p++) {
        int row = i0 + wy * 32 + mb * 16 + quad * 4 + p;
        float v = 2.f * acc[mb][nb][p] - (row == col ? 1.f : 0.f);
        S2h[(size_t)row * Nn + col] = bf_rne(v);
      }
    }
}

// ---------- Wt prep (split hi/lo) ----------
__global__ __launch_bounds__(256) void k_prep_wt(const float* __restrict__ W, int Csrc,
                                                 int ncol, u16* __restrict__ Wh,
                                                 u16* __restrict__ Wl) {
  int idx = blockIdx.x * 256 + threadIdx.x;
  if (idx >= ncol * KP) return;
  int n = idx / KP, kp = idx % KP;
  int chunk = kp / Cc, c = kp % Cc;
  float v = 0.f;
  if (kp < 3 * Cc && c < Csrc) v = W[((size_t)chunk * Csrc + c) * ncol + n];
  u16 h, l;
  split_bf(v, h, l);
  Wh[idx] = h; Wl[idx] = l;
}

// ---------- build precompute B operands (bf16, [col][n]) ----------
__global__ __launch_bounds__(256) void k_prep_xe(const float* __restrict__ x,
                                                 u16* __restrict__ Xx) {
  int idx = blockIdx.x * 256 + threadIdx.x;
  if (idx >= NXE * Nn) return;
  int col = idx >> 10, n = idx & (Nn - 1);
  int t = col >> 6, b = col & 63;
  Xx[idx] = bf_rne(x[(size_t)b * TN + (size_t)t * Nn + n]);
}

__global__ __launch_bounds__(256) void k_prep_xd(const float* __restrict__ x,
                                                 const float* __restrict__ ycov,
                                                 u16* __restrict__ Xx) {
  int idx = blockIdx.x * 256 + threadIdx.x;
  if (idx >= NXD * Nn) return;
  int col = idx >> 10, n = idx & (Nn - 1);
  float v = 0.f;
  if (col < 64) {
    v = x[(size_t)col * TN + (size_t)(Tc - 1) * Nn + n];  // go0 = x[:, -1, :, 0]
  } else if (col < 64 + Tc * 64) {
    int t = (col - 64) >> 6, b = (col - 64) & 63;
    v = ycov[(size_t)b * TN + (size_t)t * Nn + n];
  }
  Xx[idx] = bf_rne(v);
}

// ---------- ypre: Y1 = S1@Xx, Y2 = S2@Xx (precompute of x-derived Y cols) ----------
// grid = 8 * nj blocks; i0 = blk&7, j0 = (blk>>3)*128. Same staged core as ygemm.
__global__ __launch_bounds__(256, 2) void k_ypre(const u16* __restrict__ S1h,
                                                 const u16* __restrict__ S2h,
                                                 const u16* __restrict__ Xx,
                                                 u16* __restrict__ Yo1,
                                                 u16* __restrict__ Yo2) {
  __shared__ u16 lds[24576];  // 48KB
  const int tid = threadIdx.x;
  const int wave = tid >> 6;
  const int lane = tid & 63;
  const int blk = blockIdx.x;
  const int i0 = (blk & 7) * 128;
  const int j0 = (blk >> 3) * 128;
  const int wy = wave >> 1, wx = wave & 1;
  const int m = lane & 15, quad = lane >> 4;

  f32x4 acc1[4][4], acc2[4][4];
  f32x4 z4 = {0.f, 0.f, 0.f, 0.f};
#pragma unroll
  for (int a = 0; a < 4; a++)
#pragma unroll
    for (int q = 0; q < 4; q++) { acc1[a][q] = z4; acc2[a][q] = z4; }

  for (int k0 = 0; k0 < Nn; k0 += 64) {
#pragma unroll
    for (int c = 0; c < 4; c++) {
      int ci = c * 256 + tid;
      int r = ci >> 3, kc = (ci & 7) ^ SW8(r);
      gld16(S1h + (size_t)(i0 + r) * Nn + k0 + kc * 8, &lds[c * 2048 + wave * 512]);
      gld16(S2h + (size_t)(i0 + r) * Nn + k0 + kc * 8, &lds[8192 + c * 2048 + wave * 512]);
      gld16(Xx + (size_t)(j0 + r) * Nn + k0 + kc * 8, &lds[16384 + c * 2048 + wave * 512]);
    }
    __syncthreads();

#pragma unroll
    for (int ks = 0; ks < 2; ks++) {
      bf16x8 bfr[4];
#pragma unroll
      for (int nb = 0; nb < 4; nb++) {
        int rj = wx * 64 + nb * 16 + m;
        int cj = rj * 8 + ((ks * 4 + quad) ^ SW8(rj));
        bfr[nb] = *(const bf16x8*)&lds[16384 + cj * 8];
      }
      bf16x8 a1[4], a2[4];
#pragma unroll
      for (int mb = 0; mb < 4; mb++) {
        int r = wy * 64 + mb * 16 + m;
        int ci = r * 8 + ((ks * 4 + quad) ^ SW8(r));
        a1[mb] = *(const bf16x8*)&lds[ci * 8];
        a2[mb] = *(const bf16x8*)&lds[8192 + ci * 8];
      }
#pragma unroll
      for (int mb = 0; mb < 4; mb++)
#pragma unroll
        for (int nb = 0; nb < 4; nb++) {
          acc1[mb][nb] = __builtin_amdgcn_mfma_f32_16x16x32_bf16(a1[mb], bfr[nb], acc1[mb][nb], 0, 0, 0);
          acc2[mb][nb] = __builtin_amdgcn_mfma_f32_16x16x32_bf16(a2[mb], bfr[nb], acc2[mb][nb], 0, 0, 0);
        }
    }
    __syncthreads();
  }

#pragma unroll
  for (int mb = 0; mb < 4; mb++)
#pragma unroll
    for (int nb = 0; nb < 4; nb++) {
      int col = j0 + wx * 64 + nb * 16 + m;
#pragma unroll
      for (int p = 0; p < 4; p++) {
        int n = i0 + wy * 64 + mb * 16 + quad * 4 + p;
        Yo1[(size_t)col * Nn + n] = bf_rne(acc1[mb][nb][p]);
        Yo2[(size_t)col * Nn + n] = bf_rne(acc2[mb][nb][p]);
      }
    }
}

// ---------- fill enc t=0: x X-col + precomputed Y-x cols ----------
__global__ __launch_bounds__(256) void k_fill_enc(const float* __restrict__ x,
                                                  u16* __restrict__ XAh,
                                                  const u16* __restrict__ ye1,
                                                  const u16* __restrict__ ye2) {
  int idx = blockIdx.x * 256 + threadIdx.x;
  if (idx >= NB) return;
  int n = idx & (Nn - 1), b = idx >> 10;
  XAh[(size_t)idx * SA] = bf_rne(x[(size_t)b * TN + n]);
  XAh[(size_t)idx * SA + 66] = ye1[(size_t)b * Nn + n];
  XAh[(size_t)idx * SA + 132] = ye2[(size_t)b * Nn + n];
}

// ---------- dec init: go0/ycov0 X-cols + precomputed Y-x cols ----------
__global__ __launch_bounds__(256) void k_dec_init(const float* __restrict__ x,
                                                  const float* __restrict__ ycov,
                                                  u16* __restrict__ XAh,
                                                  const u16* __restrict__ yd1,
                                                  const u16* __restrict__ yd2) {
  int idx = blockIdx.x * 256 + threadIdx.x;
  if (idx >= NB) return;
  int n = idx & (Nn - 1), b = idx >> 10;
  XAh[(size_t)idx * SA] = bf_rne(x[(size_t)b * TN + (size_t)(Tc - 1) * Nn + n]);
  XAh[(size_t)idx * SA + 1] = bf_rne(ycov[(size_t)b * TN + n]);
  XAh[(size_t)idx * SA + 66] = yd1[(size_t)b * Nn + n];
  XAh[(size_t)idx * SA + 67] = yd1[(size_t)(64 + b) * Nn + n];
  XAh[(size_t)idx * SA + 132] = yd2[(size_t)b * Nn + n];
  XAh[(size_t)idx * SA + 133] = yd2[(size_t)(64 + b) * Nn + n];
}

// ---------- ygemm: Y1 = S1@Xh, Y2 = S2@Xh over 4096 h-cols. ----------
// Grid EXACTLY 256 (8 i x 32 j) -> single round, no tail. BK=64 single-buffer
// (proven baseline core). Optional epilogue derivation of the decoder go-column:
// softmax rows sum to 1  =>  S1@go = (S1@h)@pw + pb, S2@go = (S2@h)@pw + pb.
__global__ __launch_bounds__(256, 2) void k_ygemm(const u16* __restrict__ S1h,
                                                  const u16* __restrict__ S2h,
                                                  const u16* __restrict__ Xh,
                                                  u16* __restrict__ XA, int yoff,
                                                  const float* __restrict__ pw,
                                                  const float* __restrict__ pb) {
  __shared__ u16 lds[24576];  // 48KB: S1 [0,8192) | S2 [8192,16384) | Xh [16384,24576)
  const int tid = threadIdx.x;
  const int wave = tid >> 6;
  const int lane = tid & 63;
  const int blk = blockIdx.x;
  const int i0 = (blk & 7) * 128;
  const int j0 = (blk >> 3) * 128;
  const int wy = wave >> 1, wx = wave & 1;
  const int m = lane & 15, quad = lane >> 4;

  f32x4 acc1[4][4], acc2[4][4];
  f32x4 z4 = {0.f, 0.f, 0.f, 0.f};
#pragma unroll
  for (int a = 0; a < 4; a++)
#pragma unroll
    for (int q = 0; q < 4; q++) { acc1[a][q] = z4; acc2[a][q] = z4; }

  for (int k0 = 0; k0 < Nn; k0 += 64) {
#pragma unroll
    for (int c = 0; c < 4; c++) {
      int ci = c * 256 + tid;
      int r = ci >> 3, kc = (ci & 7) ^ SW8(r);
      gld16(S1h + (size_t)(i0 + r) * Nn + k0 + kc * 8, &lds[c * 2048 + wave * 512]);
      gld16(S2h + (size_t)(i0 + r) * Nn + k0 + kc * 8, &lds[8192 + c * 2048 + wave * 512]);
      gld16(Xh + (size_t)(j0 + r) * Nn + k0 + kc * 8, &lds[16384 + c * 2048 + wave * 512]);
    }
    __syncthreads();

#pragma unroll
    for (int ks = 0; ks < 2; ks++) {
      bf16x8 bfr[4];
#pragma unroll
      for (int nb = 0; nb < 4; nb++) {
        int rj = wx * 64 + nb * 16 + m;
        int cj = rj * 8 + ((ks * 4 + quad) ^ SW8(rj));
        bfr[nb] = *(const bf16x8*)&lds[16384 + cj * 8];
      }
      bf16x8 a1[4], a2[4];
#pragma unroll
      for (int mb = 0; mb < 4; mb++) {
        int r = wy * 64 + mb * 16 + m;
        int ci = r * 8 + ((ks * 4 + quad) ^ SW8(r));
        a1[mb] = *(const bf16x8*)&lds[ci * 8];
        a2[mb] = *(const bf16x8*)&lds[8192 + ci * 8];
      }
#pragma unroll
      for (int mb = 0; mb < 4; mb++)
#pragma unroll
        for (int nb = 0; nb < 4; nb++) {
          acc1[mb][nb] = __builtin_amdgcn_mfma_f32_16x16x32_bf16(a1[mb], bfr[nb], acc1[mb][nb], 0, 0, 0);
          acc2[mb][nb] = __builtin_amdgcn_mfma_f32_16x16x32_bf16(a2[mb], bfr[nb], acc2[mb][nb], 0, 0, 0);
        }
    }
    __syncthreads();
  }

  // epilogue: col -> (bb = col>>6, ch = col&63); Y cc = yoff + ch
#pragma unroll
  for (int mb = 0; mb < 4; mb++)
#pragma unroll
    for (int nb = 0; nb < 4; nb++) {
      int col = j0 + wx * 64 + nb * 16 + m;
      int bb = col >> 6, ch = col & 63;
#pragma unroll
      for (int p = 0; p < 4; p++) {
        int n = i0 + wy * 64 + mb * 16 + quad * 4 + p;
        size_t base = ((size_t)bb * Nn + n) * SA;
        XA[base + 66 + yoff + ch] = bf_rne(acc1[mb][nb][p]);
        XA[base + 132 + yoff + ch] = bf_rne(acc2[mb][nb][p]);
      }
    }

  if (pw != nullptr) {
    // derive go-column for this wave's batch from fp32 accumulators
    const int batch = (j0 >> 6) + wx;
    const float pb0 = pb[0];
    float pwv[4];
#pragma unroll
    for (int nb = 0; nb < 4; nb++) pwv[nb] = pw[nb * 16 + m];
#pragma unroll
    for (int mb = 0; mb < 4; mb++)
#pragma unroll
      for (int p = 0; p < 4; p++) {
        float s1 = 0.f, s2 = 0.f;
#pragma unroll
        for (int nb = 0; nb < 4; nb++) {
          s1 = fmaf(acc1[mb][nb][p], pwv[nb], s1);
          s2 = fmaf(acc2[mb][nb][p], pwv[nb], s2);
        }
#pragma unroll
        for (int off = 8; off > 0; off >>= 1) {
          s1 += __shfl_xor(s1, off);
          s2 += __shfl_xor(s2, off);
        }
        if (m == 0) {
          int n = i0 + wy * 64 + mb * 16 + quad * 4 + p;
          size_t base = ((size_t)batch * Nn + n) * SA;
          XA[base + 66] = bf_rne(s1 + pb0);
          XA[base + 132] = bf_rne(s2 + pb0);
        }
      }
  }
}

// ---------- gate: sigmoid(XA@W^T+b); A single bf16, W split 2-term ----------
__global__ __launch_bounds__(256) void k_gate(const u16* __restrict__ XA,
                                              const u16* __restrict__ Wh, const u16* __restrict__ Wl,
                                              const float* __restrict__ bias,
                                              const float* __restrict__ hst,
                                              u16* __restrict__ Rb,
                                              u16* __restrict__ XAo,
                                              u16* __restrict__ Xh, int off) {
  __shared__ u16 lds[12288];  // A 4096 | Wh 4096 | Wl 4096
  const int tid = threadIdx.x;
  const int wave = tid >> 6, lane = tid & 63;
  const int r0 = blockIdx.x * 128;
  const int wy = wave >> 1, wx = wave & 1;
  const int m = lane & 15, quad = lane >> 4;

  f32x4 acc[4][4];
  f32x4 z4 = {0.f, 0.f, 0.f, 0.f};
#pragma unroll
  for (int a = 0; a < 4; a++)
#pragma unroll
    for (int q = 0; q < 4; q++) acc[a][q] = z4;

  for (int kt = 0; kt < 7; kt++) {
    int k0 = kt * 32;
#pragma unroll
    for (int c = 0; c < 2; c++) {
      int ci = c * 256 + tid;
      int r = ci >> 2, kc = (ci & 3) ^ SWZ(r);
      gld16(XA + (size_t)(r0 + r) * SA + k0 + kc * 8, &lds[c * 2048 + wave * 512]);
      gld16(Wh + (size_t)r * KP + k0 + kc * 8, &lds[4096 + c * 2048 + wave * 512]);
      gld16(Wl + (size_t)r * KP + k0 + kc * 8, &lds[8192 + c * 2048 + wave * 512]);
    }
    __syncthreads();

    bf16x8 af[4], bh[4], bl[4];
#pragma unroll
    for (int mb = 0; mb < 4; mb++) {
      int r = wy * 64 + mb * 16 + m;
      int ci = r * 4 + (quad ^ SWZ(r));
      af[mb] = *(const bf16x8*)&lds[ci * 8];
    }
#pragma unroll
    for (int nb = 0; nb < 4; nb++) {
      int rj = wx * 64 + nb * 16 + m;
      int cj = rj * 4 + (quad ^ SWZ(rj));
      bh[nb] = *(const bf16x8*)&lds[4096 + cj * 8];
      bl[nb] = *(const bf16x8*)&lds[8192 + cj * 8];
    }
#pragma unroll
    for (int mb = 0; mb < 4; mb++)
#pragma unroll
      for (int nb = 0; nb < 4; nb++) {
        acc[mb][nb] = __builtin_amdgcn_mfma_f32_16x16x32_bf16(af[mb], bh[nb], acc[mb][nb], 0, 0, 0);
        acc[mb][nb] = __builtin_amdgcn_mfma_f32_16x16x32_bf16(af[mb], bl[nb], acc[mb][nb], 0, 0, 0);
      }
    __syncthreads();
  }

#pragma unroll
  for (int mb = 0; mb < 4; mb++)
#pragma unroll
    for (int nb = 0; nb < 4; nb++) {
      int col = wx * 64 + nb * 16 + m;
      float bv = bias[col];
#pragma unroll
      for (int p = 0; p < 4; p++) {
        int rid = r0 + wy * 64 + mb * 16 + quad * 4 + p;
        float sg = 1.f / (1.f + expf(-(acc[mb][nb][p] + bv)));
        if (col < 64) {
          float v = sg * hst[(size_t)rid * 64 + col];
          u16 vh = bf_rne(v);
          XAo[(size_t)rid * SA + off + col] = vh;
          int n = rid & (Nn - 1), b = rid >> 10;
          Xh[((size_t)(b * 64 + col)) * Nn + n] = vh;
        } else {
          Rb[(size_t)rid * 64 + col - 64] = bf_rne(sg);
        }
      }
    }
}

// ---------- update: hc=tanh(XA@Wu^T+b); h=r*h+(1-r)*hc; enc-fill of x/Y-x for tnext ----------
__global__ __launch_bounds__(256) void k_upd(const u16* __restrict__ XA,
                                             const u16* __restrict__ Wh, const u16* __restrict__ Wl,
                                             const float* __restrict__ bias,
                                             const u16* __restrict__ Rb,
                                             float* __restrict__ h,
                                             u16* __restrict__ XAo,
                                             u16* __restrict__ Xh,
                                             const float* __restrict__ xsrc, int tnext,
                                             int off_next,
                                             const u16* __restrict__ ye1,
                                             const u16* __restrict__ ye2) {
  __shared__ u16 lds[8192];  // A 4096 | Wh 2048 | Wl 2048
  const int tid = threadIdx.x;
  const int wave = tid >> 6, lane = tid & 63;
  const int r0 = blockIdx.x * 128;
  const int wy = wave >> 1, wx = wave & 1;
  const int m = lane & 15, quad = lane >> 4;

  f32x4 acc[4][2];
  f32x4 z4 = {0.f, 0.f, 0.f, 0.f};
#pragma unroll
  for (int a = 0; a < 4; a++) { acc[a][0] = z4; acc[a][1] = z4; }

  for (int kt = 0; kt < 7; kt++) {
    int k0 = kt * 32;
#pragma unroll
    for (int c = 0; c < 2; c++) {
      int ci = c * 256 + tid;
      int r = ci >> 2, kc = (ci & 3) ^ SWZ(r);
      gld16(XA + (size_t)(r0 + r) * SA + k0 + kc * 8, &lds[c * 2048 + wave * 512]);
    }
    {
      int r = tid >> 2, kc = (tid & 3) ^ SWZ(r);
      gld16(Wh + (size_t)r * KP + k0 + kc * 8, &lds[4096 + wave * 512]);
      gld16(Wl + (size_t)r * KP + k0 + kc * 8, &lds[6144 + wave * 512]);
    }
    __syncthreads();

    bf16x8 af[4], bh[2], bl[2];
#pragma unroll
    for (int mb = 0; mb < 4; mb++) {
      int r = wy * 64 + mb * 16 + m;
      int ci = r * 4 + (quad ^ SWZ(r));
      af[mb] = *(const bf16x8*)&lds[ci * 8];
    }
#pragma unroll
    for (int nb = 0; nb < 2; nb++) {
      int rj = wx * 32 + nb * 16 + m;
      int cj = rj * 4 + (quad ^ SWZ(rj));
      bh[nb] = *(const bf16x8*)&lds[4096 + cj * 8];
      bl[nb] = *(const bf16x8*)&lds[6144 + cj * 8];
    }
#pragma unroll
    for (int mb = 0; mb < 4; mb++)
#pragma unroll
      for (int nb = 0; nb < 2; nb++) {
        acc[mb][nb] = __builtin_amdgcn_mfma_f32_16x16x32_bf16(af[mb], bh[nb], acc[mb][nb], 0, 0, 0);
        acc[mb][nb] = __builtin_amdgcn_mfma_f32_16x16x32_bf16(af[mb], bl[nb], acc[mb][nb], 0, 0, 0);
      }
    __syncthreads();
  }

#pragma unroll
  for (int mb = 0; mb < 4; mb++)
#pragma unroll
    for (int nb = 0; nb < 2; nb++) {
      int col = wx * 32 + nb * 16 + m;
      float bv = bias[col];
#pragma unroll
      for (int p = 0; p < 4; p++) {
        int rid = r0 + wy * 64 + mb * 16 + quad * 4 + p;
        float hc = tanhf(acc[mb][nb][p] + bv);
        size_t idx = (size_t)rid * 64 + col;
        float rr = bf_to_f(Rb[idx]);
        float hn = rr * h[idx] + (1.f - rr) * hc;
        h[idx] = hn;
        u16 vh = bf_rne(hn);
        XAo[(size_t)rid * SA + off_next + col] = vh;
        int n = rid & (Nn - 1), b = rid >> 10;
        Xh[((size_t)(b * 64 + col)) * Nn + n] = vh;
        if (col == 0 && xsrc != nullptr) {
          XAo[(size_t)rid * SA] = bf_rne(xsrc[(size_t)b * TN + (size_t)tnext * Nn + n]);
          XAo[(size_t)rid * SA + 66] = ye1[((size_t)(tnext * 64 + b)) * Nn + n];
          XAo[(size_t)rid * SA + 132] = ye2[((size_t)(tnext * 64 + b)) * Nn + n];
        }
      }
    }
}

// ---------- de = h @ FC_E, split output ----------
__global__ __launch_bounds__(256) void k_de(const float* __restrict__ h,
                                            const float* __restrict__ fc,
                                            u16* __restrict__ Dh, u16* __restrict__ Dl) {
  __shared__ float fcs[Hc * Ec];
  for (int j = threadIdx.x; j < Hc * Ec; j += 256) fcs[j] = fc[j];
  __syncthreads();
  int idx = blockIdx.x * 256 + threadIdx.x;
  if (idx >= Nn * KD) return;
  int n = idx / KD;
  int rem = idx % KD;
  int b = rem / Ec, e = rem % Ec;
  const float* hp = h + ((size_t)b * Nn + n) * Hc;
  float acc = 0.f;
#pragma unroll 8
  for (int hh = 0; hh < Hc; hh++) acc = fmaf(hp[hh], fcs[hh * Ec + e], acc);
  u16 vh, vl;
  split_bf(acc, vh, vl);
  Dh[idx] = vh; Dl[idx] = vl;
}

// ---------- proj + fill next dec step (X-cols + precomputed ycov Y-cols) ----------
__global__ __launch_bounds__(256) void k_proj_fill(const float* __restrict__ h,
                                                   const float* __restrict__ pw,
                                                   const float* __restrict__ pb,
                                                   const float* __restrict__ ycov,
                                                   u16* __restrict__ XAh,
                                                   const u16* __restrict__ yd1,
                                                   const u16* __restrict__ yd2,
                                                   float* __restrict__ out, int t) {
  int idx = blockIdx.x * 256 + threadIdx.x;
  if (idx >= NB) return;
  int n = idx & (Nn - 1), b = idx >> 10;
  const float* hp = h + (size_t)idx * Hc;
  float acc = pb[0];
#pragma unroll 8
  for (int i = 0; i < Hc; i++) acc = fmaf(hp[i], pw[i], acc);
  out[(size_t)b * TN + (size_t)t * Nn + n] = acc;
  if (t + 1 < Tc) {
    XAh[(size_t)idx * SA] = bf_rne(acc);
    XAh[(size_t)idx * SA + 1] = bf_rne(ycov[(size_t)b * TN + (size_t)(t + 1) * Nn + n]);
    size_t yc = (size_t)(64 + (t + 1) * 64 + b) * Nn + n;
    XAh[(size_t)idx * SA + 67] = yd1[yc];
    XAh[(size_t)idx * SA + 133] = yd2[yc];
  }
}

extern "C" void kernel_launch(void* const* d_in, const int* in_sizes, int n_in,
                              void* d_out, int out_size, void* d_ws, size_t ws_size,
                              hipStream_t stream) {
  (void)in_sizes; (void)n_in; (void)out_size; (void)ws_size;
  const float* x    = (const float*)d_in[0];
  const float* ycov = (const float*)d_in[1];
  const float* emb  = (const float*)d_in[2];
  const float* fce  = (const float*)d_in[3];
  const float* egw  = (const float*)d_in[4];
  const float* egb  = (const float*)d_in[5];
  const float* euw  = (const float*)d_in[6];
  const float* eub  = (const float*)d_in[7];
  const float* dgw  = (const float*)d_in[8];
  const float* dgb  = (const float*)d_in[9];
  const float* duw  = (const float*)d_in[10];
  const float* dub  = (const float*)d_in[11];
  const float* pw   = (const float*)d_in[12];
  const float* pb   = (const float*)d_in[13];
  float* out = (float*)d_out;

  char* wsb = (char*)d_ws;
  size_t off = 0;
  auto alloc = [&](size_t bytes) {
    void* p = wsb + off;
    off = (off + bytes + 255) & ~(size_t)255;
    return p;
  };
  float* Gf = (float*)alloc((size_t)Nn * Nn * 4);
  u16* S1h = (u16*)alloc((size_t)Nn * Nn * 2);
  u16* S1l = (u16*)alloc((size_t)Nn * Nn * 2);
  u16* S2h = (u16*)alloc((size_t)Nn * Nn * 2);
  u16* Sth = (u16*)alloc((size_t)Nn * Nn * 2);
  u16* Stl = (u16*)alloc((size_t)Nn * Nn * 2);
  float* Hst = (float*)alloc((size_t)NB * Hc * 4);
  u16* XAh = (u16*)alloc((size_t)(NB + 4) * SA * 2);
  u16* XhT = (u16*)alloc((size_t)Bc * 64 * Nn * 2);  // h-only B operand [b*64+ch][n]
  u16* Rb = (u16*)alloc((size_t)NB * Hc * 2);
  u16* DEh = (u16*)alloc((size_t)Nn * KD * 2);
  u16* DEl = (u16*)alloc((size_t)Nn * KD * 2);
  u16* WgeH = (u16*)alloc(128 * KP * 2); u16* WgeL = (u16*)alloc(128 * KP * 2);
  u16* WueH = (u16*)alloc(64 * KP * 2);  u16* WueL = (u16*)alloc(64 * KP * 2);
  u16* WgdH = (u16*)alloc(128 * KP * 2); u16* WgdL = (u16*)alloc(128 * KP * 2);
  u16* WudH = (u16*)alloc(64 * KP * 2);  u16* WudL = (u16*)alloc(64 * KP * 2);
  u16* XxE = (u16*)alloc((size_t)NXE * Nn * 2);
  u16* YE1 = (u16*)alloc((size_t)NXE * Nn * 2);
  u16* YE2 = (u16*)alloc((size_t)NXE * Nn * 2);
  u16* XxD = (u16*)alloc((size_t)NXD * Nn * 2);
  u16* YD1 = (u16*)alloc((size_t)NXD * Nn * 2);
  u16* YD2 = (u16*)alloc((size_t)NXD * Nn * 2);

  hipMemsetAsync(Hst, 0, (size_t)NB * Hc * 4, stream);
  hipMemsetAsync(XAh, 0, (size_t)(NB + 4) * SA * 2, stream);
  hipMemsetAsync(XhT, 0, (size_t)Bc * 64 * Nn * 2, stream);

  k_prep_wt<<<(128 * KP + 255) / 256, 256, 0, stream>>>(egw, 65, 128, WgeH, WgeL);
  k_prep_wt<<<(64 * KP + 255) / 256, 256, 0, stream>>>(euw, 65, 64, WueH, WueL);
  k_prep_wt<<<(128 * KP + 255) / 256, 256, 0, stream>>>(dgw, 66, 128, WgdH, WgdL);
  k_prep_wt<<<(64 * KP + 255) / 256, 256, 0, stream>>>(duw, 66, 64, WudH, WudL);

  // encoder supports
  k_gram<<<dim3(16, 16), 256, 0, stream>>>(emb, Ec, Gf);
  k_softmax<<<Nn, 256, 0, stream>>>(Gf, S1h, S1l);
  k_tr2<<<dim3(16, 16), 256, 0, stream>>>(S1h, S1l, Sth, Stl);
  k_s2_mfma<<<128, 256, 0, stream>>>(S1h, S1l, Sth, Stl, S2h);

  // precompute Y for all encoder x-columns (12 steps known upfront)
  k_prep_xe<<<(NXE * Nn + 255) / 256, 256, 0, stream>>>(x, XxE);
  k_ypre<<<8 * 6, 256, 0, stream>>>(S1h, S2h, XxE, YE1, YE2);

  const int gNB = NB / 256;

  k_fill_enc<<<gNB, 256, 0, stream>>>(x, XAh, YE1, YE2);
  for (int t = 0; t < Tc; t++) {
    k_ygemm<<<256, 256, 0, stream>>>(S1h, S2h, XhT, XAh, 1, nullptr, nullptr);
    k_gate<<<512, 256, 0, stream>>>(XAh, WgeH, WgeL, egb, Hst, Rb, XAh, XhT, 1);
    k_ygemm<<<256, 256, 0, stream>>>(S1h, S2h, XhT, XAh, 1, nullptr, nullptr);
    k_upd<<<512, 256, 0, stream>>>(XAh, WueH, WueL, eub, Rb, Hst, XAh, XhT,
                                   (t + 1 < Tc) ? x : nullptr, t + 1,
                                   (t == Tc - 1) ? 2 : 1, YE1, YE2);
  }

  // decoder supports
  k_de<<<(Nn * KD + 255) / 256, 256, 0, stream>>>(Hst, fce, DEh, DEl);
  k_gram_mfma<<<dim3(8, 16), 256, 0, stream>>>(DEh, DEl, Gf);
  k_softmax<<<Nn, 256, 0, stream>>>(Gf, S1h, S1l);
  k_tr2<<<dim3(16, 16), 256, 0, stream>>>(S1h, S1l, Sth, Stl);
  k_s2_mfma<<<128, 256, 0, stream>>>(S1h, S1l, Sth, Stl, S2h);

  // precompute Y for decoder go0 + all ycov columns
  k_prep_xd<<<(NXD * Nn + 255) / 256, 256, 0, stream>>>(x, ycov, XxD);
  k_ypre<<<8 * 7, 256, 0, stream>>>(S1h, S2h, XxD, YD1, YD2);

  k_dec_init<<<gNB, 256, 0, stream>>>(x, ycov, XAh, YD1, YD2);

  for (int t = 0; t < Tc; t++) {
    k_ygemm<<<256, 256, 0, stream>>>(S1h, S2h, XhT, XAh, 2,
                                     (t > 0) ? pw : nullptr, pb);
    k_gate<<<512, 256, 0, stream>>>(XAh, WgdH, WgdL, dgb, Hst, Rb, XAh, XhT, 2);
    k_ygemm<<<256, 256, 0, stream>>>(S1h, S2h, XhT, XAh, 2, nullptr, nullptr);
    k_upd<<<512, 256, 0, stream>>>(XAh, WudH, WudL, dub, Rb, Hst, XAh, XhT,
                                   nullptr, 0, 2, nullptr, nullptr);
    k_proj_fill<<<gNB, 256, 0, stream>>>(Hst, pw, pb, ycov, XAh, YD1, YD2, out, t);
  }
}

// Round 5
// 2503.499 us; speedup vs baseline: 2.5549x; 1.3468x over previous
//
#include <hip/hip_runtime.h>
#include <math.h>

typedef __attribute__((ext_vector_type(8))) short bf16x8;
typedef __attribute__((ext_vector_type(4))) float f32x4;
typedef unsigned short u16;
typedef __attribute__((ext_vector_type(4))) unsigned short u16x4;

namespace {
constexpr int Bc = 64, Tc = 12, Nn = 1024, Hc = 64, Ec = 10;
constexpr int NB = Nn * Bc;  // 65536
constexpr int Cc = 66;       // unified channel count
constexpr int SA = 208;      // XA row stride ([X(66)|Y1(66)|Y2(66)|pad10])
constexpr int KP = 224;      // padded K for gate/update GEMMs (7 x 32)
constexpr int KD = Bc * Ec;  // 640, dec gram K
constexpr int TN = Tc * Nn;  // 12288
constexpr int NXE = 768;     // enc precompute cols: 12t x 64b
constexpr int NXD = 896;     // dec precompute cols: go0(64) + 12t x 64b + pad
// Row index convention: rid = b*Nn + n  (b outer, n inner).
}

#define SWZ(r) (((r) >> 1) & 3)
#define SW8(r) ((r) & 7)

__device__ __forceinline__ void gld16(const void* g, void* l) {
  __builtin_amdgcn_global_load_lds(
      (const __attribute__((address_space(1))) void*)g,
      (__attribute__((address_space(3))) void*)l, 16, 0, 0);
}

__device__ __forceinline__ void split_bf(float v, u16& h, u16& l) {
  unsigned u = __float_as_uint(v);
  unsigned hu = (u + 0x7FFFu + ((u >> 16) & 1u)) & 0xFFFF0000u;
  h = (u16)(hu >> 16);
  float r = v - __uint_as_float(hu);
  unsigned u2 = __float_as_uint(r);
  l = (u16)((u2 + 0x7FFFu + ((u2 >> 16) & 1u)) >> 16);
}
__device__ __forceinline__ u16 bf_rne(float v) {
  unsigned u = __float_as_uint(v);
  return (u16)((u + 0x7FFFu + ((u >> 16) & 1u)) >> 16);
}
__device__ __forceinline__ float bf_to_f(u16 v) {
  return __uint_as_float(((unsigned)v) << 16);
}
__device__ __forceinline__ bf16x8 ldfrag(const u16* p) { return *(const bf16x8*)p; }

// A-tile LDS address: [kt 0..6][slot r*4 + (j4^SWZ(r))][8], col in [0,224)
__device__ __forceinline__ int atile(int r, int col) {
  return ((col >> 5) * 4096) + ((r * 4 + (((col >> 3) & 3) ^ SWZ(r))) * 8) + (col & 7);
}

// ---------- enc gram: G = emb @ emb^T ----------
__global__ __launch_bounds__(256) void k_gram(const float* __restrict__ in, int Kd,
                                              float* __restrict__ G) {
  __shared__ float At[16][64];
  __shared__ float Bt[16][64];
  int i0 = blockIdx.y * 64, j0 = blockIdx.x * 64;
  int tx = threadIdx.x & 15, ty = threadIdx.x >> 4;
  float acc[4][4] = {};
  for (int k0 = 0; k0 < Kd; k0 += 16) {
    for (int u = threadIdx.x; u < 1024; u += 256) {
      int i = u >> 4, k = u & 15;
      At[k][i] = (k0 + k < Kd) ? in[(size_t)(i0 + i) * Kd + k0 + k] : 0.f;
    }
    for (int u = threadIdx.x; u < 1024; u += 256) {
      int j = u >> 4, k = u & 15;
      Bt[k][j] = (k0 + k < Kd) ? in[(size_t)(j0 + j) * Kd + k0 + k] : 0.f;
    }
    __syncthreads();
#pragma unroll
    for (int kk = 0; kk < 16; kk++) {
      float a[4], b[4];
#pragma unroll
      for (int p = 0; p < 4; p++) a[p] = At[kk][ty * 4 + p];
#pragma unroll
      for (int q = 0; q < 4; q++) b[q] = Bt[kk][tx * 4 + q];
#pragma unroll
      for (int p = 0; p < 4; p++)
#pragma unroll
        for (int q = 0; q < 4; q++) acc[p][q] = fmaf(a[p], b[q], acc[p][q]);
    }
    __syncthreads();
  }
  for (int p = 0; p < 4; p++)
    for (int q = 0; q < 4; q++)
      G[(size_t)(i0 + ty * 4 + p) * Nn + j0 + tx * 4 + q] = acc[p][q];
}

// ---------- dec gram via split-MFMA ----------
__global__ __launch_bounds__(256) void k_gram_mfma(const u16* __restrict__ Dh,
                                                   const u16* __restrict__ Dl,
                                                   float* __restrict__ G) {
  __shared__ u16 lds[12288];
  const int tid = threadIdx.x;
  const int wave = tid >> 6, lane = tid & 63;
  const int i0 = blockIdx.y * 64;
  const int j0 = blockIdx.x * 128;
  const int wy = wave >> 1, wx = wave & 1;
  const int m = lane & 15, quad = lane >> 4;

  f32x4 acc[2][4];
  f32x4 z4 = {0.f, 0.f, 0.f, 0.f};
#pragma unroll
  for (int a = 0; a < 2; a++)
#pragma unroll
    for (int q = 0; q < 4; q++) acc[a][q] = z4;

  const int ar = tid >> 2;
  const int akc = (tid & 3) ^ SWZ(ar);

  for (int k0 = 0; k0 < KD; k0 += 32) {
    gld16(Dh + (size_t)(i0 + ar) * KD + k0 + akc * 8, &lds[wave * 512]);
    gld16(Dl + (size_t)(i0 + ar) * KD + k0 + akc * 8, &lds[2048 + wave * 512]);
#pragma unroll
    for (int p = 0; p < 2; p++) {
      int r = p * 64 + (tid >> 2);
      int kc = (tid & 3) ^ SWZ(r);
      gld16(Dh + (size_t)(j0 + r) * KD + k0 + kc * 8, &lds[4096 + p * 2048 + wave * 512]);
      gld16(Dl + (size_t)(j0 + r) * KD + k0 + kc * 8, &lds[8192 + p * 2048 + wave * 512]);
    }
    __syncthreads();

    bf16x8 ah[2], al[2], bh[4], bl[4];
#pragma unroll
    for (int mb = 0; mb < 2; mb++) {
      int r = wy * 32 + mb * 16 + m;
      int ci = r * 4 + (quad ^ SWZ(r));
      ah[mb] = *(const bf16x8*)&lds[ci * 8];
      al[mb] = *(const bf16x8*)&lds[2048 + ci * 8];
    }
#pragma unroll
    for (int nb = 0; nb < 4; nb++) {
      int rj = wx * 64 + nb * 16 + m;
      int cj = rj * 4 + (quad ^ SWZ(rj));
      bh[nb] = *(const bf16x8*)&lds[4096 + cj * 8];
      bl[nb] = *(const bf16x8*)&lds[8192 + cj * 8];
    }
#pragma unroll
    for (int mb = 0; mb < 2; mb++)
#pragma unroll
      for (int nb = 0; nb < 4; nb++) {
        acc[mb][nb] = __builtin_amdgcn_mfma_f32_16x16x32_bf16(ah[mb], bh[nb], acc[mb][nb], 0, 0, 0);
        acc[mb][nb] = __builtin_amdgcn_mfma_f32_16x16x32_bf16(ah[mb], bl[nb], acc[mb][nb], 0, 0, 0);
        acc[mb][nb] = __builtin_amdgcn_mfma_f32_16x16x32_bf16(al[mb], bh[nb], acc[mb][nb], 0, 0, 0);
      }
    __syncthreads();
  }

#pragma unroll
  for (int mb = 0; mb < 2; mb++)
#pragma unroll
    for (int nb = 0; nb < 4; nb++) {
      int col = j0 + wx * 64 + nb * 16 + m;
#pragma unroll
      for (int p = 0; p < 4; p++) {
        int row = i0 + wy * 32 + mb * 16 + quad * 4 + p;
        G[(size_t)row * Nn + col] = acc[mb][nb][p];
      }
    }
}

// ---------- S = row_softmax(relu(G)) ----------
__global__ __launch_bounds__(256) void k_softmax(const float* __restrict__ G,
                                                 u16* __restrict__ S1h,
                                                 u16* __restrict__ S1l) {
  __shared__ float sred[8];
  int n = blockIdx.x;
  float v[4];
#pragma unroll
  for (int i = 0; i < 4; i++)
    v[i] = fmaxf(G[(size_t)n * Nn + threadIdx.x + i * 256], 0.f);
  float mx = fmaxf(fmaxf(v[0], v[1]), fmaxf(v[2], v[3]));
  for (int off = 32; off > 0; off >>= 1) mx = fmaxf(mx, __shfl_down(mx, off));
  if ((threadIdx.x & 63) == 0) sred[threadIdx.x >> 6] = mx;
  __syncthreads();
  float rmax = fmaxf(fmaxf(sred[0], sred[1]), fmaxf(sred[2], sred[3]));
  float s = 0.f;
#pragma unroll
  for (int i = 0; i < 4; i++) { v[i] = expf(v[i] - rmax); s += v[i]; }
  for (int off = 32; off > 0; off >>= 1) s += __shfl_down(s, off);
  if ((threadIdx.x & 63) == 0) sred[4 + (threadIdx.x >> 6)] = s;
  __syncthreads();
  float inv = 1.f / (sred[4] + sred[5] + sred[6] + sred[7]);
#pragma unroll
  for (int i = 0; i < 4; i++) {
    u16 h, l;
    split_bf(v[i] * inv, h, l);
    size_t a = (size_t)n * Nn + threadIdx.x + i * 256;
    S1h[a] = h; S1l[a] = l;
  }
}

// ---------- transpose ----------
__global__ __launch_bounds__(256) void k_tr2(const u16* __restrict__ Ah,
                                             const u16* __restrict__ Al,
                                             u16* __restrict__ Th, u16* __restrict__ Tl) {
  __shared__ u16 sm[64][72];
  int i0 = blockIdx.y * 64, j0 = blockIdx.x * 64;
  int tid = threadIdx.x;
  for (int pass = 0; pass < 2; pass++) {
    const u16* src = pass ? Al : Ah;
    u16* dst = pass ? Tl : Th;
    for (int u = tid; u < 4096; u += 256) {
      int i = u >> 6, c = u & 63;
      sm[i][c] = src[(size_t)(i0 + i) * Nn + j0 + c];
    }
    __syncthreads();
    for (int u = tid; u < 4096; u += 256) {
      int c = u >> 6, i = u & 63;
      dst[(size_t)(j0 + c) * Nn + i0 + i] = sm[i][c];
    }
    __syncthreads();
  }
}

// ---------- S2 = 2*S@S - I ----------
__global__ __launch_bounds__(256) void k_s2_mfma(const u16* __restrict__ S1h,
                                                 const u16* __restrict__ S1l,
                                                 const u16* __restrict__ Sth,
                                                 const u16* __restrict__ Stl,
                                                 u16* __restrict__ S2h) {
  const int tid = threadIdx.x;
  const int wave = tid >> 6, lane = tid & 63;
  const int blk = blockIdx.x;
  const int s = blk >> 3;
  const int i0 = ((blk & 7) * 2 + (s & 1)) * 64;
  const int j0 = (s >> 1) * 128;
  const int wy = wave >> 1, wx = wave & 1;
  const int m = lane & 15, quad = lane >> 4;

  const size_t aoff = (size_t)(i0 + wy * 32 + m) * Nn + quad * 8;
  const size_t boff = (size_t)(j0 + wx * 64 + m) * Nn + quad * 8;

  f32x4 acc[2][4];
  f32x4 z4 = {0.f, 0.f, 0.f, 0.f};
#pragma unroll
  for (int a = 0; a < 2; a++)
#pragma unroll
    for (int q = 0; q < 4; q++) acc[a][q] = z4;

  bf16x8 fAh[2][2], fAl[2][2], fBh[2][4], fBl[2][4];
  auto ld = [&](int k0, int sb) {
#pragma unroll
    for (int mb = 0; mb < 2; mb++) {
      fAh[sb][mb] = ldfrag(S1h + aoff + (size_t)mb * 16 * Nn + k0);
      fAl[sb][mb] = ldfrag(S1l + aoff + (size_t)mb * 16 * Nn + k0);
    }
#pragma unroll
    for (int nb = 0; nb < 4; nb++) {
      fBh[sb][nb] = ldfrag(Sth + boff + (size_t)nb * 16 * Nn + k0);
      fBl[sb][nb] = ldfrag(Stl + boff + (size_t)nb * 16 * Nn + k0);
    }
  };
  ld(0, 0);
#pragma unroll 2
  for (int kt = 0; kt < 32; kt++) {
    int cur = kt & 1;
    if (kt < 31) ld((kt + 1) * 32, cur ^ 1);
#pragma unroll
    for (int mb = 0; mb < 2; mb++)
#pragma unroll
      for (int nb = 0; nb < 4; nb++) {
        acc[mb][nb] = __builtin_amdgcn_mfma_f32_16x16x32_bf16(fAh[cur][mb], fBh[cur][nb], acc[mb][nb], 0, 0, 0);
        acc[mb][nb] = __builtin_amdgcn_mfma_f32_16x16x32_bf16(fAh[cur][mb], fBl[cur][nb], acc[mb][nb], 0, 0, 0);
        acc[mb][nb] = __builtin_amdgcn_mfma_f32_16x16x32_bf16(fAl[cur][mb], fBh[cur][nb], acc[mb][nb], 0, 0, 0);
      }
  }

#pragma unroll
  for (int mb = 0; mb < 2; mb++)
#pragma unroll
    for (int nb = 0; nb < 4; nb++) {
      int col = j0 + wx * 64 + nb * 16 + m;
#pragma unroll
      for (int p = 0; p < 4; p++) {
        int row = i0 + wy * 32 + mb * 16 + quad * 4 + p;
        float v = 2.f * acc[mb][nb][p] - (row == col ? 1.f : 0.f);
        S2h[(size_t)row * Nn + col] = bf_rne(v);
      }
    }
}

// ---------- Wt prep ----------
__global__ __launch_bounds__(256) void k_prep_wt(const float* __restrict__ W, int Csrc,
                                                 int ncol, u16* __restrict__ Wh,
                                                 u16* __restrict__ Wl) {
  int idx = blockIdx.x * 256 + threadIdx.x;
  if (idx >= ncol * KP) return;
  int n = idx / KP, kp = idx % KP;
  int chunk = kp / Cc, c = kp % Cc;
  float v = 0.f;
  if (kp < 3 * Cc && c < Csrc) v = W[((size_t)chunk * Csrc + c) * ncol + n];
  u16 h, l;
  split_bf(v, h, l);
  Wh[idx] = h; Wl[idx] = l;
}

// ---------- precompute B operands ----------
__global__ __launch_bounds__(256) void k_prep_xe(const float* __restrict__ x,
                                                 u16* __restrict__ Xx) {
  int idx = blockIdx.x * 256 + threadIdx.x;
  if (idx >= NXE * Nn) return;
  int col = idx >> 10, n = idx & (Nn - 1);
  int t = col >> 6, b = col & 63;
  Xx[idx] = bf_rne(x[(size_t)b * TN + (size_t)t * Nn + n]);
}

__global__ __launch_bounds__(256) void k_prep_xd(const float* __restrict__ x,
                                                 const float* __restrict__ ycov,
                                                 u16* __restrict__ Xx) {
  int idx = blockIdx.x * 256 + threadIdx.x;
  if (idx >= NXD * Nn) return;
  int col = idx >> 10, n = idx & (Nn - 1);
  float v = 0.f;
  if (col < 64) {
    v = x[(size_t)col * TN + (size_t)(Tc - 1) * Nn + n];
  } else if (col < 64 + Tc * 64) {
    int t = (col - 64) >> 6, b = (col - 64) & 63;
    v = ycov[(size_t)b * TN + (size_t)t * Nn + n];
  }
  Xx[idx] = bf_rne(v);
}

// ---------- ypre: Y1 = S1@Xx, Y2 = S2@Xx (x-derived Y cols) ----------
__global__ __launch_bounds__(256, 2) void k_ypre(const u16* __restrict__ S1h,
                                                 const u16* __restrict__ S2h,
                                                 const u16* __restrict__ Xx,
                                                 u16* __restrict__ Yo1,
                                                 u16* __restrict__ Yo2) {
  __shared__ u16 lds[24576];
  const int tid = threadIdx.x;
  const int wave = tid >> 6;
  const int lane = tid & 63;
  const int blk = blockIdx.x;
  const int i0 = (blk & 7) * 128;
  const int j0 = (blk >> 3) * 128;
  const int wy = wave >> 1, wx = wave & 1;
  const int m = lane & 15, quad = lane >> 4;

  f32x4 acc1[4][4], acc2[4][4];
  f32x4 z4 = {0.f, 0.f, 0.f, 0.f};
#pragma unroll
  for (int a = 0; a < 4; a++)
#pragma unroll
    for (int q = 0; q < 4; q++) { acc1[a][q] = z4; acc2[a][q] = z4; }

  for (int k0 = 0; k0 < Nn; k0 += 64) {
#pragma unroll
    for (int c = 0; c < 4; c++) {
      int ci = c * 256 + tid;
      int r = ci >> 3, kc = (ci & 7) ^ SW8(r);
      gld16(S1h + (size_t)(i0 + r) * Nn + k0 + kc * 8, &lds[c * 2048 + wave * 512]);
      gld16(S2h + (size_t)(i0 + r) * Nn + k0 + kc * 8, &lds[8192 + c * 2048 + wave * 512]);
      gld16(Xx + (size_t)(j0 + r) * Nn + k0 + kc * 8, &lds[16384 + c * 2048 + wave * 512]);
    }
    __syncthreads();

#pragma unroll
    for (int ks = 0; ks < 2; ks++) {
      bf16x8 bfr[4];
#pragma unroll
      for (int nb = 0; nb < 4; nb++) {
        int rj = wx * 64 + nb * 16 + m;
        int cj = rj * 8 + ((ks * 4 + quad) ^ SW8(rj));
        bfr[nb] = *(const bf16x8*)&lds[16384 + cj * 8];
      }
      bf16x8 a1[4], a2[4];
#pragma unroll
      for (int mb = 0; mb < 4; mb++) {
        int r = wy * 64 + mb * 16 + m;
        int ci = r * 8 + ((ks * 4 + quad) ^ SW8(r));
        a1[mb] = *(const bf16x8*)&lds[ci * 8];
        a2[mb] = *(const bf16x8*)&lds[8192 + ci * 8];
      }
#pragma unroll
      for (int mb = 0; mb < 4; mb++)
#pragma unroll
        for (int nb = 0; nb < 4; nb++) {
          acc1[mb][nb] = __builtin_amdgcn_mfma_f32_16x16x32_bf16(a1[mb], bfr[nb], acc1[mb][nb], 0, 0, 0);
          acc2[mb][nb] = __builtin_amdgcn_mfma_f32_16x16x32_bf16(a2[mb], bfr[nb], acc2[mb][nb], 0, 0, 0);
        }
    }
    __syncthreads();
  }

#pragma unroll
  for (int mb = 0; mb < 4; mb++)
#pragma unroll
    for (int nb = 0; nb < 4; nb++) {
      int col = j0 + wx * 64 + nb * 16 + m;
#pragma unroll
      for (int p = 0; p < 4; p++) {
        int n = i0 + wy * 64 + mb * 16 + quad * 4 + p;
        Yo1[(size_t)col * Nn + n] = bf_rne(acc1[mb][nb][p]);
        Yo2[(size_t)col * Nn + n] = bf_rne(acc2[mb][nb][p]);
      }
    }
}

// ---------- fill enc t=0 ----------
__global__ __launch_bounds__(256) void k_fill_enc(const float* __restrict__ x,
                                                  u16* __restrict__ XAh,
                                                  const u16* __restrict__ ye1,
                                                  const u16* __restrict__ ye2) {
  int idx = blockIdx.x * 256 + threadIdx.x;
  if (idx >= NB) return;
  int n = idx & (Nn - 1), b = idx >> 10;
  XAh[(size_t)idx * SA] = bf_rne(x[(size_t)b * TN + n]);
  XAh[(size_t)idx * SA + 66] = ye1[(size_t)b * Nn + n];
  XAh[(size_t)idx * SA + 132] = ye2[(size_t)b * Nn + n];
}

// ---------- dec init ----------
__global__ __launch_bounds__(256) void k_dec_init(const float* __restrict__ x,
                                                  const float* __restrict__ ycov,
                                                  u16* __restrict__ XAh,
                                                  const u16* __restrict__ yd1,
                                                  const u16* __restrict__ yd2) {
  int idx = blockIdx.x * 256 + threadIdx.x;
  if (idx >= NB) return;
  int n = idx & (Nn - 1), b = idx >> 10;
  XAh[(size_t)idx * SA] = bf_rne(x[(size_t)b * TN + (size_t)(Tc - 1) * Nn + n]);
  XAh[(size_t)idx * SA + 1] = bf_rne(ycov[(size_t)b * TN + n]);
  XAh[(size_t)idx * SA + 66] = yd1[(size_t)b * Nn + n];
  XAh[(size_t)idx * SA + 67] = yd1[(size_t)(64 + b) * Nn + n];
  XAh[(size_t)idx * SA + 132] = yd2[(size_t)b * Nn + n];
  XAh[(size_t)idx * SA + 133] = yd2[(size_t)(64 + b) * Nn + n];
}

// ================= FUSED ygemm + gate =================
// Grid 512: i0 = (blk&7)*128 (n-slice), bb = blk>>3 (batch). Block owns rows
// rid = bb*Nn + i0..+127 exclusively (reads/writes its own XA rows only).
// Phase 1: Y1h/Y2h = S1/S2 @ h(batch) into fp32 accs (verified ygemm core).
// Phase 2: build A-tile [128][KP] in LDS: zero -> stage X-part from XA
//          (chunks 0..7 raw; chunks 8,16 bitmask-selected) -> write Y from accs
//          (+ optional derived go-column: S@go = (S@h)@pw+pb, also to XA).
// Phase 3: gate GEMM, A from LDS, W direct-global fragments (L2-resident).
__global__ __launch_bounds__(256) void k_fgate(
    const u16* __restrict__ S1h, const u16* __restrict__ S2h,
    const u16* __restrict__ XhIn, const u16* XA,
    const u16* __restrict__ Wh, const u16* __restrict__ Wl,
    const float* __restrict__ bias, const float* __restrict__ hst,
    u16* __restrict__ Rb, u16* XAo, u16* __restrict__ XhOut,
    int off, int yoff, int m8, int m16,
    const float* __restrict__ pw, const float* __restrict__ pb) {
  __shared__ u16 lds[28672];  // 56KB: phase1 staging [0,20480) / phase2+3 A-tile
  const int tid = threadIdx.x;
  const int wave = tid >> 6, lane = tid & 63;
  const int i0 = (blockIdx.x & 7) * 128;
  const int bb = blockIdx.x >> 3;
  const int m = lane & 15, quad = lane >> 4;
  const size_t rowbase = (size_t)bb * Nn + i0;

  // ---- phase 1 ----
  f32x4 acc1[2][4], acc2[2][4];
  f32x4 z4 = {0.f, 0.f, 0.f, 0.f};
#pragma unroll
  for (int a = 0; a < 2; a++)
#pragma unroll
    for (int q = 0; q < 4; q++) { acc1[a][q] = z4; acc2[a][q] = z4; }

  for (int k0 = 0; k0 < Nn; k0 += 64) {
#pragma unroll
    for (int c = 0; c < 4; c++) {
      int ci = c * 256 + tid;
      int r = ci >> 3, kc = (ci & 7) ^ SW8(r);
      gld16(S1h + (size_t)(i0 + r) * Nn + k0 + kc * 8, &lds[c * 2048 + wave * 512]);
      gld16(S2h + (size_t)(i0 + r) * Nn + k0 + kc * 8, &lds[8192 + c * 2048 + wave * 512]);
    }
#pragma unroll
    for (int c = 0; c < 2; c++) {
      int ci = c * 256 + tid;
      int r = ci >> 3, kc = (ci & 7) ^ SW8(r);
      gld16(XhIn + (size_t)(bb * 64 + r) * Nn + k0 + kc * 8, &lds[16384 + c * 2048 + wave * 512]);
    }
    __syncthreads();
#pragma unroll
    for (int ks = 0; ks < 2; ks++) {
      bf16x8 bfr[4];
#pragma unroll
      for (int nb = 0; nb < 4; nb++) {
        int rj = nb * 16 + m;
        int cj = rj * 8 + ((ks * 4 + quad) ^ SW8(rj));
        bfr[nb] = *(const bf16x8*)&lds[16384 + cj * 8];
      }
      bf16x8 a1[2], a2[2];
#pragma unroll
      for (int mb = 0; mb < 2; mb++) {
        int r = wave * 32 + mb * 16 + m;
        int ci = r * 8 + ((ks * 4 + quad) ^ SW8(r));
        a1[mb] = *(const bf16x8*)&lds[ci * 8];
        a2[mb] = *(const bf16x8*)&lds[8192 + ci * 8];
      }
#pragma unroll
      for (int mb = 0; mb < 2; mb++)
#pragma unroll
        for (int nb = 0; nb < 4; nb++) {
          acc1[mb][nb] = __builtin_amdgcn_mfma_f32_16x16x32_bf16(a1[mb], bfr[nb], acc1[mb][nb], 0, 0, 0);
          acc2[mb][nb] = __builtin_amdgcn_mfma_f32_16x16x32_bf16(a2[mb], bfr[nb], acc2[mb][nb], 0, 0, 0);
        }
    }
    __syncthreads();
  }

  // ---- phase 2: A-tile ----
  {
    bf16x8 z8 = {0, 0, 0, 0, 0, 0, 0, 0};
    for (int i = tid; i < 3584; i += 256) *(bf16x8*)&lds[i * 8] = z8;
  }
  __syncthreads();
#pragma unroll
  for (int t4 = 0; t4 < 4; t4++) {
    int task = t4 * 256 + tid;
    int r = task >> 3, c = task & 7;
    bf16x8 v = *(const bf16x8*)(XA + (rowbase + r) * SA + c * 8);
    *(bf16x8*)&lds[(c >> 2) * 4096 + (r * 4 + ((c & 3) ^ SWZ(r))) * 8] = v;
  }
  {
    int r = tid >> 1;
    int cc = (tid & 1) ? 16 : 8;
    int msk = (tid & 1) ? m16 : m8;
    const u16* src = XA + (rowbase + r) * SA + cc * 8;
    bf16x8 v;
#pragma unroll
    for (int j = 0; j < 8; j++) v[j] = (short)(((msk >> j) & 1) ? src[j] : 0);
    *(bf16x8*)&lds[(cc >> 2) * 4096 + (r * 4 + SWZ(r)) * 8] = v;
  }
  __syncthreads();
  {
    const int yb1 = 66 + yoff, yb2 = 132 + yoff;
#pragma unroll
    for (int mb = 0; mb < 2; mb++)
#pragma unroll
      for (int nb = 0; nb < 4; nb++)
#pragma unroll
        for (int p = 0; p < 4; p++) {
          int r = wave * 32 + mb * 16 + quad * 4 + p;
          int ch = nb * 16 + m;
          lds[atile(r, yb1 + ch)] = bf_rne(acc1[mb][nb][p]);
          lds[atile(r, yb2 + ch)] = bf_rne(acc2[mb][nb][p]);
        }
    if (pw != nullptr) {
      float pb0 = pb[0];
      float pwv[4];
#pragma unroll
      for (int nb = 0; nb < 4; nb++) pwv[nb] = pw[nb * 16 + m];
#pragma unroll
      for (int mb = 0; mb < 2; mb++)
#pragma unroll
        for (int p = 0; p < 4; p++) {
          float s1 = 0.f, s2 = 0.f;
#pragma unroll
          for (int nb = 0; nb < 4; nb++) {
            s1 = fmaf(acc1[mb][nb][p], pwv[nb], s1);
            s2 = fmaf(acc2[mb][nb][p], pwv[nb], s2);
          }
#pragma unroll
          for (int o = 8; o > 0; o >>= 1) { s1 += __shfl_xor(s1, o); s2 += __shfl_xor(s2, o); }
          if (m == 0) {
            int r = wave * 32 + mb * 16 + quad * 4 + p;
            u16 v1 = bf_rne(s1 + pb0), v2 = bf_rne(s2 + pb0);
            lds[atile(r, 66)] = v1;
            lds[atile(r, 132)] = v2;
            XAo[(rowbase + r) * SA + 66] = v1;
            XAo[(rowbase + r) * SA + 132] = v2;
          }
        }
    }
  }
  __syncthreads();

  // ---- phase 3: gate GEMM ----
  f32x4 accg[4][4];
#pragma unroll
  for (int a = 0; a < 4; a++)
#pragma unroll
    for (int q = 0; q < 4; q++) accg[a][q] = z4;
  const int wy = wave >> 1, wx = wave & 1;
  const size_t wboff = (size_t)(wx * 64 + m) * KP + quad * 8;
#pragma unroll
  for (int kt = 0; kt < 7; kt++) {
    int k0 = kt * 32;
    bf16x8 af[4], bh[4], bl[4];
#pragma unroll
    for (int mb = 0; mb < 4; mb++) {
      int r = wy * 64 + mb * 16 + m;
      af[mb] = *(const bf16x8*)&lds[kt * 4096 + (r * 4 + (quad ^ SWZ(r))) * 8];
    }
#pragma unroll
    for (int nb = 0; nb < 4; nb++) {
      bh[nb] = ldfrag(Wh + wboff + (size_t)nb * 16 * KP + k0);
      bl[nb] = ldfrag(Wl + wboff + (size_t)nb * 16 * KP + k0);
    }
#pragma unroll
    for (int mb = 0; mb < 4; mb++)
#pragma unroll
      for (int nb = 0; nb < 4; nb++) {
        accg[mb][nb] = __builtin_amdgcn_mfma_f32_16x16x32_bf16(af[mb], bh[nb], accg[mb][nb], 0, 0, 0);
        accg[mb][nb] = __builtin_amdgcn_mfma_f32_16x16x32_bf16(af[mb], bl[nb], accg[mb][nb], 0, 0, 0);
      }
  }

  // ---- epilogue ----
#pragma unroll
  for (int mb = 0; mb < 4; mb++)
#pragma unroll
    for (int nb = 0; nb < 4; nb++) {
      int col = wx * 64 + nb * 16 + m;
      float bv = bias[col];
      int rl0 = wy * 64 + mb * 16 + quad * 4;
      if (col < 64) {
        u16x4 pk;
#pragma unroll
        for (int p = 0; p < 4; p++) {
          size_t rid = rowbase + rl0 + p;
          float sg = 1.f / (1.f + expf(-(accg[mb][nb][p] + bv)));
          u16 vh = bf_rne(sg * hst[rid * 64 + col]);
          XAo[rid * SA + off + col] = vh;
          pk[p] = vh;
        }
        *(u16x4*)&XhOut[(size_t)(bb * 64 + col) * Nn + i0 + rl0] = pk;
      } else {
#pragma unroll
        for (int p = 0; p < 4; p++) {
          size_t rid = rowbase + rl0 + p;
          float sg = 1.f / (1.f + expf(-(accg[mb][nb][p] + bv)));
          Rb[rid * 64 + col - 64] = bf_rne(sg);
        }
      }
    }
}

// ================= FUSED ygemm + update (+ optional proj/fill) =================
__global__ __launch_bounds__(256) void k_fupd(
    const u16* __restrict__ S1h, const u16* __restrict__ S2h,
    const u16* __restrict__ XhIn, const u16* XA,
    const u16* __restrict__ Wh, const u16* __restrict__ Wl,
    const float* __restrict__ bias, const u16* __restrict__ Rb,
    float* __restrict__ h, u16* XAo, u16* __restrict__ XhOut,
    int off_next, int yoff, int m8, int m16,
    const float* __restrict__ xsrc, int tnext,
    const u16* __restrict__ ye1, const u16* __restrict__ ye2,
    const float* __restrict__ pw2, const float* __restrict__ pb2,
    const float* __restrict__ ycov,
    const u16* __restrict__ yd1, const u16* __restrict__ yd2,
    float* __restrict__ out, int tt) {
  __shared__ u16 lds[28672];
  const int tid = threadIdx.x;
  const int wave = tid >> 6, lane = tid & 63;
  const int i0 = (blockIdx.x & 7) * 128;
  const int bb = blockIdx.x >> 3;
  const int m = lane & 15, quad = lane >> 4;
  const size_t rowbase = (size_t)bb * Nn + i0;

  // ---- phase 1: Y = S @ (z*h) ----
  f32x4 acc1[2][4], acc2[2][4];
  f32x4 z4 = {0.f, 0.f, 0.f, 0.f};
#pragma unroll
  for (int a = 0; a < 2; a++)
#pragma unroll
    for (int q = 0; q < 4; q++) { acc1[a][q] = z4; acc2[a][q] = z4; }

  for (int k0 = 0; k0 < Nn; k0 += 64) {
#pragma unroll
    for (int c = 0; c < 4; c++) {
      int ci = c * 256 + tid;
      int r = ci >> 3, kc = (ci & 7) ^ SW8(r);
      gld16(S1h + (size_t)(i0 + r) * Nn + k0 + kc * 8, &lds[c * 2048 + wave * 512]);
      gld16(S2h + (size_t)(i0 + r) * Nn + k0 + kc * 8, &lds[8192 + c * 2048 + wave * 512]);
    }
#pragma unroll
    for (int c = 0; c < 2; c++) {
      int ci = c * 256 + tid;
      int r = ci >> 3, kc = (ci & 7) ^ SW8(r);
      gld16(XhIn + (size_t)(bb * 64 + r) * Nn + k0 + kc * 8, &lds[16384 + c * 2048 + wave * 512]);
    }
    __syncthreads();
#pragma unroll
    for (int ks = 0; ks < 2; ks++) {
      bf16x8 bfr[4];
#pragma unroll
      for (int nb = 0; nb < 4; nb++) {
        int rj = nb * 16 + m;
        int cj = rj * 8 + ((ks * 4 + quad) ^ SW8(rj));
        bfr[nb] = *(const bf16x8*)&lds[16384 + cj * 8];
      }
      bf16x8 a1[2], a2[2];
#pragma unroll
      for (int mb = 0; mb < 2; mb++) {
        int r = wave * 32 + mb * 16 + m;
        int ci = r * 8 + ((ks * 4 + quad) ^ SW8(r));
        a1[mb] = *(const bf16x8*)&lds[ci * 8];
        a2[mb] = *(const bf16x8*)&lds[8192 + ci * 8];
      }
#pragma unroll
      for (int mb = 0; mb < 2; mb++)
#pragma unroll
        for (int nb = 0; nb < 4; nb++) {
          acc1[mb][nb] = __builtin_amdgcn_mfma_f32_16x16x32_bf16(a1[mb], bfr[nb], acc1[mb][nb], 0, 0, 0);
          acc2[mb][nb] = __builtin_amdgcn_mfma_f32_16x16x32_bf16(a2[mb], bfr[nb], acc2[mb][nb], 0, 0, 0);
        }
    }
    __syncthreads();
  }

  // ---- phase 2: A-tile ----
  {
    bf16x8 z8 = {0, 0, 0, 0, 0, 0, 0, 0};
    for (int i = tid; i < 3584; i += 256) *(bf16x8*)&lds[i * 8] = z8;
  }
  __syncthreads();
#pragma unroll
  for (int t4 = 0; t4 < 4; t4++) {
    int task = t4 * 256 + tid;
    int r = task >> 3, c = task & 7;
    bf16x8 v = *(const bf16x8*)(XA + (rowbase + r) * SA + c * 8);
    *(bf16x8*)&lds[(c >> 2) * 4096 + (r * 4 + ((c & 3) ^ SWZ(r))) * 8] = v;
  }
  {
    int r = tid >> 1;
    int cc = (tid & 1) ? 16 : 8;
    int msk = (tid & 1) ? m16 : m8;
    const u16* src = XA + (rowbase + r) * SA + cc * 8;
    bf16x8 v;
#pragma unroll
    for (int j = 0; j < 8; j++) v[j] = (short)(((msk >> j) & 1) ? src[j] : 0);
    *(bf16x8*)&lds[(cc >> 2) * 4096 + (r * 4 + SWZ(r)) * 8] = v;
  }
  __syncthreads();
  {
    const int yb1 = 66 + yoff, yb2 = 132 + yoff;
#pragma unroll
    for (int mb = 0; mb < 2; mb++)
#pragma unroll
      for (int nb = 0; nb < 4; nb++)
#pragma unroll
        for (int p = 0; p < 4; p++) {
          int r = wave * 32 + mb * 16 + quad * 4 + p;
          int ch = nb * 16 + m;
          lds[atile(r, yb1 + ch)] = bf_rne(acc1[mb][nb][p]);
          lds[atile(r, yb2 + ch)] = bf_rne(acc2[mb][nb][p]);
        }
  }
  __syncthreads();

  // ---- phase 3: update GEMM (N=64) ----
  f32x4 accg[4][2];
#pragma unroll
  for (int a = 0; a < 4; a++) { accg[a][0] = z4; accg[a][1] = z4; }
  const int wy = wave >> 1, wx = wave & 1;
  const size_t wboff = (size_t)(wx * 32 + m) * KP + quad * 8;
#pragma unroll
  for (int kt = 0; kt < 7; kt++) {
    int k0 = kt * 32;
    bf16x8 af[4], bh[2], bl[2];
#pragma unroll
    for (int mb = 0; mb < 4; mb++) {
      int r = wy * 64 + mb * 16 + m;
      af[mb] = *(const bf16x8*)&lds[kt * 4096 + (r * 4 + (quad ^ SWZ(r))) * 8];
    }
#pragma unroll
    for (int nb = 0; nb < 2; nb++) {
      bh[nb] = ldfrag(Wh + wboff + (size_t)nb * 16 * KP + k0);
      bl[nb] = ldfrag(Wl + wboff + (size_t)nb * 16 * KP + k0);
    }
#pragma unroll
    for (int mb = 0; mb < 4; mb++)
#pragma unroll
      for (int nb = 0; nb < 2; nb++) {
        accg[mb][nb] = __builtin_amdgcn_mfma_f32_16x16x32_bf16(af[mb], bh[nb], accg[mb][nb], 0, 0, 0);
        accg[mb][nb] = __builtin_amdgcn_mfma_f32_16x16x32_bf16(af[mb], bl[nb], accg[mb][nb], 0, 0, 0);
      }
  }

  // ---- epilogue: h update (+ partial proj) ----
  float par[4][4];
#pragma unroll
  for (int a = 0; a < 4; a++)
#pragma unroll
    for (int p = 0; p < 4; p++) par[a][p] = 0.f;
  float pwv2[2] = {0.f, 0.f};
  if (pw2 != nullptr) {
#pragma unroll
    for (int nb = 0; nb < 2; nb++) pwv2[nb] = pw2[wx * 32 + nb * 16 + m];
  }

#pragma unroll
  for (int mb = 0; mb < 4; mb++)
#pragma unroll
    for (int nb = 0; nb < 2; nb++) {
      int col = wx * 32 + nb * 16 + m;
      float bv = bias[col];
      int rl0 = wy * 64 + mb * 16 + quad * 4;
      u16x4 pk;
#pragma unroll
      for (int p = 0; p < 4; p++) {
        size_t rid = rowbase + rl0 + p;
        float hc = tanhf(accg[mb][nb][p] + bv);
        size_t idx = rid * 64 + col;
        float rr = bf_to_f(Rb[idx]);
        float hn = rr * h[idx] + (1.f - rr) * hc;
        h[idx] = hn;
        u16 vh = bf_rne(hn);
        XAo[rid * SA + off_next + col] = vh;
        pk[p] = vh;
        par[mb][p] = fmaf(hn, pwv2[nb], par[mb][p]);
      }
      *(u16x4*)&XhOut[(size_t)(bb * 64 + col) * Nn + i0 + rl0] = pk;
      if (col == 0 && xsrc != nullptr) {
#pragma unroll
        for (int p = 0; p < 4; p++) {
          size_t rid = rowbase + rl0 + p;
          int n = i0 + rl0 + p;
          XAo[rid * SA] = bf_rne(xsrc[(size_t)bb * TN + (size_t)tnext * Nn + n]);
          XAo[rid * SA + 66] = ye1[((size_t)(tnext * 64 + bb)) * Nn + n];
          XAo[rid * SA + 132] = ye2[((size_t)(tnext * 64 + bb)) * Nn + n];
        }
      }
    }

  if (pw2 != nullptr) {
    // cross-wave reduce: out = h @ pw + pb, plus next-step dec fill
#pragma unroll
    for (int mb = 0; mb < 4; mb++)
#pragma unroll
      for (int p = 0; p < 4; p++)
#pragma unroll
        for (int o = 8; o > 0; o >>= 1) par[mb][p] += __shfl_xor(par[mb][p], o);
    __syncthreads();  // all A-tile reads done; reuse LDS as float scratch
    float* buf = (float*)lds;
    if (m == 0) {
#pragma unroll
      for (int mb = 0; mb < 4; mb++)
#pragma unroll
        for (int p = 0; p < 4; p++)
          buf[wx * 128 + wy * 64 + mb * 16 + quad * 4 + p] = par[mb][p];
    }
    __syncthreads();
    if (tid < 128) {
      int r = tid;
      int n = i0 + r;
      size_t rid = rowbase + r;
      float s = buf[r] + buf[128 + r] + pb2[0];
      out[(size_t)bb * TN + (size_t)tt * Nn + n] = s;
      if (tt + 1 < Tc) {
        XAo[rid * SA] = bf_rne(s);
        XAo[rid * SA + 1] = bf_rne(ycov[(size_t)bb * TN + (size_t)(tt + 1) * Nn + n]);
        size_t yc = (size_t)(64 + (tt + 1) * 64 + bb) * Nn + n;
        XAo[rid * SA + 67] = yd1[yc];
        XAo[rid * SA + 133] = yd2[yc];
      }
    }
  }
}

// ---------- de = h @ FC_E ----------
__global__ __launch_bounds__(256) void k_de(const float* __restrict__ h,
                                            const float* __restrict__ fc,
                                            u16* __restrict__ Dh, u16* __restrict__ Dl) {
  __shared__ float fcs[Hc * Ec];
  for (int j = threadIdx.x; j < Hc * Ec; j += 256) fcs[j] = fc[j];
  __syncthreads();
  int idx = blockIdx.x * 256 + threadIdx.x;
  if (idx >= Nn * KD) return;
  int n = idx / KD;
  int rem = idx % KD;
  int b = rem / Ec, e = rem % Ec;
  const float* hp = h + ((size_t)b * Nn + n) * Hc;
  float acc = 0.f;
#pragma unroll 8
  for (int hh = 0; hh < Hc; hh++) acc = fmaf(hp[hh], fcs[hh * Ec + e], acc);
  u16 vh, vl;
  split_bf(acc, vh, vl);
  Dh[idx] = vh; Dl[idx] = vl;
}

extern "C" void kernel_launch(void* const* d_in, const int* in_sizes, int n_in,
                              void* d_out, int out_size, void* d_ws, size_t ws_size,
                              hipStream_t stream) {
  (void)in_sizes; (void)n_in; (void)out_size; (void)ws_size;
  const float* x    = (const float*)d_in[0];
  const float* ycov = (const float*)d_in[1];
  const float* emb  = (const float*)d_in[2];
  const float* fce  = (const float*)d_in[3];
  const float* egw  = (const float*)d_in[4];
  const float* egb  = (const float*)d_in[5];
  const float* euw  = (const float*)d_in[6];
  const float* eub  = (const float*)d_in[7];
  const float* dgw  = (const float*)d_in[8];
  const float* dgb  = (const float*)d_in[9];
  const float* duw  = (const float*)d_in[10];
  const float* dub  = (const float*)d_in[11];
  const float* pw   = (const float*)d_in[12];
  const float* pb   = (const float*)d_in[13];
  float* out = (float*)d_out;

  char* wsb = (char*)d_ws;
  size_t off = 0;
  auto alloc = [&](size_t bytes) {
    void* p = wsb + off;
    off = (off + bytes + 255) & ~(size_t)255;
    return p;
  };
  float* Gf = (float*)alloc((size_t)Nn * Nn * 4);
  u16* S1h = (u16*)alloc((size_t)Nn * Nn * 2);
  u16* S1l = (u16*)alloc((size_t)Nn * Nn * 2);
  u16* S2h = (u16*)alloc((size_t)Nn * Nn * 2);
  u16* Sth = (u16*)alloc((size_t)Nn * Nn * 2);
  u16* Stl = (u16*)alloc((size_t)Nn * Nn * 2);
  float* Hst = (float*)alloc((size_t)NB * Hc * 4);
  u16* XAh = (u16*)alloc((size_t)(NB + 4) * SA * 2);
  u16* XhA = (u16*)alloc((size_t)Bc * 64 * Nn * 2);  // h   [b*64+ch][n]
  u16* XhB = (u16*)alloc((size_t)Bc * 64 * Nn * 2);  // z*h [b*64+ch][n]
  u16* Rb = (u16*)alloc((size_t)NB * Hc * 2);
  u16* DEh = (u16*)alloc((size_t)Nn * KD * 2);
  u16* DEl = (u16*)alloc((size_t)Nn * KD * 2);
  u16* WgeH = (u16*)alloc(128 * KP * 2); u16* WgeL = (u16*)alloc(128 * KP * 2);
  u16* WueH = (u16*)alloc(64 * KP * 2);  u16* WueL = (u16*)alloc(64 * KP * 2);
  u16* WgdH = (u16*)alloc(128 * KP * 2); u16* WgdL = (u16*)alloc(128 * KP * 2);
  u16* WudH = (u16*)alloc(64 * KP * 2);  u16* WudL = (u16*)alloc(64 * KP * 2);
  u16* XxE = (u16*)alloc((size_t)NXE * Nn * 2);
  u16* YE1 = (u16*)alloc((size_t)NXE * Nn * 2);
  u16* YE2 = (u16*)alloc((size_t)NXE * Nn * 2);
  u16* XxD = (u16*)alloc((size_t)NXD * Nn * 2);
  u16* YD1 = (u16*)alloc((size_t)NXD * Nn * 2);
  u16* YD2 = (u16*)alloc((size_t)NXD * Nn * 2);

  hipMemsetAsync(Hst, 0, (size_t)NB * Hc * 4, stream);
  hipMemsetAsync(XAh, 0, (size_t)(NB + 4) * SA * 2, stream);
  hipMemsetAsync(XhA, 0, (size_t)Bc * 64 * Nn * 2, stream);

  k_prep_wt<<<(128 * KP + 255) / 256, 256, 0, stream>>>(egw, 65, 128, WgeH, WgeL);
  k_prep_wt<<<(64 * KP + 255) / 256, 256, 0, stream>>>(euw, 65, 64, WueH, WueL);
  k_prep_wt<<<(128 * KP + 255) / 256, 256, 0, stream>>>(dgw, 66, 128, WgdH, WgdL);
  k_prep_wt<<<(64 * KP + 255) / 256, 256, 0, stream>>>(duw, 66, 64, WudH, WudL);

  // encoder supports
  k_gram<<<dim3(16, 16), 256, 0, stream>>>(emb, Ec, Gf);
  k_softmax<<<Nn, 256, 0, stream>>>(Gf, S1h, S1l);
  k_tr2<<<dim3(16, 16), 256, 0, stream>>>(S1h, S1l, Sth, Stl);
  k_s2_mfma<<<128, 256, 0, stream>>>(S1h, S1l, Sth, Stl, S2h);

  // precompute Y for all encoder x-columns
  k_prep_xe<<<(NXE * Nn + 255) / 256, 256, 0, stream>>>(x, XxE);
  k_ypre<<<8 * 6, 256, 0, stream>>>(S1h, S2h, XxE, YE1, YE2);

  const int gNB = NB / 256;
  k_fill_enc<<<gNB, 256, 0, stream>>>(x, XAh, YE1, YE2);

  // enc masks: chunk8 cols {64,65,66}, chunk16 cols {132}
  for (int t = 0; t < Tc; t++) {
    k_fgate<<<512, 256, 0, stream>>>(S1h, S2h, XhA, XAh, WgeH, WgeL, egb, Hst,
                                     Rb, XAh, XhB, 1, 1, 0x07, 0x10,
                                     nullptr, nullptr);
    k_fupd<<<512, 256, 0, stream>>>(S1h, S2h, XhB, XAh, WueH, WueL, eub, Rb,
                                    Hst, XAh, XhA, (t == Tc - 1) ? 2 : 1, 1,
                                    0x07, 0x10,
                                    (t + 1 < Tc) ? x : nullptr, t + 1, YE1, YE2,
                                    nullptr, nullptr, nullptr, nullptr, nullptr,
                                    nullptr, 0);
  }

  // decoder supports
  k_de<<<(Nn * KD + 255) / 256, 256, 0, stream>>>(Hst, fce, DEh, DEl);
  k_gram_mfma<<<dim3(8, 16), 256, 0, stream>>>(DEh, DEl, Gf);
  k_softmax<<<Nn, 256, 0, stream>>>(Gf, S1h, S1l);
  k_tr2<<<dim3(16, 16), 256, 0, stream>>>(S1h, S1l, Sth, Stl);
  k_s2_mfma<<<128, 256, 0, stream>>>(S1h, S1l, Sth, Stl, S2h);

  // precompute Y for decoder go0 + ycov columns
  k_prep_xd<<<(NXD * Nn + 255) / 256, 256, 0, stream>>>(x, ycov, XxD);
  k_ypre<<<8 * 7, 256, 0, stream>>>(S1h, S2h, XxD, YD1, YD2);

  k_dec_init<<<gNB, 256, 0, stream>>>(x, ycov, XAh, YD1, YD2);

  // dec masks: t=0 chunk8 {64,65,66,67}/chunk16 {132,133};
  //            t>0 gate: {64,65,67}/{133} + derived go-col; upd: full.
  for (int t = 0; t < Tc; t++) {
    k_fgate<<<512, 256, 0, stream>>>(S1h, S2h, XhA, XAh, WgdH, WgdL, dgb, Hst,
                                     Rb, XAh, XhB, 2, 2,
                                     (t == 0) ? 0x0F : 0x0B,
                                     (t == 0) ? 0x30 : 0x20,
                                     (t > 0) ? pw : nullptr, pb);
    k_fupd<<<512, 256, 0, stream>>>(S1h, S2h, XhB, XAh, WudH, WudL, dub, Rb,
                                    Hst, XAh, XhA, 2, 2, 0x0F, 0x30,
                                    nullptr, 0, nullptr, nullptr,
                                    pw, pb, ycov, YD1, YD2, out, t);
  }
}

// Round 6
// 2479.760 us; speedup vs baseline: 2.5793x; 1.0096x over previous
//
#include <hip/hip_runtime.h>
#include <math.h>

typedef __attribute__((ext_vector_type(8))) short bf16x8;
typedef __attribute__((ext_vector_type(4))) float f32x4;
typedef unsigned short u16;
typedef __attribute__((ext_vector_type(4))) unsigned short u16x4;

namespace {
constexpr int Bc = 64, Tc = 12, Nn = 1024, Hc = 64, Ec = 10;
constexpr int NB = Nn * Bc;  // 65536
constexpr int Cc = 66;       // unified channel count
constexpr int SA = 208;      // XA row stride ([X(66)|Y1(66)|Y2(66)|pad10])
constexpr int KP = 224;      // padded K for gate/update GEMMs (7 x 32)
constexpr int KD = Bc * Ec;  // 640, dec gram K
constexpr int TN = Tc * Nn;  // 12288
constexpr int NXE = 768;     // enc precompute cols: 12t x 64b
constexpr int NXD = 896;     // dec precompute cols: go0(64) + 12t x 64b + pad
// Row index convention: rid = b*Nn + n  (b outer, n inner).
}

#define SWZ(r) (((r) >> 1) & 3)
#define SW8(r) ((r) & 7)

__device__ __forceinline__ void gld16(const void* g, void* l) {
  __builtin_amdgcn_global_load_lds(
      (const __attribute__((address_space(1))) void*)g,
      (__attribute__((address_space(3))) void*)l, 16, 0, 0);
}

__device__ __forceinline__ void split_bf(float v, u16& h, u16& l) {
  unsigned u = __float_as_uint(v);
  unsigned hu = (u + 0x7FFFu + ((u >> 16) & 1u)) & 0xFFFF0000u;
  h = (u16)(hu >> 16);
  float r = v - __uint_as_float(hu);
  unsigned u2 = __float_as_uint(r);
  l = (u16)((u2 + 0x7FFFu + ((u2 >> 16) & 1u)) >> 16);
}
__device__ __forceinline__ u16 bf_rne(float v) {
  unsigned u = __float_as_uint(v);
  return (u16)((u + 0x7FFFu + ((u >> 16) & 1u)) >> 16);
}
__device__ __forceinline__ float bf_to_f(u16 v) {
  return __uint_as_float(((unsigned)v) << 16);
}
__device__ __forceinline__ bf16x8 ldfrag(const u16* p) { return *(const bf16x8*)p; }

// A-tile LDS address (Y region only, kt 2..6): [(kt-2)][slot r*4 + (j4^SWZ(r))][8]
__device__ __forceinline__ int atile(int r, int col) {
  return (((col >> 5) - 2) * 4096) + ((r * 4 + (((col >> 3) & 3) ^ SWZ(r))) * 8) + (col & 7);
}

// ---------- enc gram: G = emb @ emb^T ----------
__global__ __launch_bounds__(256) void k_gram(const float* __restrict__ in, int Kd,
                                              float* __restrict__ G) {
  __shared__ float At[16][64];
  __shared__ float Bt[16][64];
  int i0 = blockIdx.y * 64, j0 = blockIdx.x * 64;
  int tx = threadIdx.x & 15, ty = threadIdx.x >> 4;
  float acc[4][4] = {};
  for (int k0 = 0; k0 < Kd; k0 += 16) {
    for (int u = threadIdx.x; u < 1024; u += 256) {
      int i = u >> 4, k = u & 15;
      At[k][i] = (k0 + k < Kd) ? in[(size_t)(i0 + i) * Kd + k0 + k] : 0.f;
    }
    for (int u = threadIdx.x; u < 1024; u += 256) {
      int j = u >> 4, k = u & 15;
      Bt[k][j] = (k0 + k < Kd) ? in[(size_t)(j0 + j) * Kd + k0 + k] : 0.f;
    }
    __syncthreads();
#pragma unroll
    for (int kk = 0; kk < 16; kk++) {
      float a[4], b[4];
#pragma unroll
      for (int p = 0; p < 4; p++) a[p] = At[kk][ty * 4 + p];
#pragma unroll
      for (int q = 0; q < 4; q++) b[q] = Bt[kk][tx * 4 + q];
#pragma unroll
      for (int p = 0; p < 4; p++)
#pragma unroll
        for (int q = 0; q < 4; q++) acc[p][q] = fmaf(a[p], b[q], acc[p][q]);
    }
    __syncthreads();
  }
  for (int p = 0; p < 4; p++)
    for (int q = 0; q < 4; q++)
      G[(size_t)(i0 + ty * 4 + p) * Nn + j0 + tx * 4 + q] = acc[p][q];
}

// ---------- dec gram via split-MFMA ----------
__global__ __launch_bounds__(256) void k_gram_mfma(const u16* __restrict__ Dh,
                                                   const u16* __restrict__ Dl,
                                                   float* __restrict__ G) {
  __shared__ u16 lds[12288];
  const int tid = threadIdx.x;
  const int wave = tid >> 6, lane = tid & 63;
  const int i0 = blockIdx.y * 64;
  const int j0 = blockIdx.x * 128;
  const int wy = wave >> 1, wx = wave & 1;
  const int m = lane & 15, quad = lane >> 4;

  f32x4 acc[2][4];
  f32x4 z4 = {0.f, 0.f, 0.f, 0.f};
#pragma unroll
  for (int a = 0; a < 2; a++)
#pragma unroll
    for (int q = 0; q < 4; q++) acc[a][q] = z4;

  const int ar = tid >> 2;
  const int akc = (tid & 3) ^ SWZ(ar);

  for (int k0 = 0; k0 < KD; k0 += 32) {
    gld16(Dh + (size_t)(i0 + ar) * KD + k0 + akc * 8, &lds[wave * 512]);
    gld16(Dl + (size_t)(i0 + ar) * KD + k0 + akc * 8, &lds[2048 + wave * 512]);
#pragma unroll
    for (int p = 0; p < 2; p++) {
      int r = p * 64 + (tid >> 2);
      int kc = (tid & 3) ^ SWZ(r);
      gld16(Dh + (size_t)(j0 + r) * KD + k0 + kc * 8, &lds[4096 + p * 2048 + wave * 512]);
      gld16(Dl + (size_t)(j0 + r) * KD + k0 + kc * 8, &lds[8192 + p * 2048 + wave * 512]);
    }
    __syncthreads();

    bf16x8 ah[2], al[2], bh[4], bl[4];
#pragma unroll
    for (int mb = 0; mb < 2; mb++) {
      int r = wy * 32 + mb * 16 + m;
      int ci = r * 4 + (quad ^ SWZ(r));
      ah[mb] = *(const bf16x8*)&lds[ci * 8];
      al[mb] = *(const bf16x8*)&lds[2048 + ci * 8];
    }
#pragma unroll
    for (int nb = 0; nb < 4; nb++) {
      int rj = wx * 64 + nb * 16 + m;
      int cj = rj * 4 + (quad ^ SWZ(rj));
      bh[nb] = *(const bf16x8*)&lds[4096 + cj * 8];
      bl[nb] = *(const bf16x8*)&lds[8192 + cj * 8];
    }
#pragma unroll
    for (int mb = 0; mb < 2; mb++)
#pragma unroll
      for (int nb = 0; nb < 4; nb++) {
        acc[mb][nb] = __builtin_amdgcn_mfma_f32_16x16x32_bf16(ah[mb], bh[nb], acc[mb][nb], 0, 0, 0);
        acc[mb][nb] = __builtin_amdgcn_mfma_f32_16x16x32_bf16(ah[mb], bl[nb], acc[mb][nb], 0, 0, 0);
        acc[mb][nb] = __builtin_amdgcn_mfma_f32_16x16x32_bf16(al[mb], bh[nb], acc[mb][nb], 0, 0, 0);
      }
    __syncthreads();
  }

#pragma unroll
  for (int mb = 0; mb < 2; mb++)
#pragma unroll
    for (int nb = 0; nb < 4; nb++) {
      int col = j0 + wx * 64 + nb * 16 + m;
#pragma unroll
      for (int p = 0; p < 4; p++) {
        int row = i0 + wy * 32 + mb * 16 + quad * 4 + p;
        G[(size_t)row * Nn + col] = acc[mb][nb][p];
      }
    }
}

// ---------- S = row_softmax(relu(G)) ----------
__global__ __launch_bounds__(256) void k_softmax(const float* __restrict__ G,
                                                 u16* __restrict__ S1h,
                                                 u16* __restrict__ S1l) {
  __shared__ float sred[8];
  int n = blockIdx.x;
  float v[4];
#pragma unroll
  for (int i = 0; i < 4; i++)
    v[i] = fmaxf(G[(size_t)n * Nn + threadIdx.x + i * 256], 0.f);
  float mx = fmaxf(fmaxf(v[0], v[1]), fmaxf(v[2], v[3]));
  for (int off = 32; off > 0; off >>= 1) mx = fmaxf(mx, __shfl_down(mx, off));
  if ((threadIdx.x & 63) == 0) sred[threadIdx.x >> 6] = mx;
  __syncthreads();
  float rmax = fmaxf(fmaxf(sred[0], sred[1]), fmaxf(sred[2], sred[3]));
  float s = 0.f;
#pragma unroll
  for (int i = 0; i < 4; i++) { v[i] = expf(v[i] - rmax); s += v[i]; }
  for (int off = 32; off > 0; off >>= 1) s += __shfl_down(s, off);
  if ((threadIdx.x & 63) == 0) sred[4 + (threadIdx.x >> 6)] = s;
  __syncthreads();
  float inv = 1.f / (sred[4] + sred[5] + sred[6] + sred[7]);
#pragma unroll
  for (int i = 0; i < 4; i++) {
    u16 h, l;
    split_bf(v[i] * inv, h, l);
    size_t a = (size_t)n * Nn + threadIdx.x + i * 256;
    S1h[a] = h; S1l[a] = l;
  }
}

// ---------- transpose ----------
__global__ __launch_bounds__(256) void k_tr2(const u16* __restrict__ Ah,
                                             const u16* __restrict__ Al,
                                             u16* __restrict__ Th, u16* __restrict__ Tl) {
  __shared__ u16 sm[64][72];
  int i0 = blockIdx.y * 64, j0 = blockIdx.x * 64;
  int tid = threadIdx.x;
  for (int pass = 0; pass < 2; pass++) {
    const u16* src = pass ? Al : Ah;
    u16* dst = pass ? Tl : Th;
    for (int u = tid; u < 4096; u += 256) {
      int i = u >> 6, c = u & 63;
      sm[i][c] = src[(size_t)(i0 + i) * Nn + j0 + c];
    }
    __syncthreads();
    for (int u = tid; u < 4096; u += 256) {
      int c = u >> 6, i = u & 63;
      dst[(size_t)(j0 + c) * Nn + i0 + i] = sm[i][c];
    }
    __syncthreads();
  }
}

// ---------- S2 = 2*S@S - I ----------
__global__ __launch_bounds__(256) void k_s2_mfma(const u16* __restrict__ S1h,
                                                 const u16* __restrict__ S1l,
                                                 const u16* __restrict__ Sth,
                                                 const u16* __restrict__ Stl,
                                                 u16* __restrict__ S2h) {
  const int tid = threadIdx.x;
  const int wave = tid >> 6, lane = tid & 63;
  const int blk = blockIdx.x;
  const int s = blk >> 3;
  const int i0 = ((blk & 7) * 2 + (s & 1)) * 64;
  const int j0 = (s >> 1) * 128;
  const int wy = wave >> 1, wx = wave & 1;
  const int m = lane & 15, quad = lane >> 4;

  const size_t aoff = (size_t)(i0 + wy * 32 + m) * Nn + quad * 8;
  const size_t boff = (size_t)(j0 + wx * 64 + m) * Nn + quad * 8;

  f32x4 acc[2][4];
  f32x4 z4 = {0.f, 0.f, 0.f, 0.f};
#pragma unroll
  for (int a = 0; a < 2; a++)
#pragma unroll
    for (int q = 0; q < 4; q++) acc[a][q] = z4;

  bf16x8 fAh[2][2], fAl[2][2], fBh[2][4], fBl[2][4];
  auto ld = [&](int k0, int sb) {
#pragma unroll
    for (int mb = 0; mb < 2; mb++) {
      fAh[sb][mb] = ldfrag(S1h + aoff + (size_t)mb * 16 * Nn + k0);
      fAl[sb][mb] = ldfrag(S1l + aoff + (size_t)mb * 16 * Nn + k0);
    }
#pragma unroll
    for (int nb = 0; nb < 4; nb++) {
      fBh[sb][nb] = ldfrag(Sth + boff + (size_t)nb * 16 * Nn + k0);
      fBl[sb][nb] = ldfrag(Stl + boff + (size_t)nb * 16 * Nn + k0);
    }
  };
  ld(0, 0);
#pragma unroll 2
  for (int kt = 0; kt < 32; kt++) {
    int cur = kt & 1;
    if (kt < 31) ld((kt + 1) * 32, cur ^ 1);
#pragma unroll
    for (int mb = 0; mb < 2; mb++)
#pragma unroll
      for (int nb = 0; nb < 4; nb++) {
        acc[mb][nb] = __builtin_amdgcn_mfma_f32_16x16x32_bf16(fAh[cur][mb], fBh[cur][nb], acc[mb][nb], 0, 0, 0);
        acc[mb][nb] = __builtin_amdgcn_mfma_f32_16x16x32_bf16(fAh[cur][mb], fBl[cur][nb], acc[mb][nb], 0, 0, 0);
        acc[mb][nb] = __builtin_amdgcn_mfma_f32_16x16x32_bf16(fAl[cur][mb], fBh[cur][nb], acc[mb][nb], 0, 0, 0);
      }
  }

#pragma unroll
  for (int mb = 0; mb < 2; mb++)
#pragma unroll
    for (int nb = 0; nb < 4; nb++) {
      int col = j0 + wx * 64 + nb * 16 + m;
#pragma unroll
      for (int p = 0; p < 4; p++) {
        int row = i0 + wy * 32 + mb * 16 + quad * 4 + p;
        float v = 2.f * acc[mb][nb][p] - (row == col ? 1.f : 0.f);
        S2h[(size_t)row * Nn + col] = bf_rne(v);
      }
    }
}

// ---------- Wt prep ----------
__global__ __launch_bounds__(256) void k_prep_wt(const float* __restrict__ W, int Csrc,
                                                 int ncol, u16* __restrict__ Wh,
                                                 u16* __restrict__ Wl) {
  int idx = blockIdx.x * 256 + threadIdx.x;
  if (idx >= ncol * KP) return;
  int n = idx / KP, kp = idx % KP;
  int chunk = kp / Cc, c = kp % Cc;
  float v = 0.f;
  if (kp < 3 * Cc && c < Csrc) v = W[((size_t)chunk * Csrc + c) * ncol + n];
  u16 h, l;
  split_bf(v, h, l);
  Wh[idx] = h; Wl[idx] = l;
}

// ---------- precompute B operands ----------
__global__ __launch_bounds__(256) void k_prep_xe(const float* __restrict__ x,
                                                 u16* __restrict__ Xx) {
  int idx = blockIdx.x * 256 + threadIdx.x;
  if (idx >= NXE * Nn) return;
  int col = idx >> 10, n = idx & (Nn - 1);
  int t = col >> 6, b = col & 63;
  Xx[idx] = bf_rne(x[(size_t)b * TN + (size_t)t * Nn + n]);
}

__global__ __launch_bounds__(256) void k_prep_xd(const float* __restrict__ x,
                                                 const float* __restrict__ ycov,
                                                 u16* __restrict__ Xx) {
  int idx = blockIdx.x * 256 + threadIdx.x;
  if (idx >= NXD * Nn) return;
  int col = idx >> 10, n = idx & (Nn - 1);
  float v = 0.f;
  if (col < 64) {
    v = x[(size_t)col * TN + (size_t)(Tc - 1) * Nn + n];
  } else if (col < 64 + Tc * 64) {
    int t = (col - 64) >> 6, b = (col - 64) & 63;
    v = ycov[(size_t)b * TN + (size_t)t * Nn + n];
  }
  Xx[idx] = bf_rne(v);
}

// ---------- ypre: Y1 = S1@Xx, Y2 = S2@Xx (x-derived Y cols) ----------
__global__ __launch_bounds__(256, 2) void k_ypre(const u16* __restrict__ S1h,
                                                 const u16* __restrict__ S2h,
                                                 const u16* __restrict__ Xx,
                                                 u16* __restrict__ Yo1,
                                                 u16* __restrict__ Yo2) {
  __shared__ u16 lds[24576];
  const int tid = threadIdx.x;
  const int wave = tid >> 6;
  const int lane = tid & 63;
  const int blk = blockIdx.x;
  const int i0 = (blk & 7) * 128;
  const int j0 = (blk >> 3) * 128;
  const int wy = wave >> 1, wx = wave & 1;
  const int m = lane & 15, quad = lane >> 4;

  f32x4 acc1[4][4], acc2[4][4];
  f32x4 z4 = {0.f, 0.f, 0.f, 0.f};
#pragma unroll
  for (int a = 0; a < 4; a++)
#pragma unroll
    for (int q = 0; q < 4; q++) { acc1[a][q] = z4; acc2[a][q] = z4; }

  for (int k0 = 0; k0 < Nn; k0 += 64) {
#pragma unroll
    for (int c = 0; c < 4; c++) {
      int ci = c * 256 + tid;
      int r = ci >> 3, kc = (ci & 7) ^ SW8(r);
      gld16(S1h + (size_t)(i0 + r) * Nn + k0 + kc * 8, &lds[c * 2048 + wave * 512]);
      gld16(S2h + (size_t)(i0 + r) * Nn + k0 + kc * 8, &lds[8192 + c * 2048 + wave * 512]);
      gld16(Xx + (size_t)(j0 + r) * Nn + k0 + kc * 8, &lds[16384 + c * 2048 + wave * 512]);
    }
    __syncthreads();

#pragma unroll
    for (int ks = 0; ks < 2; ks++) {
      bf16x8 bfr[4];
#pragma unroll
      for (int nb = 0; nb < 4; nb++) {
        int rj = wx * 64 + nb * 16 + m;
        int cj = rj * 8 + ((ks * 4 + quad) ^ SW8(rj));
        bfr[nb] = *(const bf16x8*)&lds[16384 + cj * 8];
      }
      bf16x8 a1[4], a2[4];
#pragma unroll
      for (int mb = 0; mb < 4; mb++) {
        int r = wy * 64 + mb * 16 + m;
        int ci = r * 8 + ((ks * 4 + quad) ^ SW8(r));
        a1[mb] = *(const bf16x8*)&lds[ci * 8];
        a2[mb] = *(const bf16x8*)&lds[8192 + ci * 8];
      }
#pragma unroll
      for (int mb = 0; mb < 4; mb++)
#pragma unroll
        for (int nb = 0; nb < 4; nb++) {
          acc1[mb][nb] = __builtin_amdgcn_mfma_f32_16x16x32_bf16(a1[mb], bfr[nb], acc1[mb][nb], 0, 0, 0);
          acc2[mb][nb] = __builtin_amdgcn_mfma_f32_16x16x32_bf16(a2[mb], bfr[nb], acc2[mb][nb], 0, 0, 0);
        }
    }
    __syncthreads();
  }

#pragma unroll
  for (int mb = 0; mb < 4; mb++)
#pragma unroll
    for (int nb = 0; nb < 4; nb++) {
      int col = j0 + wx * 64 + nb * 16 + m;
#pragma unroll
      for (int p = 0; p < 4; p++) {
        int n = i0 + wy * 64 + mb * 16 + quad * 4 + p;
        Yo1[(size_t)col * Nn + n] = bf_rne(acc1[mb][nb][p]);
        Yo2[(size_t)col * Nn + n] = bf_rne(acc2[mb][nb][p]);
      }
    }
}

// ---------- fill enc t=0 ----------
__global__ __launch_bounds__(256) void k_fill_enc(const float* __restrict__ x,
                                                  u16* __restrict__ XAh,
                                                  const u16* __restrict__ ye1,
                                                  const u16* __restrict__ ye2) {
  int idx = blockIdx.x * 256 + threadIdx.x;
  if (idx >= NB) return;
  int n = idx & (Nn - 1), b = idx >> 10;
  XAh[(size_t)idx * SA] = bf_rne(x[(size_t)b * TN + n]);
  XAh[(size_t)idx * SA + 66] = ye1[(size_t)b * Nn + n];
  XAh[(size_t)idx * SA + 132] = ye2[(size_t)b * Nn + n];
}

// ---------- dec init ----------
__global__ __launch_bounds__(256) void k_dec_init(const float* __restrict__ x,
                                                  const float* __restrict__ ycov,
                                                  u16* __restrict__ XAh,
                                                  const u16* __restrict__ yd1,
                                                  const u16* __restrict__ yd2) {
  int idx = blockIdx.x * 256 + threadIdx.x;
  if (idx >= NB) return;
  int n = idx & (Nn - 1), b = idx >> 10;
  XAh[(size_t)idx * SA] = bf_rne(x[(size_t)b * TN + (size_t)(Tc - 1) * Nn + n]);
  XAh[(size_t)idx * SA + 1] = bf_rne(ycov[(size_t)b * TN + n]);
  XAh[(size_t)idx * SA + 66] = yd1[(size_t)b * Nn + n];
  XAh[(size_t)idx * SA + 67] = yd1[(size_t)(64 + b) * Nn + n];
  XAh[(size_t)idx * SA + 132] = yd2[(size_t)b * Nn + n];
  XAh[(size_t)idx * SA + 133] = yd2[(size_t)(64 + b) * Nn + n];
}

// ================= FUSED ygemm + gate =================
// Grid 512: i0 = (blk&7)*128, bb = blk>>3. LDS = 40KB (phase1 staging 40KB
// UNION Y-only A-tile kt2..6 40KB) -> 4 blocks/CU (VGPR 128 = 4 waves/SIMD).
// Phase 3 reads kt0/kt1 (pure-X cols 0..63) A-fragments DIRECT from XA global
// (L2-hot), so the A-tile holds only the Y region. Masked chunk writes provide
// all needed zeros; K-pad garbage multiplies W=0.
__global__ __launch_bounds__(256) void k_fgate(
    const u16* __restrict__ S1h, const u16* __restrict__ S2h,
    const u16* __restrict__ XhIn, const u16* XA,
    const u16* __restrict__ Wh, const u16* __restrict__ Wl,
    const float* __restrict__ bias, const float* __restrict__ hst,
    u16* __restrict__ Rb, u16* XAo, u16* __restrict__ XhOut,
    int off, int yoff, int m8, int m16,
    const float* __restrict__ pw, const float* __restrict__ pb) {
  __shared__ u16 lds[20480];  // 40KB
  const int tid = threadIdx.x;
  const int wave = tid >> 6, lane = tid & 63;
  const int i0 = (blockIdx.x & 7) * 128;
  const int bb = blockIdx.x >> 3;
  const int m = lane & 15, quad = lane >> 4;
  const size_t rowbase = (size_t)bb * Nn + i0;

  // ---- phase 1 ----
  f32x4 acc1[2][4], acc2[2][4];
  f32x4 z4 = {0.f, 0.f, 0.f, 0.f};
#pragma unroll
  for (int a = 0; a < 2; a++)
#pragma unroll
    for (int q = 0; q < 4; q++) { acc1[a][q] = z4; acc2[a][q] = z4; }

  for (int k0 = 0; k0 < Nn; k0 += 64) {
#pragma unroll
    for (int c = 0; c < 4; c++) {
      int ci = c * 256 + tid;
      int r = ci >> 3, kc = (ci & 7) ^ SW8(r);
      gld16(S1h + (size_t)(i0 + r) * Nn + k0 + kc * 8, &lds[c * 2048 + wave * 512]);
      gld16(S2h + (size_t)(i0 + r) * Nn + k0 + kc * 8, &lds[8192 + c * 2048 + wave * 512]);
    }
#pragma unroll
    for (int c = 0; c < 2; c++) {
      int ci = c * 256 + tid;
      int r = ci >> 3, kc = (ci & 7) ^ SW8(r);
      gld16(XhIn + (size_t)(bb * 64 + r) * Nn + k0 + kc * 8, &lds[16384 + c * 2048 + wave * 512]);
    }
    __syncthreads();
#pragma unroll
    for (int ks = 0; ks < 2; ks++) {
      bf16x8 bfr[4];
#pragma unroll
      for (int nb = 0; nb < 4; nb++) {
        int rj = nb * 16 + m;
        int cj = rj * 8 + ((ks * 4 + quad) ^ SW8(rj));
        bfr[nb] = *(const bf16x8*)&lds[16384 + cj * 8];
      }
      bf16x8 a1[2], a2[2];
#pragma unroll
      for (int mb = 0; mb < 2; mb++) {
        int r = wave * 32 + mb * 16 + m;
        int ci = r * 8 + ((ks * 4 + quad) ^ SW8(r));
        a1[mb] = *(const bf16x8*)&lds[ci * 8];
        a2[mb] = *(const bf16x8*)&lds[8192 + ci * 8];
      }
#pragma unroll
      for (int mb = 0; mb < 2; mb++)
#pragma unroll
        for (int nb = 0; nb < 4; nb++) {
          acc1[mb][nb] = __builtin_amdgcn_mfma_f32_16x16x32_bf16(a1[mb], bfr[nb], acc1[mb][nb], 0, 0, 0);
          acc2[mb][nb] = __builtin_amdgcn_mfma_f32_16x16x32_bf16(a2[mb], bfr[nb], acc2[mb][nb], 0, 0, 0);
        }
    }
    __syncthreads();
  }

  // ---- phase 2: Y-only A-tile (kt2..6). Masked chunks zero their full width. ----
  {
    int r = tid >> 1;
    int cc = (tid & 1) ? 16 : 8;
    int msk = (tid & 1) ? m16 : m8;
    const u16* src = XA + (rowbase + r) * SA + cc * 8;
    bf16x8 v;
#pragma unroll
    for (int j = 0; j < 8; j++) v[j] = (short)(((msk >> j) & 1) ? src[j] : 0);
    *(bf16x8*)&lds[((cc >> 2) - 2) * 4096 + (r * 4 + SWZ(r)) * 8] = v;
  }
  __syncthreads();
  {
    const int yb1 = 66 + yoff, yb2 = 132 + yoff;
#pragma unroll
    for (int mb = 0; mb < 2; mb++)
#pragma unroll
      for (int nb = 0; nb < 4; nb++)
#pragma unroll
        for (int p = 0; p < 4; p++) {
          int r = wave * 32 + mb * 16 + quad * 4 + p;
          int ch = nb * 16 + m;
          lds[atile(r, yb1 + ch)] = bf_rne(acc1[mb][nb][p]);
          lds[atile(r, yb2 + ch)] = bf_rne(acc2[mb][nb][p]);
        }
    if (pw != nullptr) {
      float pb0 = pb[0];
      float pwv[4];
#pragma unroll
      for (int nb = 0; nb < 4; nb++) pwv[nb] = pw[nb * 16 + m];
#pragma unroll
      for (int mb = 0; mb < 2; mb++)
#pragma unroll
        for (int p = 0; p < 4; p++) {
          float s1 = 0.f, s2 = 0.f;
#pragma unroll
          for (int nb = 0; nb < 4; nb++) {
            s1 = fmaf(acc1[mb][nb][p], pwv[nb], s1);
            s2 = fmaf(acc2[mb][nb][p], pwv[nb], s2);
          }
#pragma unroll
          for (int o = 8; o > 0; o >>= 1) { s1 += __shfl_xor(s1, o); s2 += __shfl_xor(s2, o); }
          if (m == 0) {
            int r = wave * 32 + mb * 16 + quad * 4 + p;
            u16 v1 = bf_rne(s1 + pb0), v2 = bf_rne(s2 + pb0);
            lds[atile(r, 66)] = v1;
            lds[atile(r, 132)] = v2;
            XAo[(rowbase + r) * SA + 66] = v1;
            XAo[(rowbase + r) * SA + 132] = v2;
          }
        }
    }
  }
  __syncthreads();

  // ---- phase 3: gate GEMM (A: kt0/1 direct-global, kt2..6 LDS) ----
  f32x4 accg[4][4];
#pragma unroll
  for (int a = 0; a < 4; a++)
#pragma unroll
    for (int q = 0; q < 4; q++) accg[a][q] = z4;
  const int wy = wave >> 1, wx = wave & 1;
  const size_t wboff = (size_t)(wx * 64 + m) * KP + quad * 8;
#pragma unroll
  for (int kt = 0; kt < 7; kt++) {
    int k0 = kt * 32;
    bf16x8 af[4], bh[4], bl[4];
#pragma unroll
    for (int mb = 0; mb < 4; mb++) {
      int r = wy * 64 + mb * 16 + m;
      if (kt < 2)
        af[mb] = ldfrag(XA + (rowbase + r) * SA + k0 + quad * 8);
      else
        af[mb] = *(const bf16x8*)&lds[(kt - 2) * 4096 + (r * 4 + (quad ^ SWZ(r))) * 8];
    }
#pragma unroll
    for (int nb = 0; nb < 4; nb++) {
      bh[nb] = ldfrag(Wh + wboff + (size_t)nb * 16 * KP + k0);
      bl[nb] = ldfrag(Wl + wboff + (size_t)nb * 16 * KP + k0);
    }
#pragma unroll
    for (int mb = 0; mb < 4; mb++)
#pragma unroll
      for (int nb = 0; nb < 4; nb++) {
        accg[mb][nb] = __builtin_amdgcn_mfma_f32_16x16x32_bf16(af[mb], bh[nb], accg[mb][nb], 0, 0, 0);
        accg[mb][nb] = __builtin_amdgcn_mfma_f32_16x16x32_bf16(af[mb], bl[nb], accg[mb][nb], 0, 0, 0);
      }
  }

  // ---- epilogue ----
#pragma unroll
  for (int mb = 0; mb < 4; mb++)
#pragma unroll
    for (int nb = 0; nb < 4; nb++) {
      int col = wx * 64 + nb * 16 + m;
      float bv = bias[col];
      int rl0 = wy * 64 + mb * 16 + quad * 4;
      if (col < 64) {
        u16x4 pk;
#pragma unroll
        for (int p = 0; p < 4; p++) {
          size_t rid = rowbase + rl0 + p;
          float sg = 1.f / (1.f + expf(-(accg[mb][nb][p] + bv)));
          u16 vh = bf_rne(sg * hst[rid * 64 + col]);
          XAo[rid * SA + off + col] = vh;
          pk[p] = vh;
        }
        *(u16x4*)&XhOut[(size_t)(bb * 64 + col) * Nn + i0 + rl0] = pk;
      } else {
#pragma unroll
        for (int p = 0; p < 4; p++) {
          size_t rid = rowbase + rl0 + p;
          float sg = 1.f / (1.f + expf(-(accg[mb][nb][p] + bv)));
          Rb[rid * 64 + col - 64] = bf_rne(sg);
        }
      }
    }
}

// ================= FUSED ygemm + update (+ optional proj/fill) =================
__global__ __launch_bounds__(256) void k_fupd(
    const u16* __restrict__ S1h, const u16* __restrict__ S2h,
    const u16* __restrict__ XhIn, const u16* XA,
    const u16* __restrict__ Wh, const u16* __restrict__ Wl,
    const float* __restrict__ bias, const u16* __restrict__ Rb,
    float* __restrict__ h, u16* XAo, u16* __restrict__ XhOut,
    int off_next, int yoff, int m8, int m16,
    const float* __restrict__ xsrc, int tnext,
    const u16* __restrict__ ye1, const u16* __restrict__ ye2,
    const float* __restrict__ pw2, const float* __restrict__ pb2,
    const float* __restrict__ ycov,
    const u16* __restrict__ yd1, const u16* __restrict__ yd2,
    float* __restrict__ out, int tt) {
  __shared__ u16 lds[20480];  // 40KB
  const int tid = threadIdx.x;
  const int wave = tid >> 6, lane = tid & 63;
  const int i0 = (blockIdx.x & 7) * 128;
  const int bb = blockIdx.x >> 3;
  const int m = lane & 15, quad = lane >> 4;
  const size_t rowbase = (size_t)bb * Nn + i0;

  // ---- phase 1: Y = S @ (z*h) ----
  f32x4 acc1[2][4], acc2[2][4];
  f32x4 z4 = {0.f, 0.f, 0.f, 0.f};
#pragma unroll
  for (int a = 0; a < 2; a++)
#pragma unroll
    for (int q = 0; q < 4; q++) { acc1[a][q] = z4; acc2[a][q] = z4; }

  for (int k0 = 0; k0 < Nn; k0 += 64) {
#pragma unroll
    for (int c = 0; c < 4; c++) {
      int ci = c * 256 + tid;
      int r = ci >> 3, kc = (ci & 7) ^ SW8(r);
      gld16(S1h + (size_t)(i0 + r) * Nn + k0 + kc * 8, &lds[c * 2048 + wave * 512]);
      gld16(S2h + (size_t)(i0 + r) * Nn + k0 + kc * 8, &lds[8192 + c * 2048 + wave * 512]);
    }
#pragma unroll
    for (int c = 0; c < 2; c++) {
      int ci = c * 256 + tid;
      int r = ci >> 3, kc = (ci & 7) ^ SW8(r);
      gld16(XhIn + (size_t)(bb * 64 + r) * Nn + k0 + kc * 8, &lds[16384 + c * 2048 + wave * 512]);
    }
    __syncthreads();
#pragma unroll
    for (int ks = 0; ks < 2; ks++) {
      bf16x8 bfr[4];
#pragma unroll
      for (int nb = 0; nb < 4; nb++) {
        int rj = nb * 16 + m;
        int cj = rj * 8 + ((ks * 4 + quad) ^ SW8(rj));
        bfr[nb] = *(const bf16x8*)&lds[16384 + cj * 8];
      }
      bf16x8 a1[2], a2[2];
#pragma unroll
      for (int mb = 0; mb < 2; mb++) {
        int r = wave * 32 + mb * 16 + m;
        int ci = r * 8 + ((ks * 4 + quad) ^ SW8(r));
        a1[mb] = *(const bf16x8*)&lds[ci * 8];
        a2[mb] = *(const bf16x8*)&lds[8192 + ci * 8];
      }
#pragma unroll
      for (int mb = 0; mb < 2; mb++)
#pragma unroll
        for (int nb = 0; nb < 4; nb++) {
          acc1[mb][nb] = __builtin_amdgcn_mfma_f32_16x16x32_bf16(a1[mb], bfr[nb], acc1[mb][nb], 0, 0, 0);
          acc2[mb][nb] = __builtin_amdgcn_mfma_f32_16x16x32_bf16(a2[mb], bfr[nb], acc2[mb][nb], 0, 0, 0);
        }
    }
    __syncthreads();
  }

  // ---- phase 2: Y-only A-tile ----
  {
    int r = tid >> 1;
    int cc = (tid & 1) ? 16 : 8;
    int msk = (tid & 1) ? m16 : m8;
    const u16* src = XA + (rowbase + r) * SA + cc * 8;
    bf16x8 v;
#pragma unroll
    for (int j = 0; j < 8; j++) v[j] = (short)(((msk >> j) & 1) ? src[j] : 0);
    *(bf16x8*)&lds[((cc >> 2) - 2) * 4096 + (r * 4 + SWZ(r)) * 8] = v;
  }
  __syncthreads();
  {
    const int yb1 = 66 + yoff, yb2 = 132 + yoff;
#pragma unroll
    for (int mb = 0; mb < 2; mb++)
#pragma unroll
      for (int nb = 0; nb < 4; nb++)
#pragma unroll
        for (int p = 0; p < 4; p++) {
          int r = wave * 32 + mb * 16 + quad * 4 + p;
          int ch = nb * 16 + m;
          lds[atile(r, yb1 + ch)] = bf_rne(acc1[mb][nb][p]);
          lds[atile(r, yb2 + ch)] = bf_rne(acc2[mb][nb][p]);
        }
  }
  __syncthreads();

  // ---- phase 3: update GEMM (N=64; A: kt0/1 direct-global, kt2..6 LDS) ----
  f32x4 accg[4][2];
#pragma unroll
  for (int a = 0; a < 4; a++) { accg[a][0] = z4; accg[a][1] = z4; }
  const int wy = wave >> 1, wx = wave & 1;
  const size_t wboff = (size_t)(wx * 32 + m) * KP + quad * 8;
#pragma unroll
  for (int kt = 0; kt < 7; kt++) {
    int k0 = kt * 32;
    bf16x8 af[4], bh[2], bl[2];
#pragma unroll
    for (int mb = 0; mb < 4; mb++) {
      int r = wy * 64 + mb * 16 + m;
      if (kt < 2)
        af[mb] = ldfrag(XA + (rowbase + r) * SA + k0 + quad * 8);
      else
        af[mb] = *(const bf16x8*)&lds[(kt - 2) * 4096 + (r * 4 + (quad ^ SWZ(r))) * 8];
    }
#pragma unroll
    for (int nb = 0; nb < 2; nb++) {
      bh[nb] = ldfrag(Wh + wboff + (size_t)nb * 16 * KP + k0);
      bl[nb] = ldfrag(Wl + wboff + (size_t)nb * 16 * KP + k0);
    }
#pragma unroll
    for (int mb = 0; mb < 4; mb++)
#pragma unroll
      for (int nb = 0; nb < 2; nb++) {
        accg[mb][nb] = __builtin_amdgcn_mfma_f32_16x16x32_bf16(af[mb], bh[nb], accg[mb][nb], 0, 0, 0);
        accg[mb][nb] = __builtin_amdgcn_mfma_f32_16x16x32_bf16(af[mb], bl[nb], accg[mb][nb], 0, 0, 0);
      }
  }

  // ---- epilogue: h update (+ partial proj) ----
  float par[4][4];
#pragma unroll
  for (int a = 0; a < 4; a++)
#pragma unroll
    for (int p = 0; p < 4; p++) par[a][p] = 0.f;
  float pwv2[2] = {0.f, 0.f};
  if (pw2 != nullptr) {
#pragma unroll
    for (int nb = 0; nb < 2; nb++) pwv2[nb] = pw2[wx * 32 + nb * 16 + m];
  }

#pragma unroll
  for (int mb = 0; mb < 4; mb++)
#pragma unroll
    for (int nb = 0; nb < 2; nb++) {
      int col = wx * 32 + nb * 16 + m;
      float bv = bias[col];
      int rl0 = wy * 64 + mb * 16 + quad * 4;
      u16x4 pk;
#pragma unroll
      for (int p = 0; p < 4; p++) {
        size_t rid = rowbase + rl0 + p;
        float hc = tanhf(accg[mb][nb][p] + bv);
        size_t idx = rid * 64 + col;
        float rr = bf_to_f(Rb[idx]);
        float hn = rr * h[idx] + (1.f - rr) * hc;
        h[idx] = hn;
        u16 vh = bf_rne(hn);
        XAo[rid * SA + off_next + col] = vh;
        pk[p] = vh;
        par[mb][p] = fmaf(hn, pwv2[nb], par[mb][p]);
      }
      *(u16x4*)&XhOut[(size_t)(bb * 64 + col) * Nn + i0 + rl0] = pk;
      if (col == 0 && xsrc != nullptr) {
#pragma unroll
        for (int p = 0; p < 4; p++) {
          size_t rid = rowbase + rl0 + p;
          int n = i0 + rl0 + p;
          XAo[rid * SA] = bf_rne(xsrc[(size_t)bb * TN + (size_t)tnext * Nn + n]);
          XAo[rid * SA + 66] = ye1[((size_t)(tnext * 64 + bb)) * Nn + n];
          XAo[rid * SA + 132] = ye2[((size_t)(tnext * 64 + bb)) * Nn + n];
        }
      }
    }

  if (pw2 != nullptr) {
    // cross-wave reduce: out = h @ pw + pb, plus next-step dec fill
#pragma unroll
    for (int mb = 0; mb < 4; mb++)
#pragma unroll
      for (int p = 0; p < 4; p++)
#pragma unroll
        for (int o = 8; o > 0; o >>= 1) par[mb][p] += __shfl_xor(par[mb][p], o);
    __syncthreads();  // all A-tile reads done; reuse LDS as float scratch
    float* buf = (float*)lds;
    if (m == 0) {
#pragma unroll
      for (int mb = 0; mb < 4; mb++)
#pragma unroll
        for (int p = 0; p < 4; p++)
          buf[wx * 128 + wy * 64 + mb * 16 + quad * 4 + p] = par[mb][p];
    }
    __syncthreads();
    if (tid < 128) {
      int r = tid;
      int n = i0 + r;
      size_t rid = rowbase + r;
      float s = buf[r] + buf[128 + r] + pb2[0];
      out[(size_t)bb * TN + (size_t)tt * Nn + n] = s;
      if (tt + 1 < Tc) {
        XAo[rid * SA] = bf_rne(s);
        XAo[rid * SA + 1] = bf_rne(ycov[(size_t)bb * TN + (size_t)(tt + 1) * Nn + n]);
        size_t yc = (size_t)(64 + (tt + 1) * 64 + bb) * Nn + n;
        XAo[rid * SA + 67] = yd1[yc];
        XAo[rid * SA + 133] = yd2[yc];
      }
    }
  }
}

// ---------- de = h @ FC_E ----------
__global__ __launch_bounds__(256) void k_de(const float* __restrict__ h,
                                            const float* __restrict__ fc,
                                            u16* __restrict__ Dh, u16* __restrict__ Dl) {
  __shared__ float fcs[Hc * Ec];
  for (int j = threadIdx.x; j < Hc * Ec; j += 256) fcs[j] = fc[j];
  __syncthreads();
  int idx = blockIdx.x * 256 + threadIdx.x;
  if (idx >= Nn * KD) return;
  int n = idx / KD;
  int rem = idx % KD;
  int b = rem / Ec, e = rem % Ec;
  const float* hp = h + ((size_t)b * Nn + n) * Hc;
  float acc = 0.f;
#pragma unroll 8
  for (int hh = 0; hh < Hc; hh++) acc = fmaf(hp[hh], fcs[hh * Ec + e], acc);
  u16 vh, vl;
  split_bf(acc, vh, vl);
  Dh[idx] = vh; Dl[idx] = vl;
}

extern "C" void kernel_launch(void* const* d_in, const int* in_sizes, int n_in,
                              void* d_out, int out_size, void* d_ws, size_t ws_size,
                              hipStream_t stream) {
  (void)in_sizes; (void)n_in; (void)out_size; (void)ws_size;
  const float* x    = (const float*)d_in[0];
  const float* ycov = (const float*)d_in[1];
  const float* emb  = (const float*)d_in[2];
  const float* fce  = (const float*)d_in[3];
  const float* egw  = (const float*)d_in[4];
  const float* egb  = (const float*)d_in[5];
  const float* euw  = (const float*)d_in[6];
  const float* eub  = (const float*)d_in[7];
  const float* dgw  = (const float*)d_in[8];
  const float* dgb  = (const float*)d_in[9];
  const float* duw  = (const float*)d_in[10];
  const float* dub  = (const float*)d_in[11];
  const float* pw   = (const float*)d_in[12];
  const float* pb   = (const float*)d_in[13];
  float* out = (float*)d_out;

  char* wsb = (char*)d_ws;
  size_t off = 0;
  auto alloc = [&](size_t bytes) {
    void* p = wsb + off;
    off = (off + bytes + 255) & ~(size_t)255;
    return p;
  };
  float* Gf = (float*)alloc((size_t)Nn * Nn * 4);
  u16* S1h = (u16*)alloc((size_t)Nn * Nn * 2);
  u16* S1l = (u16*)alloc((size_t)Nn * Nn * 2);
  u16* S2h = (u16*)alloc((size_t)Nn * Nn * 2);
  u16* Sth = (u16*)alloc((size_t)Nn * Nn * 2);
  u16* Stl = (u16*)alloc((size_t)Nn * Nn * 2);
  float* Hst = (float*)alloc((size_t)NB * Hc * 4);
  u16* XAh = (u16*)alloc((size_t)(NB + 4) * SA * 2);
  u16* XhA = (u16*)alloc((size_t)Bc * 64 * Nn * 2);  // h   [b*64+ch][n]
  u16* XhB = (u16*)alloc((size_t)Bc * 64 * Nn * 2);  // z*h [b*64+ch][n]
  u16* Rb = (u16*)alloc((size_t)NB * Hc * 2);
  u16* DEh = (u16*)alloc((size_t)Nn * KD * 2);
  u16* DEl = (u16*)alloc((size_t)Nn * KD * 2);
  u16* WgeH = (u16*)alloc(128 * KP * 2); u16* WgeL = (u16*)alloc(128 * KP * 2);
  u16* WueH = (u16*)alloc(64 * KP * 2);  u16* WueL = (u16*)alloc(64 * KP * 2);
  u16* WgdH = (u16*)alloc(128 * KP * 2); u16* WgdL = (u16*)alloc(128 * KP * 2);
  u16* WudH = (u16*)alloc(64 * KP * 2);  u16* WudL = (u16*)alloc(64 * KP * 2);
  u16* XxE = (u16*)alloc((size_t)NXE * Nn * 2);
  u16* YE1 = (u16*)alloc((size_t)NXE * Nn * 2);
  u16* YE2 = (u16*)alloc((size_t)NXE * Nn * 2);
  u16* XxD = (u16*)alloc((size_t)NXD * Nn * 2);
  u16* YD1 = (u16*)alloc((size_t)NXD * Nn * 2);
  u16* YD2 = (u16*)alloc((size_t)NXD * Nn * 2);

  hipMemsetAsync(Hst, 0, (size_t)NB * Hc * 4, stream);
  hipMemsetAsync(XAh, 0, (size_t)(NB + 4) * SA * 2, stream);
  hipMemsetAsync(XhA, 0, (size_t)Bc * 64 * Nn * 2, stream);

  k_prep_wt<<<(128 * KP + 255) / 256, 256, 0, stream>>>(egw, 65, 128, WgeH, WgeL);
  k_prep_wt<<<(64 * KP + 255) / 256, 256, 0, stream>>>(euw, 65, 64, WueH, WueL);
  k_prep_wt<<<(128 * KP + 255) / 256, 256, 0, stream>>>(dgw, 66, 128, WgdH, WgdL);
  k_prep_wt<<<(64 * KP + 255) / 256, 256, 0, stream>>>(duw, 66, 64, WudH, WudL);

  // encoder supports
  k_gram<<<dim3(16, 16), 256, 0, stream>>>(emb, Ec, Gf);
  k_softmax<<<Nn, 256, 0, stream>>>(Gf, S1h, S1l);
  k_tr2<<<dim3(16, 16), 256, 0, stream>>>(S1h, S1l, Sth, Stl);
  k_s2_mfma<<<128, 256, 0, stream>>>(S1h, S1l, Sth, Stl, S2h);

  // precompute Y for all encoder x-columns
  k_prep_xe<<<(NXE * Nn + 255) / 256, 256, 0, stream>>>(x, XxE);
  k_ypre<<<8 * 6, 256, 0, stream>>>(S1h, S2h, XxE, YE1, YE2);

  const int gNB = NB / 256;
  k_fill_enc<<<gNB, 256, 0, stream>>>(x, XAh, YE1, YE2);

  // enc masks: chunk8 cols {64,65,66}, chunk16 cols {132}
  for (int t = 0; t < Tc; t++) {
    k_fgate<<<512, 256, 0, stream>>>(S1h, S2h, XhA, XAh, WgeH, WgeL, egb, Hst,
                                     Rb, XAh, XhB, 1, 1, 0x07, 0x10,
                                     nullptr, nullptr);
    k_fupd<<<512, 256, 0, stream>>>(S1h, S2h, XhB, XAh, WueH, WueL, eub, Rb,
                                    Hst, XAh, XhA, (t == Tc - 1) ? 2 : 1, 1,
                                    0x07, 0x10,
                                    (t + 1 < Tc) ? x : nullptr, t + 1, YE1, YE2,
                                    nullptr, nullptr, nullptr, nullptr, nullptr,
                                    nullptr, 0);
  }

  // decoder supports
  k_de<<<(Nn * KD + 255) / 256, 256, 0, stream>>>(Hst, fce, DEh, DEl);
  k_gram_mfma<<<dim3(8, 16), 256, 0, stream>>>(DEh, DEl, Gf);
  k_softmax<<<Nn, 256, 0, stream>>>(Gf, S1h, S1l);
  k_tr2<<<dim3(16, 16), 256, 0, stream>>>(S1h, S1l, Sth, Stl);
  k_s2_mfma<<<128, 256, 0, stream>>>(S1h, S1l, Sth, Stl, S2h);

  // precompute Y for decoder go0 + ycov columns
  k_prep_xd<<<(NXD * Nn + 255) / 256, 256, 0, stream>>>(x, ycov, XxD);
  k_ypre<<<8 * 7, 256, 0, stream>>>(S1h, S2h, XxD, YD1, YD2);

  k_dec_init<<<gNB, 256, 0, stream>>>(x, ycov, XAh, YD1, YD2);

  // dec masks: t=0 chunk8 {64,65,66,67}/chunk16 {132,133};
  //            t>0 gate: {64,65,67}/{133} + derived go-col; upd: full.
  for (int t = 0; t < Tc; t++) {
    k_fgate<<<512, 256, 0, stream>>>(S1h, S2h, XhA, XAh, WgdH, WgdL, dgb, Hst,
                                     Rb, XAh, XhB, 2, 2,
                                     (t == 0) ? 0x0F : 0x0B,
                                     (t == 0) ? 0x30 : 0x20,
                                     (t > 0) ? pw : nullptr, pb);
    k_fupd<<<512, 256, 0, stream>>>(S1h, S2h, XhB, XAh, WudH, WudL, dub, Rb,
                                    Hst, XAh, XhA, 2, 2, 0x0F, 0x30,
                                    nullptr, 0, nullptr, nullptr,
                                    pw, pb, ycov, YD1, YD2, out, t);
  }
}

// Round 7
// 2219.648 us; speedup vs baseline: 2.8816x; 1.1172x over previous
//
#include <hip/hip_runtime.h>
#include <math.h>

typedef __attribute__((ext_vector_type(8))) short bf16x8;
typedef __attribute__((ext_vector_type(4))) float f32x4;
typedef unsigned short u16;
typedef __attribute__((ext_vector_type(4))) unsigned short u16x4;

namespace {
constexpr int Bc = 64, Tc = 12, Nn = 1024, Hc = 64, Ec = 10;
constexpr int NB = Nn * Bc;  // 65536
constexpr int Cc = 66;       // unified channel count
constexpr int SA = 208;      // XA row stride ([X(66)|Y1(66)|Y2(66)|pad10])
constexpr int KP = 224;      // padded K for gate/update GEMMs (7 x 32)
constexpr int KD = Bc * Ec;  // 640, dec gram K
constexpr int TN = Tc * Nn;  // 12288
constexpr int NXE = 768;     // enc precompute cols: 12t x 64b
constexpr int NXD = 896;     // dec precompute cols: go0(64) + 12t x 64b + pad
// Row index convention: rid = b*Nn + n  (b outer, n inner).
}

#define SWZ(r) (((r) >> 1) & 3)
#define SW8(r) ((r) & 7)

__device__ __forceinline__ void gld16(const void* g, void* l) {
  __builtin_amdgcn_global_load_lds(
      (const __attribute__((address_space(1))) void*)g,
      (__attribute__((address_space(3))) void*)l, 16, 0, 0);
}

__device__ __forceinline__ void split_bf(float v, u16& h, u16& l) {
  unsigned u = __float_as_uint(v);
  unsigned hu = (u + 0x7FFFu + ((u >> 16) & 1u)) & 0xFFFF0000u;
  h = (u16)(hu >> 16);
  float r = v - __uint_as_float(hu);
  unsigned u2 = __float_as_uint(r);
  l = (u16)((u2 + 0x7FFFu + ((u2 >> 16) & 1u)) >> 16);
}
__device__ __forceinline__ u16 bf_rne(float v) {
  unsigned u = __float_as_uint(v);
  return (u16)((u + 0x7FFFu + ((u >> 16) & 1u)) >> 16);
}
__device__ __forceinline__ float bf_to_f(u16 v) {
  return __uint_as_float(((unsigned)v) << 16);
}
__device__ __forceinline__ bf16x8 ldfrag(const u16* p) { return *(const bf16x8*)p; }

// A-tile LDS address (Y region only, kt 2..6, 64 rows): [(kt-2)*2048][slot r*4+(j4^SWZ(r))][8]
__device__ __forceinline__ int atile(int r, int col) {
  return (((col >> 5) - 2) * 2048) + ((r * 4 + (((col >> 3) & 3) ^ SWZ(r))) * 8) + (col & 7);
}

// ---------- enc gram: G = emb @ emb^T ----------
__global__ __launch_bounds__(256) void k_gram(const float* __restrict__ in, int Kd,
                                              float* __restrict__ G) {
  __shared__ float At[16][64];
  __shared__ float Bt[16][64];
  int i0 = blockIdx.y * 64, j0 = blockIdx.x * 64;
  int tx = threadIdx.x & 15, ty = threadIdx.x >> 4;
  float acc[4][4] = {};
  for (int k0 = 0; k0 < Kd; k0 += 16) {
    for (int u = threadIdx.x; u < 1024; u += 256) {
      int i = u >> 4, k = u & 15;
      At[k][i] = (k0 + k < Kd) ? in[(size_t)(i0 + i) * Kd + k0 + k] : 0.f;
    }
    for (int u = threadIdx.x; u < 1024; u += 256) {
      int j = u >> 4, k = u & 15;
      Bt[k][j] = (k0 + k < Kd) ? in[(size_t)(j0 + j) * Kd + k0 + k] : 0.f;
    }
    __syncthreads();
#pragma unroll
    for (int kk = 0; kk < 16; kk++) {
      float a[4], b[4];
#pragma unroll
      for (int p = 0; p < 4; p++) a[p] = At[kk][ty * 4 + p];
#pragma unroll
      for (int q = 0; q < 4; q++) b[q] = Bt[kk][tx * 4 + q];
#pragma unroll
      for (int p = 0; p < 4; p++)
#pragma unroll
        for (int q = 0; q < 4; q++) acc[p][q] = fmaf(a[p], b[q], acc[p][q]);
    }
    __syncthreads();
  }
  for (int p = 0; p < 4; p++)
    for (int q = 0; q < 4; q++)
      G[(size_t)(i0 + ty * 4 + p) * Nn + j0 + tx * 4 + q] = acc[p][q];
}

// ---------- dec gram via split-MFMA ----------
__global__ __launch_bounds__(256) void k_gram_mfma(const u16* __restrict__ Dh,
                                                   const u16* __restrict__ Dl,
                                                   float* __restrict__ G) {
  __shared__ u16 lds[12288];
  const int tid = threadIdx.x;
  const int wave = tid >> 6, lane = tid & 63;
  const int i0 = blockIdx.y * 64;
  const int j0 = blockIdx.x * 128;
  const int wy = wave >> 1, wx = wave & 1;
  const int m = lane & 15, quad = lane >> 4;

  f32x4 acc[2][4];
  f32x4 z4 = {0.f, 0.f, 0.f, 0.f};
#pragma unroll
  for (int a = 0; a < 2; a++)
#pragma unroll
    for (int q = 0; q < 4; q++) acc[a][q] = z4;

  const int ar = tid >> 2;
  const int akc = (tid & 3) ^ SWZ(ar);

  for (int k0 = 0; k0 < KD; k0 += 32) {
    gld16(Dh + (size_t)(i0 + ar) * KD + k0 + akc * 8, &lds[wave * 512]);
    gld16(Dl + (size_t)(i0 + ar) * KD + k0 + akc * 8, &lds[2048 + wave * 512]);
#pragma unroll
    for (int p = 0; p < 2; p++) {
      int r = p * 64 + (tid >> 2);
      int kc = (tid & 3) ^ SWZ(r);
      gld16(Dh + (size_t)(j0 + r) * KD + k0 + kc * 8, &lds[4096 + p * 2048 + wave * 512]);
      gld16(Dl + (size_t)(j0 + r) * KD + k0 + kc * 8, &lds[8192 + p * 2048 + wave * 512]);
    }
    __syncthreads();

    bf16x8 ah[2], al[2], bh[4], bl[4];
#pragma unroll
    for (int mb = 0; mb < 2; mb++) {
      int r = wy * 32 + mb * 16 + m;
      int ci = r * 4 + (quad ^ SWZ(r));
      ah[mb] = *(const bf16x8*)&lds[ci * 8];
      al[mb] = *(const bf16x8*)&lds[2048 + ci * 8];
    }
#pragma unroll
    for (int nb = 0; nb < 4; nb++) {
      int rj = wx * 64 + nb * 16 + m;
      int cj = rj * 4 + (quad ^ SWZ(rj));
      bh[nb] = *(const bf16x8*)&lds[4096 + cj * 8];
      bl[nb] = *(const bf16x8*)&lds[8192 + cj * 8];
    }
#pragma unroll
    for (int mb = 0; mb < 2; mb++)
#pragma unroll
      for (int nb = 0; nb < 4; nb++) {
        acc[mb][nb] = __builtin_amdgcn_mfma_f32_16x16x32_bf16(ah[mb], bh[nb], acc[mb][nb], 0, 0, 0);
        acc[mb][nb] = __builtin_amdgcn_mfma_f32_16x16x32_bf16(ah[mb], bl[nb], acc[mb][nb], 0, 0, 0);
        acc[mb][nb] = __builtin_amdgcn_mfma_f32_16x16x32_bf16(al[mb], bh[nb], acc[mb][nb], 0, 0, 0);
      }
    __syncthreads();
  }

#pragma unroll
  for (int mb = 0; mb < 2; mb++)
#pragma unroll
    for (int nb = 0; nb < 4; nb++) {
      int col = j0 + wx * 64 + nb * 16 + m;
#pragma unroll
      for (int p = 0; p < 4; p++) {
        int row = i0 + wy * 32 + mb * 16 + quad * 4 + p;
        G[(size_t)row * Nn + col] = acc[mb][nb][p];
      }
    }
}

// ---------- S = row_softmax(relu(G)) ----------
__global__ __launch_bounds__(256) void k_softmax(const float* __restrict__ G,
                                                 u16* __restrict__ S1h,
                                                 u16* __restrict__ S1l) {
  __shared__ float sred[8];
  int n = blockIdx.x;
  float v[4];
#pragma unroll
  for (int i = 0; i < 4; i++)
    v[i] = fmaxf(G[(size_t)n * Nn + threadIdx.x + i * 256], 0.f);
  float mx = fmaxf(fmaxf(v[0], v[1]), fmaxf(v[2], v[3]));
  for (int off = 32; off > 0; off >>= 1) mx = fmaxf(mx, __shfl_down(mx, off));
  if ((threadIdx.x & 63) == 0) sred[threadIdx.x >> 6] = mx;
  __syncthreads();
  float rmax = fmaxf(fmaxf(sred[0], sred[1]), fmaxf(sred[2], sred[3]));
  float s = 0.f;
#pragma unroll
  for (int i = 0; i < 4; i++) { v[i] = expf(v[i] - rmax); s += v[i]; }
  for (int off = 32; off > 0; off >>= 1) s += __shfl_down(s, off);
  if ((threadIdx.x & 63) == 0) sred[4 + (threadIdx.x >> 6)] = s;
  __syncthreads();
  float inv = 1.f / (sred[4] + sred[5] + sred[6] + sred[7]);
#pragma unroll
  for (int i = 0; i < 4; i++) {
    u16 h, l;
    split_bf(v[i] * inv, h, l);
    size_t a = (size_t)n * Nn + threadIdx.x + i * 256;
    S1h[a] = h; S1l[a] = l;
  }
}

// ---------- transpose ----------
__global__ __launch_bounds__(256) void k_tr2(const u16* __restrict__ Ah,
                                             const u16* __restrict__ Al,
                                             u16* __restrict__ Th, u16* __restrict__ Tl) {
  __shared__ u16 sm[64][72];
  int i0 = blockIdx.y * 64, j0 = blockIdx.x * 64;
  int tid = threadIdx.x;
  for (int pass = 0; pass < 2; pass++) {
    const u16* src = pass ? Al : Ah;
    u16* dst = pass ? Tl : Th;
    for (int u = tid; u < 4096; u += 256) {
      int i = u >> 6, c = u & 63;
      sm[i][c] = src[(size_t)(i0 + i) * Nn + j0 + c];
    }
    __syncthreads();
    for (int u = tid; u < 4096; u += 256) {
      int c = u >> 6, i = u & 63;
      dst[(size_t)(j0 + c) * Nn + i0 + i] = sm[i][c];
    }
    __syncthreads();
  }
}

// ---------- S2 = 2*S@S - I ----------
__global__ __launch_bounds__(256) void k_s2_mfma(const u16* __restrict__ S1h,
                                                 const u16* __restrict__ S1l,
                                                 const u16* __restrict__ Sth,
                                                 const u16* __restrict__ Stl,
                                                 u16* __restrict__ S2h) {
  const int tid = threadIdx.x;
  const int wave = tid >> 6, lane = tid & 63;
  const int blk = blockIdx.x;
  const int s = blk >> 3;
  const int i0 = ((blk & 7) * 2 + (s & 1)) * 64;
  const int j0 = (s >> 1) * 128;
  const int wy = wave >> 1, wx = wave & 1;
  const int m = lane & 15, quad = lane >> 4;

  const size_t aoff = (size_t)(i0 + wy * 32 + m) * Nn + quad * 8;
  const size_t boff = (size_t)(j0 + wx * 64 + m) * Nn + quad * 8;

  f32x4 acc[2][4];
  f32x4 z4 = {0.f, 0.f, 0.f, 0.f};
#pragma unroll
  for (int a = 0; a < 2; a++)
#pragma unroll
    for (int q = 0; q < 4; q++) acc[a][q] = z4;

  bf16x8 fAh[2][2], fAl[2][2], fBh[2][4], fBl[2][4];
  auto ld = [&](int k0, int sb) {
#pragma unroll
    for (int mb = 0; mb < 2; mb++) {
      fAh[sb][mb] = ldfrag(S1h + aoff + (size_t)mb * 16 * Nn + k0);
      fAl[sb][mb] = ldfrag(S1l + aoff + (size_t)mb * 16 * Nn + k0);
    }
#pragma unroll
    for (int nb = 0; nb < 4; nb++) {
      fBh[sb][nb] = ldfrag(Sth + boff + (size_t)nb * 16 * Nn + k0);
      fBl[sb][nb] = ldfrag(Stl + boff + (size_t)nb * 16 * Nn + k0);
    }
  };
  ld(0, 0);
#pragma unroll 2
  for (int kt = 0; kt < 32; kt++) {
    int cur = kt & 1;
    if (kt < 31) ld((kt + 1) * 32, cur ^ 1);
#pragma unroll
    for (int mb = 0; mb < 2; mb++)
#pragma unroll
      for (int nb = 0; nb < 4; nb++) {
        acc[mb][nb] = __builtin_amdgcn_mfma_f32_16x16x32_bf16(fAh[cur][mb], fBh[cur][nb], acc[mb][nb], 0, 0, 0);
        acc[mb][nb] = __builtin_amdgcn_mfma_f32_16x16x32_bf16(fAh[cur][mb], fBl[cur][nb], acc[mb][nb], 0, 0, 0);
        acc[mb][nb] = __builtin_amdgcn_mfma_f32_16x16x32_bf16(fAl[cur][mb], fBh[cur][nb], acc[mb][nb], 0, 0, 0);
      }
  }

#pragma unroll
  for (int mb = 0; mb < 2; mb++)
#pragma unroll
    for (int nb = 0; nb < 4; nb++) {
      int col = j0 + wx * 64 + nb * 16 + m;
#pragma unroll
      for (int p = 0; p < 4; p++) {
        int row = i0 + wy * 32 + mb * 16 + quad * 4 + p;
        float v = 2.f * acc[mb][nb][p] - (row == col ? 1.f : 0.f);
        S2h[(size_t)row * Nn + col] = bf_rne(v);
      }
    }
}

// ---------- Wt prep ----------
__global__ __launch_bounds__(256) void k_prep_wt(const float* __restrict__ W, int Csrc,
                                                 int ncol, u16* __restrict__ Wh,
                                                 u16* __restrict__ Wl) {
  int idx = blockIdx.x * 256 + threadIdx.x;
  if (idx >= ncol * KP) return;
  int n = idx / KP, kp = idx % KP;
  int chunk = kp / Cc, c = kp % Cc;
  float v = 0.f;
  if (kp < 3 * Cc && c < Csrc) v = W[((size_t)chunk * Csrc + c) * ncol + n];
  u16 h, l;
  split_bf(v, h, l);
  Wh[idx] = h; Wl[idx] = l;
}

// ---------- precompute B operands ----------
__global__ __launch_bounds__(256) void k_prep_xe(const float* __restrict__ x,
                                                 u16* __restrict__ Xx) {
  int idx = blockIdx.x * 256 + threadIdx.x;
  if (idx >= NXE * Nn) return;
  int col = idx >> 10, n = idx & (Nn - 1);
  int t = col >> 6, b = col & 63;
  Xx[idx] = bf_rne(x[(size_t)b * TN + (size_t)t * Nn + n]);
}

__global__ __launch_bounds__(256) void k_prep_xd(const float* __restrict__ x,
                                                 const float* __restrict__ ycov,
                                                 u16* __restrict__ Xx) {
  int idx = blockIdx.x * 256 + threadIdx.x;
  if (idx >= NXD * Nn) return;
  int col = idx >> 10, n = idx & (Nn - 1);
  float v = 0.f;
  if (col < 64) {
    v = x[(size_t)col * TN + (size_t)(Tc - 1) * Nn + n];
  } else if (col < 64 + Tc * 64) {
    int t = (col - 64) >> 6, b = (col - 64) & 63;
    v = ycov[(size_t)b * TN + (size_t)t * Nn + n];
  }
  Xx[idx] = bf_rne(v);
}

// ---------- ypre: Y1 = S1@Xx, Y2 = S2@Xx (x-derived Y cols) ----------
__global__ __launch_bounds__(256, 2) void k_ypre(const u16* __restrict__ S1h,
                                                 const u16* __restrict__ S2h,
                                                 const u16* __restrict__ Xx,
                                                 u16* __restrict__ Yo1,
                                                 u16* __restrict__ Yo2) {
  __shared__ u16 lds[24576];
  const int tid = threadIdx.x;
  const int wave = tid >> 6;
  const int lane = tid & 63;
  const int blk = blockIdx.x;
  const int i0 = (blk & 7) * 128;
  const int j0 = (blk >> 3) * 128;
  const int wy = wave >> 1, wx = wave & 1;
  const int m = lane & 15, quad = lane >> 4;

  f32x4 acc1[4][4], acc2[4][4];
  f32x4 z4 = {0.f, 0.f, 0.f, 0.f};
#pragma unroll
  for (int a = 0; a < 4; a++)
#pragma unroll
    for (int q = 0; q < 4; q++) { acc1[a][q] = z4; acc2[a][q] = z4; }

  for (int k0 = 0; k0 < Nn; k0 += 64) {
#pragma unroll
    for (int c = 0; c < 4; c++) {
      int ci = c * 256 + tid;
      int r = ci >> 3, kc = (ci & 7) ^ SW8(r);
      gld16(S1h + (size_t)(i0 + r) * Nn + k0 + kc * 8, &lds[c * 2048 + wave * 512]);
      gld16(S2h + (size_t)(i0 + r) * Nn + k0 + kc * 8, &lds[8192 + c * 2048 + wave * 512]);
      gld16(Xx + (size_t)(j0 + r) * Nn + k0 + kc * 8, &lds[16384 + c * 2048 + wave * 512]);
    }
    __syncthreads();

#pragma unroll
    for (int ks = 0; ks < 2; ks++) {
      bf16x8 bfr[4];
#pragma unroll
      for (int nb = 0; nb < 4; nb++) {
        int rj = wx * 64 + nb * 16 + m;
        int cj = rj * 8 + ((ks * 4 + quad) ^ SW8(rj));
        bfr[nb] = *(const bf16x8*)&lds[16384 + cj * 8];
      }
      bf16x8 a1[4], a2[4];
#pragma unroll
      for (int mb = 0; mb < 4; mb++) {
        int r = wy * 64 + mb * 16 + m;
        int ci = r * 8 + ((ks * 4 + quad) ^ SW8(r));
        a1[mb] = *(const bf16x8*)&lds[ci * 8];
        a2[mb] = *(const bf16x8*)&lds[8192 + ci * 8];
      }
#pragma unroll
      for (int mb = 0; mb < 4; mb++)
#pragma unroll
        for (int nb = 0; nb < 4; nb++) {
          acc1[mb][nb] = __builtin_amdgcn_mfma_f32_16x16x32_bf16(a1[mb], bfr[nb], acc1[mb][nb], 0, 0, 0);
          acc2[mb][nb] = __builtin_amdgcn_mfma_f32_16x16x32_bf16(a2[mb], bfr[nb], acc2[mb][nb], 0, 0, 0);
        }
    }
    __syncthreads();
  }

#pragma unroll
  for (int mb = 0; mb < 4; mb++)
#pragma unroll
    for (int nb = 0; nb < 4; nb++) {
      int col = j0 + wx * 64 + nb * 16 + m;
#pragma unroll
      for (int p = 0; p < 4; p++) {
        int n = i0 + wy * 64 + mb * 16 + quad * 4 + p;
        Yo1[(size_t)col * Nn + n] = bf_rne(acc1[mb][nb][p]);
        Yo2[(size_t)col * Nn + n] = bf_rne(acc2[mb][nb][p]);
      }
    }
}

// ---------- fill enc t=0 ----------
__global__ __launch_bounds__(256) void k_fill_enc(const float* __restrict__ x,
                                                  u16* __restrict__ XAh,
                                                  const u16* __restrict__ ye1,
                                                  const u16* __restrict__ ye2) {
  int idx = blockIdx.x * 256 + threadIdx.x;
  if (idx >= NB) return;
  int n = idx & (Nn - 1), b = idx >> 10;
  XAh[(size_t)idx * SA] = bf_rne(x[(size_t)b * TN + n]);
  XAh[(size_t)idx * SA + 66] = ye1[(size_t)b * Nn + n];
  XAh[(size_t)idx * SA + 132] = ye2[(size_t)b * Nn + n];
}

// ---------- dec init ----------
__global__ __launch_bounds__(256) void k_dec_init(const float* __restrict__ x,
                                                  const float* __restrict__ ycov,
                                                  u16* __restrict__ XAh,
                                                  const u16* __restrict__ yd1,
                                                  const u16* __restrict__ yd2) {
  int idx = blockIdx.x * 256 + threadIdx.x;
  if (idx >= NB) return;
  int n = idx & (Nn - 1), b = idx >> 10;
  XAh[(size_t)idx * SA] = bf_rne(x[(size_t)b * TN + (size_t)(Tc - 1) * Nn + n]);
  XAh[(size_t)idx * SA + 1] = bf_rne(ycov[(size_t)b * TN + n]);
  XAh[(size_t)idx * SA + 66] = yd1[(size_t)b * Nn + n];
  XAh[(size_t)idx * SA + 67] = yd1[(size_t)(64 + b) * Nn + n];
  XAh[(size_t)idx * SA + 132] = yd2[(size_t)b * Nn + n];
  XAh[(size_t)idx * SA + 133] = yd2[(size_t)(64 + b) * Nn + n];
}

// ================= FUSED ygemm + gate (M=64 tiles, grid 1024 = 4 blocks/CU) =================
// i0 = (blk&15)*64, bb = blk>>4. LDS 24KB (staging 24KB UNION Y A-tile 20KB).
// 4 independent blocks/CU -> cross-block latency hiding (barriers don't cross blocks).
// Phase 3: kt0/1 A-fragments direct-global from XA; kt2..6 from LDS Y-tile.
__global__ __launch_bounds__(256, 4) void k_fgate(
    const u16* __restrict__ S1h, const u16* __restrict__ S2h,
    const u16* __restrict__ XhIn, const u16* XA,
    const u16* __restrict__ Wh, const u16* __restrict__ Wl,
    const float* __restrict__ bias, const float* __restrict__ hst,
    u16* __restrict__ Rb, u16* XAo, u16* __restrict__ XhOut,
    int off, int yoff, int m8, int m16,
    const float* __restrict__ pw, const float* __restrict__ pb) {
  __shared__ u16 lds[12288];  // 24KB
  const int tid = threadIdx.x;
  const int wave = tid >> 6, lane = tid & 63;
  const int i0 = (blockIdx.x & 15) * 64;
  const int bb = blockIdx.x >> 4;
  const int m = lane & 15, quad = lane >> 4;
  const size_t rowbase = (size_t)bb * Nn + i0;

  // ---- phase 1: Y1/Y2 = S1/S2 @ h ----
  f32x4 acc1[4], acc2[4];
  f32x4 z4 = {0.f, 0.f, 0.f, 0.f};
#pragma unroll
  for (int q = 0; q < 4; q++) { acc1[q] = z4; acc2[q] = z4; }

  for (int k0 = 0; k0 < Nn; k0 += 64) {
#pragma unroll
    for (int c = 0; c < 2; c++) {
      int ci = c * 256 + tid;
      int r = ci >> 3, kc = (ci & 7) ^ SW8(r);
      gld16(S1h + (size_t)(i0 + r) * Nn + k0 + kc * 8, &lds[c * 2048 + wave * 512]);
      gld16(S2h + (size_t)(i0 + r) * Nn + k0 + kc * 8, &lds[4096 + c * 2048 + wave * 512]);
      gld16(XhIn + (size_t)(bb * 64 + r) * Nn + k0 + kc * 8, &lds[8192 + c * 2048 + wave * 512]);
    }
    __syncthreads();
#pragma unroll
    for (int ks = 0; ks < 2; ks++) {
      bf16x8 bfr[4];
#pragma unroll
      for (int nb = 0; nb < 4; nb++) {
        int rj = nb * 16 + m;
        int cj = rj * 8 + ((ks * 4 + quad) ^ SW8(rj));
        bfr[nb] = *(const bf16x8*)&lds[8192 + cj * 8];
      }
      bf16x8 a1, a2;
      {
        int r = wave * 16 + m;
        int ci = r * 8 + ((ks * 4 + quad) ^ SW8(r));
        a1 = *(const bf16x8*)&lds[ci * 8];
        a2 = *(const bf16x8*)&lds[4096 + ci * 8];
      }
#pragma unroll
      for (int nb = 0; nb < 4; nb++) {
        acc1[nb] = __builtin_amdgcn_mfma_f32_16x16x32_bf16(a1, bfr[nb], acc1[nb], 0, 0, 0);
        acc2[nb] = __builtin_amdgcn_mfma_f32_16x16x32_bf16(a2, bfr[nb], acc2[nb], 0, 0, 0);
      }
    }
    __syncthreads();
  }

  // ---- phase 2: Y-only A-tile (kt2..6, 64 rows). Masked chunks zero full width. ----
  if (tid < 128) {
    int r = tid >> 1;
    int cc = (tid & 1) ? 16 : 8;
    int msk = (tid & 1) ? m16 : m8;
    const u16* src = XA + (rowbase + r) * SA + cc * 8;
    bf16x8 v;
#pragma unroll
    for (int j = 0; j < 8; j++) v[j] = (short)(((msk >> j) & 1) ? src[j] : 0);
    *(bf16x8*)&lds[((cc >> 2) - 2) * 2048 + (r * 4 + SWZ(r)) * 8] = v;
  }
  __syncthreads();
  {
    const int yb1 = 66 + yoff, yb2 = 132 + yoff;
#pragma unroll
    for (int nb = 0; nb < 4; nb++)
#pragma unroll
      for (int p = 0; p < 4; p++) {
        int r = wave * 16 + quad * 4 + p;
        int ch = nb * 16 + m;
        lds[atile(r, yb1 + ch)] = bf_rne(acc1[nb][p]);
        lds[atile(r, yb2 + ch)] = bf_rne(acc2[nb][p]);
      }
    if (pw != nullptr) {
      float pb0 = pb[0];
      float pwv[4];
#pragma unroll
      for (int nb = 0; nb < 4; nb++) pwv[nb] = pw[nb * 16 + m];
#pragma unroll
      for (int p = 0; p < 4; p++) {
        float s1 = 0.f, s2 = 0.f;
#pragma unroll
        for (int nb = 0; nb < 4; nb++) {
          s1 = fmaf(acc1[nb][p], pwv[nb], s1);
          s2 = fmaf(acc2[nb][p], pwv[nb], s2);
        }
#pragma unroll
        for (int o = 8; o > 0; o >>= 1) { s1 += __shfl_xor(s1, o); s2 += __shfl_xor(s2, o); }
        if (m == 0) {
          int r = wave * 16 + quad * 4 + p;
          u16 v1 = bf_rne(s1 + pb0), v2 = bf_rne(s2 + pb0);
          lds[atile(r, 66)] = v1;
          lds[atile(r, 132)] = v2;
          XAo[(rowbase + r) * SA + 66] = v1;
          XAo[(rowbase + r) * SA + 132] = v2;
        }
      }
    }
  }
  __syncthreads();

  // ---- phase 3: gate GEMM. M=64, N=128; wave wx = wave covers 32 cols ----
  f32x4 accg[4][2];
#pragma unroll
  for (int a = 0; a < 4; a++) { accg[a][0] = z4; accg[a][1] = z4; }
#pragma unroll
  for (int kt = 0; kt < 7; kt++) {
    int k0 = kt * 32;
    bf16x8 af[4], bh[2], bl[2];
#pragma unroll
    for (int mb = 0; mb < 4; mb++) {
      int r = mb * 16 + m;
      if (kt < 2)
        af[mb] = ldfrag(XA + (rowbase + r) * SA + k0 + quad * 8);
      else
        af[mb] = *(const bf16x8*)&lds[(kt - 2) * 2048 + (r * 4 + (quad ^ SWZ(r))) * 8];
    }
#pragma unroll
    for (int nb = 0; nb < 2; nb++) {
      size_t wrow = (size_t)(wave * 32 + nb * 16 + m) * KP + quad * 8;
      bh[nb] = ldfrag(Wh + wrow + k0);
      bl[nb] = ldfrag(Wl + wrow + k0);
    }
#pragma unroll
    for (int mb = 0; mb < 4; mb++)
#pragma unroll
      for (int nb = 0; nb < 2; nb++) {
        accg[mb][nb] = __builtin_amdgcn_mfma_f32_16x16x32_bf16(af[mb], bh[nb], accg[mb][nb], 0, 0, 0);
        accg[mb][nb] = __builtin_amdgcn_mfma_f32_16x16x32_bf16(af[mb], bl[nb], accg[mb][nb], 0, 0, 0);
      }
  }

  // ---- epilogue ----
#pragma unroll
  for (int mb = 0; mb < 4; mb++)
#pragma unroll
    for (int nb = 0; nb < 2; nb++) {
      int col = wave * 32 + nb * 16 + m;
      float bv = bias[col];
      int rl0 = mb * 16 + quad * 4;
      if (col < 64) {  // wave-uniform (wave<2)
        u16x4 pk;
#pragma unroll
        for (int p = 0; p < 4; p++) {
          size_t rid = rowbase + rl0 + p;
          float sg = 1.f / (1.f + expf(-(accg[mb][nb][p] + bv)));
          u16 vh = bf_rne(sg * hst[rid * 64 + col]);
          XAo[rid * SA + off + col] = vh;
          pk[p] = vh;
        }
        *(u16x4*)&XhOut[(size_t)(bb * 64 + col) * Nn + i0 + rl0] = pk;
      } else {
#pragma unroll
        for (int p = 0; p < 4; p++) {
          size_t rid = rowbase + rl0 + p;
          float sg = 1.f / (1.f + expf(-(accg[mb][nb][p] + bv)));
          Rb[rid * 64 + col - 64] = bf_rne(sg);
        }
      }
    }
}

// ================= FUSED ygemm + update (+ optional proj/fill), M=64 tiles =================
__global__ __launch_bounds__(256, 4) void k_fupd(
    const u16* __restrict__ S1h, const u16* __restrict__ S2h,
    const u16* __restrict__ XhIn, const u16* XA,
    const u16* __restrict__ Wh, const u16* __restrict__ Wl,
    const float* __restrict__ bias, const u16* __restrict__ Rb,
    float* __restrict__ h, u16* XAo, u16* __restrict__ XhOut,
    int off_next, int yoff, int m8, int m16,
    const float* __restrict__ xsrc, int tnext,
    const u16* __restrict__ ye1, const u16* __restrict__ ye2,
    const float* __restrict__ pw2, const float* __restrict__ pb2,
    const float* __restrict__ ycov,
    const u16* __restrict__ yd1, const u16* __restrict__ yd2,
    float* __restrict__ out, int tt) {
  __shared__ u16 lds[12288];  // 24KB
  const int tid = threadIdx.x;
  const int wave = tid >> 6, lane = tid & 63;
  const int i0 = (blockIdx.x & 15) * 64;
  const int bb = blockIdx.x >> 4;
  const int m = lane & 15, quad = lane >> 4;
  const size_t rowbase = (size_t)bb * Nn + i0;

  // ---- phase 1: Y = S @ (z*h) ----
  f32x4 acc1[4], acc2[4];
  f32x4 z4 = {0.f, 0.f, 0.f, 0.f};
#pragma unroll
  for (int q = 0; q < 4; q++) { acc1[q] = z4; acc2[q] = z4; }

  for (int k0 = 0; k0 < Nn; k0 += 64) {
#pragma unroll
    for (int c = 0; c < 2; c++) {
      int ci = c * 256 + tid;
      int r = ci >> 3, kc = (ci & 7) ^ SW8(r);
      gld16(S1h + (size_t)(i0 + r) * Nn + k0 + kc * 8, &lds[c * 2048 + wave * 512]);
      gld16(S2h + (size_t)(i0 + r) * Nn + k0 + kc * 8, &lds[4096 + c * 2048 + wave * 512]);
      gld16(XhIn + (size_t)(bb * 64 + r) * Nn + k0 + kc * 8, &lds[8192 + c * 2048 + wave * 512]);
    }
    __syncthreads();
#pragma unroll
    for (int ks = 0; ks < 2; ks++) {
      bf16x8 bfr[4];
#pragma unroll
      for (int nb = 0; nb < 4; nb++) {
        int rj = nb * 16 + m;
        int cj = rj * 8 + ((ks * 4 + quad) ^ SW8(rj));
        bfr[nb] = *(const bf16x8*)&lds[8192 + cj * 8];
      }
      bf16x8 a1, a2;
      {
        int r = wave * 16 + m;
        int ci = r * 8 + ((ks * 4 + quad) ^ SW8(r));
        a1 = *(const bf16x8*)&lds[ci * 8];
        a2 = *(const bf16x8*)&lds[4096 + ci * 8];
      }
#pragma unroll
      for (int nb = 0; nb < 4; nb++) {
        acc1[nb] = __builtin_amdgcn_mfma_f32_16x16x32_bf16(a1, bfr[nb], acc1[nb], 0, 0, 0);
        acc2[nb] = __builtin_amdgcn_mfma_f32_16x16x32_bf16(a2, bfr[nb], acc2[nb], 0, 0, 0);
      }
    }
    __syncthreads();
  }

  // ---- phase 2: Y-only A-tile ----
  if (tid < 128) {
    int r = tid >> 1;
    int cc = (tid & 1) ? 16 : 8;
    int msk = (tid & 1) ? m16 : m8;
    const u16* src = XA + (rowbase + r) * SA + cc * 8;
    bf16x8 v;
#pragma unroll
    for (int j = 0; j < 8; j++) v[j] = (short)(((msk >> j) & 1) ? src[j] : 0);
    *(bf16x8*)&lds[((cc >> 2) - 2) * 2048 + (r * 4 + SWZ(r)) * 8] = v;
  }
  __syncthreads();
  {
    const int yb1 = 66 + yoff, yb2 = 132 + yoff;
#pragma unroll
    for (int nb = 0; nb < 4; nb++)
#pragma unroll
      for (int p = 0; p < 4; p++) {
        int r = wave * 16 + quad * 4 + p;
        int ch = nb * 16 + m;
        lds[atile(r, yb1 + ch)] = bf_rne(acc1[nb][p]);
        lds[atile(r, yb2 + ch)] = bf_rne(acc2[nb][p]);
      }
  }
  __syncthreads();

  // ---- phase 3: update GEMM. M=64, N=64; wave covers 16 cols ----
  f32x4 accg[4];
#pragma unroll
  for (int a = 0; a < 4; a++) accg[a] = z4;
#pragma unroll
  for (int kt = 0; kt < 7; kt++) {
    int k0 = kt * 32;
    bf16x8 af[4], bh0, bl0;
#pragma unroll
    for (int mb = 0; mb < 4; mb++) {
      int r = mb * 16 + m;
      if (kt < 2)
        af[mb] = ldfrag(XA + (rowbase + r) * SA + k0 + quad * 8);
      else
        af[mb] = *(const bf16x8*)&lds[(kt - 2) * 2048 + (r * 4 + (quad ^ SWZ(r))) * 8];
    }
    {
      size_t wrow = (size_t)(wave * 16 + m) * KP + quad * 8;
      bh0 = ldfrag(Wh + wrow + k0);
      bl0 = ldfrag(Wl + wrow + k0);
    }
#pragma unroll
    for (int mb = 0; mb < 4; mb++) {
      accg[mb] = __builtin_amdgcn_mfma_f32_16x16x32_bf16(af[mb], bh0, accg[mb], 0, 0, 0);
      accg[mb] = __builtin_amdgcn_mfma_f32_16x16x32_bf16(af[mb], bl0, accg[mb], 0, 0, 0);
    }
  }

  // ---- epilogue: h update (+ partial proj) ----
  float par[4][4];
#pragma unroll
  for (int a = 0; a < 4; a++)
#pragma unroll
    for (int p = 0; p < 4; p++) par[a][p] = 0.f;
  float pwv2 = 0.f;
  if (pw2 != nullptr) pwv2 = pw2[wave * 16 + m];

  const int col = wave * 16 + m;
  const float bv = bias[col];
#pragma unroll
  for (int mb = 0; mb < 4; mb++) {
    int rl0 = mb * 16 + quad * 4;
    u16x4 pk;
#pragma unroll
    for (int p = 0; p < 4; p++) {
      size_t rid = rowbase + rl0 + p;
      float hc = tanhf(accg[mb][p] + bv);
      size_t idx = rid * 64 + col;
      float rr = bf_to_f(Rb[idx]);
      float hn = rr * h[idx] + (1.f - rr) * hc;
      h[idx] = hn;
      u16 vh = bf_rne(hn);
      XAo[rid * SA + off_next + col] = vh;
      pk[p] = vh;
      par[mb][p] = fmaf(hn, pwv2, par[mb][p]);
    }
    *(u16x4*)&XhOut[(size_t)(bb * 64 + col) * Nn + i0 + rl0] = pk;
    if (col == 0 && xsrc != nullptr) {
#pragma unroll
      for (int p = 0; p < 4; p++) {
        size_t rid = rowbase + rl0 + p;
        int n = i0 + rl0 + p;
        XAo[rid * SA] = bf_rne(xsrc[(size_t)bb * TN + (size_t)tnext * Nn + n]);
        XAo[rid * SA + 66] = ye1[((size_t)(tnext * 64 + bb)) * Nn + n];
        XAo[rid * SA + 132] = ye2[((size_t)(tnext * 64 + bb)) * Nn + n];
      }
    }
  }

  if (pw2 != nullptr) {
    // reduce over m within wave, then across 4 waves via LDS
#pragma unroll
    for (int mb = 0; mb < 4; mb++)
#pragma unroll
      for (int p = 0; p < 4; p++)
#pragma unroll
        for (int o = 8; o > 0; o >>= 1) par[mb][p] += __shfl_xor(par[mb][p], o);
    __syncthreads();  // all A-tile reads done; reuse LDS as float scratch
    float* buf = (float*)lds;
    if (m == 0) {
#pragma unroll
      for (int mb = 0; mb < 4; mb++)
#pragma unroll
        for (int p = 0; p < 4; p++)
          buf[wave * 64 + mb * 16 + quad * 4 + p] = par[mb][p];
    }
    __syncthreads();
    if (tid < 64) {
      int r = tid;
      int n = i0 + r;
      size_t rid = rowbase + r;
      float s = buf[r] + buf[64 + r] + buf[128 + r] + buf[192 + r] + pb2[0];
      out[(size_t)bb * TN + (size_t)tt * Nn + n] = s;
      if (tt + 1 < Tc) {
        XAo[rid * SA] = bf_rne(s);
        XAo[rid * SA + 1] = bf_rne(ycov[(size_t)bb * TN + (size_t)(tt + 1) * Nn + n]);
        size_t yc = (size_t)(64 + (tt + 1) * 64 + bb) * Nn + n;
        XAo[rid * SA + 67] = yd1[yc];
        XAo[rid * SA + 133] = yd2[yc];
      }
    }
  }
}

// ---------- de = h @ FC_E ----------
__global__ __launch_bounds__(256) void k_de(const float* __restrict__ h,
                                            const float* __restrict__ fc,
                                            u16* __restrict__ Dh, u16* __restrict__ Dl) {
  __shared__ float fcs[Hc * Ec];
  for (int j = threadIdx.x; j < Hc * Ec; j += 256) fcs[j] = fc[j];
  __syncthreads();
  int idx = blockIdx.x * 256 + threadIdx.x;
  if (idx >= Nn * KD) return;
  int n = idx / KD;
  int rem = idx % KD;
  int b = rem / Ec, e = rem % Ec;
  const float* hp = h + ((size_t)b * Nn + n) * Hc;
  float acc = 0.f;
#pragma unroll 8
  for (int hh = 0; hh < Hc; hh++) acc = fmaf(hp[hh], fcs[hh * Ec + e], acc);
  u16 vh, vl;
  split_bf(acc, vh, vl);
  Dh[idx] = vh; Dl[idx] = vl;
}

extern "C" void kernel_launch(void* const* d_in, const int* in_sizes, int n_in,
                              void* d_out, int out_size, void* d_ws, size_t ws_size,
                              hipStream_t stream) {
  (void)in_sizes; (void)n_in; (void)out_size; (void)ws_size;
  const float* x    = (const float*)d_in[0];
  const float* ycov = (const float*)d_in[1];
  const float* emb  = (const float*)d_in[2];
  const float* fce  = (const float*)d_in[3];
  const float* egw  = (const float*)d_in[4];
  const float* egb  = (const float*)d_in[5];
  const float* euw  = (const float*)d_in[6];
  const float* eub  = (const float*)d_in[7];
  const float* dgw  = (const float*)d_in[8];
  const float* dgb  = (const float*)d_in[9];
  const float* duw  = (const float*)d_in[10];
  const float* dub  = (const float*)d_in[11];
  const float* pw   = (const float*)d_in[12];
  const float* pb   = (const float*)d_in[13];
  float* out = (float*)d_out;

  char* wsb = (char*)d_ws;
  size_t off = 0;
  auto alloc = [&](size_t bytes) {
    void* p = wsb + off;
    off = (off + bytes + 255) & ~(size_t)255;
    return p;
  };
  float* Gf = (float*)alloc((size_t)Nn * Nn * 4);
  u16* S1h = (u16*)alloc((size_t)Nn * Nn * 2);
  u16* S1l = (u16*)alloc((size_t)Nn * Nn * 2);
  u16* S2h = (u16*)alloc((size_t)Nn * Nn * 2);
  u16* Sth = (u16*)alloc((size_t)Nn * Nn * 2);
  u16* Stl = (u16*)alloc((size_t)Nn * Nn * 2);
  float* Hst = (float*)alloc((size_t)NB * Hc * 4);
  u16* XAh = (u16*)alloc((size_t)(NB + 4) * SA * 2);
  u16* XhA = (u16*)alloc((size_t)Bc * 64 * Nn * 2);  // h   [b*64+ch][n]
  u16* XhB = (u16*)alloc((size_t)Bc * 64 * Nn * 2);  // z*h [b*64+ch][n]
  u16* Rb = (u16*)alloc((size_t)NB * Hc * 2);
  u16* DEh = (u16*)alloc((size_t)Nn * KD * 2);
  u16* DEl = (u16*)alloc((size_t)Nn * KD * 2);
  u16* WgeH = (u16*)alloc(128 * KP * 2); u16* WgeL = (u16*)alloc(128 * KP * 2);
  u16* WueH = (u16*)alloc(64 * KP * 2);  u16* WueL = (u16*)alloc(64 * KP * 2);
  u16* WgdH = (u16*)alloc(128 * KP * 2); u16* WgdL = (u16*)alloc(128 * KP * 2);
  u16* WudH = (u16*)alloc(64 * KP * 2);  u16* WudL = (u16*)alloc(64 * KP * 2);
  u16* XxE = (u16*)alloc((size_t)NXE * Nn * 2);
  u16* YE1 = (u16*)alloc((size_t)NXE * Nn * 2);
  u16* YE2 = (u16*)alloc((size_t)NXE * Nn * 2);
  u16* XxD = (u16*)alloc((size_t)NXD * Nn * 2);
  u16* YD1 = (u16*)alloc((size_t)NXD * Nn * 2);
  u16* YD2 = (u16*)alloc((size_t)NXD * Nn * 2);

  hipMemsetAsync(Hst, 0, (size_t)NB * Hc * 4, stream);
  hipMemsetAsync(XAh, 0, (size_t)(NB + 4) * SA * 2, stream);
  hipMemsetAsync(XhA, 0, (size_t)Bc * 64 * Nn * 2, stream);

  k_prep_wt<<<(128 * KP + 255) / 256, 256, 0, stream>>>(egw, 65, 128, WgeH, WgeL);
  k_prep_wt<<<(64 * KP + 255) / 256, 256, 0, stream>>>(euw, 65, 64, WueH, WueL);
  k_prep_wt<<<(128 * KP + 255) / 256, 256, 0, stream>>>(dgw, 66, 128, WgdH, WgdL);
  k_prep_wt<<<(64 * KP + 255) / 256, 256, 0, stream>>>(duw, 66, 64, WudH, WudL);

  // encoder supports
  k_gram<<<dim3(16, 16), 256, 0, stream>>>(emb, Ec, Gf);
  k_softmax<<<Nn, 256, 0, stream>>>(Gf, S1h, S1l);
  k_tr2<<<dim3(16, 16), 256, 0, stream>>>(S1h, S1l, Sth, Stl);
  k_s2_mfma<<<128, 256, 0, stream>>>(S1h, S1l, Sth, Stl, S2h);

  // precompute Y for all encoder x-columns
  k_prep_xe<<<(NXE * Nn + 255) / 256, 256, 0, stream>>>(x, XxE);
  k_ypre<<<8 * 6, 256, 0, stream>>>(S1h, S2h, XxE, YE1, YE2);

  const int gNB = NB / 256;
  k_fill_enc<<<gNB, 256, 0, stream>>>(x, XAh, YE1, YE2);

  // enc masks: chunk8 cols {64,65,66}, chunk16 cols {132}
  for (int t = 0; t < Tc; t++) {
    k_fgate<<<1024, 256, 0, stream>>>(S1h, S2h, XhA, XAh, WgeH, WgeL, egb, Hst,
                                      Rb, XAh, XhB, 1, 1, 0x07, 0x10,
                                      nullptr, nullptr);
    k_fupd<<<1024, 256, 0, stream>>>(S1h, S2h, XhB, XAh, WueH, WueL, eub, Rb,
                                     Hst, XAh, XhA, (t == Tc - 1) ? 2 : 1, 1,
                                     0x07, 0x10,
                                     (t + 1 < Tc) ? x : nullptr, t + 1, YE1, YE2,
                                     nullptr, nullptr, nullptr, nullptr, nullptr,
                                     nullptr, 0);
  }

  // decoder supports
  k_de<<<(Nn * KD + 255) / 256, 256, 0, stream>>>(Hst, fce, DEh, DEl);
  k_gram_mfma<<<dim3(8, 16), 256, 0, stream>>>(DEh, DEl, Gf);
  k_softmax<<<Nn, 256, 0, stream>>>(Gf, S1h, S1l);
  k_tr2<<<dim3(16, 16), 256, 0, stream>>>(S1h, S1l, Sth, Stl);
  k_s2_mfma<<<128, 256, 0, stream>>>(S1h, S1l, Sth, Stl, S2h);

  // precompute Y for decoder go0 + ycov columns
  k_prep_xd<<<(NXD * Nn + 255) / 256, 256, 0, stream>>>(x, ycov, XxD);
  k_ypre<<<8 * 7, 256, 0, stream>>>(S1h, S2h, XxD, YD1, YD2);

  k_dec_init<<<gNB, 256, 0, stream>>>(x, ycov, XAh, YD1, YD2);

  // dec masks: t=0 chunk8 {64,65,66,67}/chunk16 {132,133};
  //            t>0 gate: {64,65,67}/{133} + derived go-col; upd: full.
  for (int t = 0; t < Tc; t++) {
    k_fgate<<<1024, 256, 0, stream>>>(S1h, S2h, XhA, XAh, WgdH, WgdL, dgb, Hst,
                                      Rb, XAh, XhB, 2, 2,
                                      (t == 0) ? 0x0F : 0x0B,
                                      (t == 0) ? 0x30 : 0x20,
                                      (t > 0) ? pw : nullptr, pb);
    k_fupd<<<1024, 256, 0, stream>>>(S1h, S2h, XhB, XAh, WudH, WudL, dub, Rb,
                                     Hst, XAh, XhA, 2, 2, 0x0F, 0x30,
                                     nullptr, 0, nullptr, nullptr,
                                     pw, pb, ycov, YD1, YD2, out, t);
  }
}